// Round 4
// baseline (12366.906 us; speedup 1.0000x reference)
//
#include <hip/hip_runtime.h>
#include <cstdint>
#include <cstddef>

// AttentiveFP forward. B=256 L=128 K=6 FA=39 FB=10 D=128 R=3 T=2.
// ALL float tensors fp32; indices int32.
// ws: h fp32 [B*L*D] (16MB) + transposed GRU weights [3][2][128][384] (1.2MB).
// k_round processes NA=8 atoms per block; GRU/attend GEMMs are x-stationary:
// coalesced weight loads broadcast against LDS-resident activations.

#define B_ 256
#define L_ 128
#define K_ 6
#define FA_ 39
#define FB_ 10
#define D_ 128
#define PAD_ 127
#define NEGC (-9.0e8f)
#define NA 8
#define NP (NA * K_)   // 48 gather pairs per block

__device__ __forceinline__ float lrelu(float x) { return x > 0.f ? x : 0.01f * x; }
__device__ __forceinline__ float eluf(float x)  { return x > 0.f ? x : expm1f(x); }
__device__ __forceinline__ float sigm(float x)  { return 1.f / (1.f + expf(-x)); }

// acc + dot(w_row[0:128], x[0:128]) — used only in k_mol (256 blocks, cheap)
__device__ __forceinline__ float dot128(const float* __restrict__ w,
                                        const float* __restrict__ x, float acc) {
  const float4* wp = (const float4*)w;
#pragma unroll
  for (int i = 0; i < 32; i++) {
    float4 u = wp[i];
    acc += x[4 * i + 0] * u.x + x[4 * i + 1] * u.y
         + x[4 * i + 2] * u.z + x[4 * i + 3] * u.w;
  }
  return acc;
}

__device__ __forceinline__ float blk_sum(float v, float* red, int tid) {
  red[tid] = v; __syncthreads();
  for (int s = 64; s > 0; s >>= 1) {
    if (tid < s) red[tid] += red[tid + s];
    __syncthreads();
  }
  float r = red[0]; __syncthreads();
  return r;
}
__device__ __forceinline__ float blk_max(float v, float* red, int tid) {
  red[tid] = v; __syncthreads();
  for (int s = 64; s > 0; s >>= 1) {
    if (tid < s) red[tid] = fmaxf(red[tid], red[tid + s]);
    __syncthreads();
  }
  float r = red[0]; __syncthreads();
  return r;
}

// Transpose gru weights: wT[((d*2+m)*128 + j)*384 + g] = src[d][g*128+j]
__global__ __launch_bounds__(256) void k_tr(const float* __restrict__ wih,
                                            const float* __restrict__ whh,
                                            float* __restrict__ wT) {
  int idx = blockIdx.x * 256 + threadIdx.x;
  if (idx >= 3 * 2 * 128 * 384) return;
  int g = idx % 384;
  int j = (idx / 384) % 128;
  int m = (idx / (384 * 128)) % 2;
  int d = idx / (384 * 128 * 2);
  const float* src = (m == 0 ? wih : whh) + (size_t)d * 384 * 128;
  wT[idx] = src[g * 128 + j];
}

__global__ __launch_bounds__(128) void k_round(
    int first,
    const float* __restrict__ hin,
    float* __restrict__ hout,
    const float* __restrict__ atom_list,
    const float* __restrict__ bond_list,
    const int* __restrict__ adeg,
    const int* __restrict__ bdeg,
    const float* __restrict__ afc_w, const float* __restrict__ afc_b,
    const float* __restrict__ nbr_w, const float* __restrict__ nbr_b,
    const float* __restrict__ aw, const float* __restrict__ ab,
    const float* __restrict__ tw, const float* __restrict__ tb,
    const float* __restrict__ wT,     // this round: [2][128][384] (ih, hh)
    const float* __restrict__ bih, const float* __restrict__ bhh)
{
  int tid = threadIdx.x;
  int a0 = blockIdx.x * NA;     // first global atom of this block
  int bb = a0 >> 7;             // molecule (NA divides L)

  __shared__ float nbrS[NA][K_][D_ + 1];
  __shared__ float curS[NA][D_ + 1];
  __shared__ __align__(16) float hrowS[NA][D_];
  __shared__ __align__(16) float ybarS[NA][D_];
  __shared__ __align__(16) float ctxS[NA][D_];
  __shared__ float scratch[NA * 384];   // round0: xc[48][52]+xa[8][40]; later: gi[NA][384]
  __shared__ float awloS[D_], awhiS[D_];
  __shared__ float pS[NA], qS[NA][K_], wkS[NA][K_], wsS[NA];
  __shared__ int aidxS[NA][K_], bidxS[NA][K_];

  if (tid < NP) {
    int a = tid / K_, k = tid % K_;
    aidxS[a][k] = adeg[(a0 + a) * K_ + k];
    bidxS[a][k] = bdeg[(a0 + a) * K_ + k];
  }
  awloS[tid] = aw[tid];
  awhiS[tid] = aw[D_ + tid];
  __syncthreads();

  if (first) {
    // stage xc (48 pairs x 49) and xa (8 atoms x 39) into scratch
    if (tid < NP) {
      int a = tid / K_, k = tid % K_;
      const float* ar = atom_list + (size_t)(bb * L_ + aidxS[a][k]) * FA_;
      const float* br = bond_list + (size_t)(bb * L_ + bidxS[a][k]) * FB_;
      float* dst = scratch + tid * 52;
      for (int j = 0; j < FA_; j++) dst[j] = ar[j];
      for (int j = 0; j < FB_; j++) dst[FA_ + j] = br[j];
    } else if (tid >= 64 && tid < 64 + NA) {
      int a = tid - 64;
      const float* ar = atom_list + (size_t)(a0 + a) * FA_;
      float* dst = scratch + 2496 + a * 40;
      for (int j = 0; j < FA_; j++) dst[j] = ar[j];
    }
    __syncthreads();

    // atom features: hrow = cur = lrelu(xa @ afc_w + afc_b)
    {
      float acc[NA];
      float bv = afc_b[tid];
#pragma unroll
      for (int a = 0; a < NA; a++) acc[a] = bv;
      for (int j = 0; j < FA_; j++) {
        float w = afc_w[j * D_ + tid];
#pragma unroll
        for (int a = 0; a < NA; a++) acc[a] += scratch[2496 + a * 40 + j] * w;
      }
#pragma unroll
      for (int a = 0; a < NA; a++) {
        float hv = lrelu(acc[a]);
        hrowS[a][tid] = hv;
        curS[a][tid] = hv;
      }
    }
    // neighbor features in chunks of 8 pairs: lrelu(xc @ nbr_w + nbr_b)
    for (int p0 = 0; p0 < NP; p0 += 8) {
      float acc[8];
      float bv = nbr_b[tid];
#pragma unroll
      for (int q = 0; q < 8; q++) acc[q] = bv;
      for (int j = 0; j < FA_ + FB_; j++) {
        float w = nbr_w[j * D_ + tid];
#pragma unroll
        for (int q = 0; q < 8; q++) acc[q] += scratch[(p0 + q) * 52 + j] * w;
      }
#pragma unroll
      for (int q = 0; q < 8; q++) {
        int p = p0 + q;
        nbrS[p / K_][p % K_][tid] = lrelu(acc[q]);
      }
    }
    __syncthreads();
  } else {
#pragma unroll
    for (int a = 0; a < NA; a++) {
      float hv = hin[(size_t)(a0 + a) * D_ + tid];
      hrowS[a][tid] = hv;
      curS[a][tid] = fmaxf(hv, 0.f);
    }
    for (int p = 0; p < NP; p++) {
      int a = p / K_, k = p % K_;
      nbrS[a][k][tid] = fmaxf(hin[(size_t)(bb * L_ + aidxS[a][k]) * D_ + tid], 0.f);
    }
    __syncthreads();
  }

  // ---- attention scores: p[a] = cur.awlo ; q[a][k] = nbr.awhi
  if (tid < NP) {
    int a = tid / K_, k = tid % K_;
    float s = 0.f;
    for (int j = 0; j < D_; j++) s += nbrS[a][k][j] * awhiS[j];
    qS[a][k] = s;
  } else if (tid >= 64 && tid < 64 + NA) {
    int a = tid - 64;
    float s = 0.f;
    for (int j = 0; j < D_; j++) s += curS[a][j] * awloS[j];
    pS[a] = s;
  }
  __syncthreads();

  // softmax over K per atom (8 threads)
  if (tid < NA) {
    int a = tid;
    float abv = ab[0];
    float sc[K_];
    float m = -3.0e38f;
#pragma unroll
    for (int k = 0; k < K_; k++) {
      float s = lrelu(pS[a] + qS[a][k] + abv);
      if (aidxS[a][k] == PAD_) s += NEGC;
      sc[k] = s; m = fmaxf(m, s);
    }
    float es = 0.f;
#pragma unroll
    for (int k = 0; k < K_; k++) { sc[k] = expf(sc[k] - m); es += sc[k]; }
    float ws = 0.f;
#pragma unroll
    for (int k = 0; k < K_; k++) {
      float w = (aidxS[a][k] == PAD_) ? 0.f : sc[k] / es;
      wkS[a][k] = w; ws += w;
    }
    wsS[a] = ws;
  }
  __syncthreads();

  // ---- ybar[a] = sum_k w_k * nbr_k
#pragma unroll
  for (int a = 0; a < NA; a++) {
    float yb = 0.f;
#pragma unroll
    for (int k = 0; k < K_; k++) yb += wkS[a][k] * nbrS[a][k][tid];
    ybarS[a][tid] = yb;
  }
  __syncthreads();

  // ---- ctx[a] = elu(ybar[a] @ tw + wsum[a]*tb)
  {
    float acc[NA];
    float bv = tb[tid];
#pragma unroll
    for (int a = 0; a < NA; a++) acc[a] = wsS[a] * bv;
    for (int j0 = 0; j0 < D_; j0 += 4) {
      float4 y4[NA];
#pragma unroll
      for (int a = 0; a < NA; a++) y4[a] = *(const float4*)&ybarS[a][j0];
#pragma unroll
      for (int i = 0; i < 4; i++) {
        float w = tw[(j0 + i) * D_ + tid];
#pragma unroll
        for (int a = 0; a < NA; a++) {
          float xv = (i == 0) ? y4[a].x : (i == 1) ? y4[a].y : (i == 2) ? y4[a].z : y4[a].w;
          acc[a] += xv * w;
        }
      }
    }
#pragma unroll
    for (int a = 0; a < NA; a++) ctxS[a][tid] = eluf(acc[a]);
  }
  __syncthreads();

  // ---- GRU: gi = ctx @ wih^T + bih  (x-stationary, coalesced wT loads)
  const float* wih_t = wT;                  // [128][384]
  const float* whh_t = wT + 128 * 384;
  {
    float acc0[NA], acc1[NA], acc2[NA];
    float b0 = bih[tid], b1 = bih[D_ + tid], b2 = bih[2 * D_ + tid];
#pragma unroll
    for (int a = 0; a < NA; a++) { acc0[a] = b0; acc1[a] = b1; acc2[a] = b2; }
    for (int j0 = 0; j0 < D_; j0 += 4) {
      float4 x4[NA];
#pragma unroll
      for (int a = 0; a < NA; a++) x4[a] = *(const float4*)&ctxS[a][j0];
#pragma unroll
      for (int i = 0; i < 4; i++) {
        const float* wr = wih_t + (size_t)(j0 + i) * 384;
        float w0 = wr[tid], w1 = wr[D_ + tid], w2 = wr[2 * D_ + tid];
#pragma unroll
        for (int a = 0; a < NA; a++) {
          float xv = (i == 0) ? x4[a].x : (i == 1) ? x4[a].y : (i == 2) ? x4[a].z : x4[a].w;
          acc0[a] += xv * w0; acc1[a] += xv * w1; acc2[a] += xv * w2;
        }
      }
    }
#pragma unroll
    for (int a = 0; a < NA; a++) {
      scratch[a * 384 + tid] = acc0[a];
      scratch[a * 384 + D_ + tid] = acc1[a];
      scratch[a * 384 + 2 * D_ + tid] = acc2[a];
    }
  }
  // gh = hrow @ whh^T + bhh, then gates (gi read back: own-thread entries only)
  {
    float acc0[NA], acc1[NA], acc2[NA];
    float b0 = bhh[tid], b1 = bhh[D_ + tid], b2 = bhh[2 * D_ + tid];
#pragma unroll
    for (int a = 0; a < NA; a++) { acc0[a] = b0; acc1[a] = b1; acc2[a] = b2; }
    for (int j0 = 0; j0 < D_; j0 += 4) {
      float4 x4[NA];
#pragma unroll
      for (int a = 0; a < NA; a++) x4[a] = *(const float4*)&hrowS[a][j0];
#pragma unroll
      for (int i = 0; i < 4; i++) {
        const float* wr = whh_t + (size_t)(j0 + i) * 384;
        float w0 = wr[tid], w1 = wr[D_ + tid], w2 = wr[2 * D_ + tid];
#pragma unroll
        for (int a = 0; a < NA; a++) {
          float xv = (i == 0) ? x4[a].x : (i == 1) ? x4[a].y : (i == 2) ? x4[a].z : x4[a].w;
          acc0[a] += xv * w0; acc1[a] += xv * w1; acc2[a] += xv * w2;
        }
      }
    }
#pragma unroll
    for (int a = 0; a < NA; a++) {
      float r = sigm(scratch[a * 384 + tid] + acc0[a]);
      float z = sigm(scratch[a * 384 + D_ + tid] + acc1[a]);
      float n = tanhf(scratch[a * 384 + 2 * D_ + tid] + r * acc2[a]);
      float hv = hrowS[a][tid];
      hout[(size_t)(a0 + a) * D_ + tid] = (1.f - z) * n + z * hv;
    }
  }
}

__global__ __launch_bounds__(128) void k_mol(
    const float* __restrict__ hfin,
    float* __restrict__ hcopy,
    const float* __restrict__ amask,
    const float* __restrict__ maw, const float* __restrict__ mab,
    const float* __restrict__ mtw, const float* __restrict__ mtb,
    const float* __restrict__ wih, const float* __restrict__ whh,
    const float* __restrict__ bih, const float* __restrict__ bhh,
    const float* __restrict__ ow, const float* __restrict__ ob,
    float* __restrict__ pred)
{
  int b = blockIdx.x;
  int tid = threadIdx.x;
  __shared__ float actS[L_][D_ + 1];
  __shared__ float red[D_], wgt[L_], ybv[D_], ctx[D_], mfS[D_], amol[D_];
  __shared__ float msk[L_], mawh[D_];

  msk[tid] = amask[b * L_ + tid];
  mawh[tid] = maw[D_ + tid];
  for (int l = 0; l < L_; l++) {
    float hv = hfin[(size_t)(b * L_ + l) * D_ + tid];
    hcopy[(size_t)(b * L_ + l) * D_ + tid] = hv;
    actS[l][tid] = fmaxf(hv, 0.f);
  }
  __syncthreads();

  float mf = 0.f;
  for (int l = 0; l < L_; l++) mf += actS[l][tid] * msk[l];
  mfS[tid] = mf;
  amol[tid] = fmaxf(mf, 0.f);
  __syncthreads();

  float mabv = mab[0];

  for (int t = 0; t < 2; t++) {
    float s0 = blk_sum(amol[tid] * maw[tid], red, tid);

    float sc = s0 + mabv;
    for (int j = 0; j < D_; j++) sc += actS[tid][j] * mawh[j];
    sc = lrelu(sc);
    if (msk[tid] == 0.f) sc += NEGC;

    float mx = blk_max(sc, red, tid);
    float e = expf(sc - mx);
    float es = blk_sum(e, red, tid);
    float w = (e / es) * msk[tid];
    wgt[tid] = w;
    float wsum = blk_sum(w, red, tid);
    __syncthreads();

    float y = 0.f;
    for (int l = 0; l < L_; l++) y += wgt[l] * actS[l][tid];
    ybv[tid] = y;
    __syncthreads();
    float acc = wsum * mtb[tid];
    for (int j = 0; j < D_; j++) acc += ybv[j] * mtw[j * D_ + tid];
    ctx[tid] = eluf(acc);
    __syncthreads();

    float gi[3], gh[3];
#pragma unroll
    for (int c = 0; c < 3; c++) {
      int g = c * D_ + tid;
      gi[c] = dot128(wih + (size_t)g * D_, ctx, bih[g]);
      gh[c] = dot128(whh + (size_t)g * D_, mfS, bhh[g]);
    }
    float r = sigm(gi[0] + gh[0]);
    float z = sigm(gi[1] + gh[1]);
    float n = tanhf(gi[2] + r * gh[2]);
    float hn = (1.f - z) * n + z * mfS[tid];
    __syncthreads();
    mfS[tid] = hn;
    amol[tid] = fmaxf(hn, 0.f);
    __syncthreads();
  }

  float p = blk_sum(mfS[tid] * ow[tid], red, tid);
  if (tid == 0) pred[b] = p + ob[0];
}

extern "C" void kernel_launch(void* const* d_in, const int* in_sizes, int n_in,
                              void* d_out, int out_size, void* d_ws, size_t ws_size,
                              hipStream_t stream) {
  const float* atom_list    = (const float*)d_in[0];
  const float* bond_list    = (const float*)d_in[1];
  const float* atom_mask    = (const float*)d_in[2];
  const float* atom_fc_w    = (const float*)d_in[3];
  const float* atom_fc_b    = (const float*)d_in[4];
  const float* nbr_fc_w     = (const float*)d_in[5];
  const float* nbr_fc_b     = (const float*)d_in[6];
  const float* align_w      = (const float*)d_in[7];
  const float* align_b      = (const float*)d_in[8];
  const float* attend_w     = (const float*)d_in[9];
  const float* attend_b     = (const float*)d_in[10];
  const float* gru_wih      = (const float*)d_in[11];
  const float* gru_whh      = (const float*)d_in[12];
  const float* gru_bih      = (const float*)d_in[13];
  const float* gru_bhh      = (const float*)d_in[14];
  const float* mol_align_w  = (const float*)d_in[15];
  const float* mol_align_b  = (const float*)d_in[16];
  const float* mol_attend_w = (const float*)d_in[17];
  const float* mol_attend_b = (const float*)d_in[18];
  const float* mol_gru_wih  = (const float*)d_in[19];
  const float* mol_gru_whh  = (const float*)d_in[20];
  const float* mol_gru_bih  = (const float*)d_in[21];
  const float* mol_gru_bhh  = (const float*)d_in[22];
  const float* out_w        = (const float*)d_in[23];
  const float* out_b        = (const float*)d_in[24];
  const int*   adeg         = (const int*)d_in[25];
  const int*   bdeg         = (const int*)d_in[26];

  const size_t NH = (size_t)B_ * L_ * D_;
  float* hW   = (float*)d_ws;              // 16 MB
  float* wT   = hW + NH;                   // 3*2*128*384 fp32 = 1.2 MB
  float* hOut = (float*)d_out;
  float* pred = hOut + NH;

  // transpose GRU weights (294912 elements)
  hipLaunchKernelGGL(k_tr, dim3((3 * 2 * 128 * 384 + 255) / 256), dim3(256), 0, stream,
                     gru_wih, gru_whh, wT);

  dim3 blk(128), grd(B_ * L_ / NA);
  const float* rin[3]  = { nullptr, hW, hOut };
  float*       rout[3] = { hW, hOut, hW };
  for (int d = 0; d < 3; d++) {
    hipLaunchKernelGGL(k_round, grd, blk, 0, stream,
        (d == 0) ? 1 : 0, rin[d], rout[d],
        atom_list, bond_list, adeg, bdeg,
        atom_fc_w, atom_fc_b, nbr_fc_w, nbr_fc_b,
        align_w + (size_t)d * 2 * D_, align_b + d,
        attend_w + (size_t)d * D_ * D_, attend_b + (size_t)d * D_,
        wT + (size_t)d * 2 * 128 * 384,
        gru_bih + (size_t)d * 3 * D_, gru_bhh + (size_t)d * 3 * D_);
  }

  hipLaunchKernelGGL(k_mol, dim3(B_), blk, 0, stream,
      hW, hOut, atom_mask, mol_align_w, mol_align_b, mol_attend_w, mol_attend_b,
      mol_gru_wih, mol_gru_whh, mol_gru_bih, mol_gru_bhh, out_w, out_b, pred);
}

// Round 5
// 1253.507 us; speedup vs baseline: 9.8658x; 9.8658x over previous
//
#include <hip/hip_runtime.h>
#include <cstddef>

// AttentiveFP forward. B=256 L=128 K=6 FA=39 FB=10 D=128 R=3 T=2. All fp32.
// ws: h fp32 [B*L*D] (16MB) + transposed GRU weights wT [8][128][384] (1.57MB):
//   m=0..5: round d=m/2, (even=wih, odd=whh); m=6: mol_wih; m=7: mol_whh.
// k_round<FIRST>: NA=8 atoms/block, x-stationary GEMMs (coalesced weight loads,
// LDS-broadcast activations), 48 scalar GRU accumulators, no spill-prone arrays.

#define B_ 256
#define L_ 128
#define K_ 6
#define FA_ 39
#define FB_ 10
#define D_ 128
#define PAD_ 127
#define NEGC (-9.0e8f)
#define NA 8
#define NP (NA * K_)   // 48

__device__ __forceinline__ float lrelu(float x) { return x > 0.f ? x : 0.01f * x; }
__device__ __forceinline__ float eluf(float x)  { return x > 0.f ? x : expm1f(x); }
__device__ __forceinline__ float sigm(float x)  { return 1.f / (1.f + expf(-x)); }

__device__ __forceinline__ float blk_sum(float v, float* red, int tid) {
  red[tid] = v; __syncthreads();
  for (int s = 64; s > 0; s >>= 1) {
    if (tid < s) red[tid] += red[tid + s];
    __syncthreads();
  }
  float r = red[0]; __syncthreads();
  return r;
}
__device__ __forceinline__ float blk_max(float v, float* red, int tid) {
  red[tid] = v; __syncthreads();
  for (int s = 64; s > 0; s >>= 1) {
    if (tid < s) red[tid] = fmaxf(red[tid], red[tid + s]);
    __syncthreads();
  }
  float r = red[0]; __syncthreads();
  return r;
}

// Transpose 8 [384][128] matrices into wT[m][j][g] = src_m[g*128+j]
__global__ __launch_bounds__(256) void k_tr(
    const float* __restrict__ wih, const float* __restrict__ whh,
    const float* __restrict__ mwih, const float* __restrict__ mwhh,
    float* __restrict__ wT) {
  int idx = blockIdx.x * 256 + threadIdx.x;
  if (idx >= 8 * 128 * 384) return;
  int g = idx % 384;
  int j = (idx / 384) % 128;
  int m = idx / (384 * 128);
  const float* src;
  if (m < 6) src = ((m & 1) ? whh : wih) + (size_t)(m >> 1) * 384 * 128;
  else       src = (m == 6) ? mwih : mwhh;
  wT[idx] = src[g * 128 + j];
}

template <int FIRST>
__global__ __launch_bounds__(128, 2) void k_round(
    const float* __restrict__ hin,
    float* __restrict__ hout,
    const float* __restrict__ atom_list,
    const float* __restrict__ bond_list,
    const int* __restrict__ adeg,
    const int* __restrict__ bdeg,
    const float* __restrict__ afc_w, const float* __restrict__ afc_b,
    const float* __restrict__ nbr_w, const float* __restrict__ nbr_b,
    const float* __restrict__ aw, const float* __restrict__ ab,
    const float* __restrict__ tw, const float* __restrict__ tb,
    const float* __restrict__ wih_t, const float* __restrict__ whh_t,
    const float* __restrict__ bih, const float* __restrict__ bhh)
{
  int tid = threadIdx.x;
  int a0 = blockIdx.x * NA;
  int bb = a0 >> 7;

  __shared__ float nbrS[NA][K_][D_ + 1];
  __shared__ float hrowS[NA][D_];
  __shared__ float ybarS[NA][D_];
  __shared__ float ctxS[NA][D_];
  __shared__ float awS[2 * D_];
  __shared__ float pS[NA], qS[NP], wkS[NP], wsS[NA];
  __shared__ int aidxS[NP];
  __shared__ float xstage[FIRST ? 2816 : 1];
  __shared__ int bidxS[FIRST ? NP : 1];

  if (tid < NP) {
    aidxS[tid] = adeg[a0 * K_ + tid];
    if (FIRST) bidxS[tid] = bdeg[a0 * K_ + tid];
  }
  awS[tid] = aw[tid];
  awS[D_ + tid] = aw[D_ + tid];
  __syncthreads();

  if (FIRST) {
    // stage gather inputs: xc 48x52 (atom||bond), xa 8x40
    if (tid < NP) {
      const float* ar = atom_list + (size_t)(bb * L_ + aidxS[tid]) * FA_;
      const float* br = bond_list + (size_t)(bb * L_ + bidxS[tid]) * FB_;
      float* dst = xstage + tid * 52;
      for (int j = 0; j < FA_; j++) dst[j] = ar[j];
      for (int j = 0; j < FB_; j++) dst[FA_ + j] = br[j];
    } else if (tid >= 64 && tid < 64 + NA) {
      int a = tid - 64;
      const float* ar = atom_list + (size_t)(a0 + a) * FA_;
      float* dst = xstage + 2496 + a * 40;
      for (int j = 0; j < FA_; j++) dst[j] = ar[j];
    }
    __syncthreads();

    { // atom fc -> hrow (= cur for round 0)
      float acc[NA];
      float bv = afc_b[tid];
#pragma unroll
      for (int a = 0; a < NA; a++) acc[a] = bv;
#pragma unroll 1
      for (int j = 0; j < FA_; j++) {
        float w = afc_w[j * D_ + tid];
#pragma unroll
        for (int a = 0; a < NA; a++) acc[a] += xstage[2496 + a * 40 + j] * w;
      }
#pragma unroll
      for (int a = 0; a < NA; a++) hrowS[a][tid] = lrelu(acc[a]);
    }
    // nbr fc in chunks of 8 pairs
#pragma unroll 1
    for (int p0 = 0; p0 < NP; p0 += 8) {
      float acc[8];
      float bv = nbr_b[tid];
#pragma unroll
      for (int q = 0; q < 8; q++) acc[q] = bv;
#pragma unroll 1
      for (int j = 0; j < FA_ + FB_; j++) {
        float w = nbr_w[j * D_ + tid];
#pragma unroll
        for (int q = 0; q < 8; q++) acc[q] += xstage[(p0 + q) * 52 + j] * w;
      }
#pragma unroll
      for (int q = 0; q < 8; q++)
        nbrS[(p0 + q) / K_][(p0 + q) % K_][tid] = lrelu(acc[q]);
    }
    __syncthreads();
  } else {
#pragma unroll
    for (int a = 0; a < NA; a++)
      hrowS[a][tid] = hin[(size_t)(a0 + a) * D_ + tid];
#pragma unroll 1
    for (int p = 0; p < NP; p++)
      nbrS[p / K_][p % K_][tid] =
          fmaxf(hin[(size_t)(bb * L_ + aidxS[p]) * D_ + tid], 0.f);
    __syncthreads();
  }

  // ---- attention scores: q[p]=nbr.aw_hi (48 threads), p[a]=cur.aw_lo (8 threads)
  if (tid < NP) {
    int a = tid / K_, k = tid % K_;
    float s = 0.f;
    for (int j = 0; j < D_; j++) s += nbrS[a][k][j] * awS[D_ + j];
    qS[tid] = s;
  } else if (tid >= 64 && tid < 64 + NA) {
    int a = tid - 64;
    float s = 0.f;
    for (int j = 0; j < D_; j++) {
      float v = hrowS[a][j];
      if (!FIRST) v = fmaxf(v, 0.f);
      s += v * awS[j];
    }
    pS[a] = s;
  }
  __syncthreads();

  // softmax over K per atom (8 threads)
  if (tid < NA) {
    int a = tid;
    float abv = ab[0];
    float sc[K_];
    float m = -3.0e38f;
#pragma unroll
    for (int k = 0; k < K_; k++) {
      float s = lrelu(pS[a] + qS[a * K_ + k] + abv);
      if (aidxS[a * K_ + k] == PAD_) s += NEGC;
      sc[k] = s; m = fmaxf(m, s);
    }
    float es = 0.f;
#pragma unroll
    for (int k = 0; k < K_; k++) { sc[k] = expf(sc[k] - m); es += sc[k]; }
    float ws = 0.f;
#pragma unroll
    for (int k = 0; k < K_; k++) {
      float w = (aidxS[a * K_ + k] == PAD_) ? 0.f : sc[k] / es;
      wkS[a * K_ + k] = w; ws += w;
    }
    wsS[a] = ws;
  }
  __syncthreads();

  // ---- ybar[a] = sum_k w_k * nbr_k
#pragma unroll
  for (int a = 0; a < NA; a++) {
    float yb = 0.f;
#pragma unroll
    for (int k = 0; k < K_; k++) yb += wkS[a * K_ + k] * nbrS[a][k][tid];
    ybarS[a][tid] = yb;
  }
  __syncthreads();

  // ---- ctx[a] = elu(ybar[a] @ tw + wsum[a]*tb)
  {
    float acc[NA];
    float bv = tb[tid];
#pragma unroll
    for (int a = 0; a < NA; a++) acc[a] = wsS[a] * bv;
#pragma unroll 1
    for (int j = 0; j < D_; j++) {
      float w = tw[j * D_ + tid];
#pragma unroll
      for (int a = 0; a < NA; a++) acc[a] += ybarS[a][j] * w;
    }
#pragma unroll
    for (int a = 0; a < NA; a++) ctxS[a][tid] = eluf(acc[a]);
  }
  __syncthreads();

  // ---- GRU, fused single pass: thread t owns gate outputs (t, 128+t, 256+t)
  float gi0[NA], gi1[NA], gi2[NA], gh0[NA], gh1[NA], gh2[NA];
  {
    float bi0 = bih[tid], bi1 = bih[D_ + tid], bi2 = bih[2 * D_ + tid];
    float bh0 = bhh[tid], bh1 = bhh[D_ + tid], bh2 = bhh[2 * D_ + tid];
#pragma unroll
    for (int a = 0; a < NA; a++) {
      gi0[a] = bi0; gi1[a] = bi1; gi2[a] = bi2;
      gh0[a] = bh0; gh1[a] = bh1; gh2[a] = bh2;
    }
  }
#pragma unroll 1
  for (int j0 = 0; j0 < D_; j0 += 2) {
#pragma unroll
    for (int i = 0; i < 2; i++) {
      int j = j0 + i;
      const float* wi = wih_t + (size_t)j * 384;
      const float* wh = whh_t + (size_t)j * 384;
      float wi0 = wi[tid], wi1 = wi[D_ + tid], wi2 = wi[2 * D_ + tid];
      float wh0 = wh[tid], wh1 = wh[D_ + tid], wh2 = wh[2 * D_ + tid];
#pragma unroll
      for (int a = 0; a < NA; a++) {
        float xc = ctxS[a][j], xh = hrowS[a][j];
        gi0[a] += xc * wi0; gi1[a] += xc * wi1; gi2[a] += xc * wi2;
        gh0[a] += xh * wh0; gh1[a] += xh * wh1; gh2[a] += xh * wh2;
      }
    }
  }
#pragma unroll
  for (int a = 0; a < NA; a++) {
    float r = sigm(gi0[a] + gh0[a]);
    float z = sigm(gi1[a] + gh1[a]);
    float n = tanhf(gi2[a] + r * gh2[a]);
    float hv = hrowS[a][tid];
    hout[(size_t)(a0 + a) * D_ + tid] = (1.f - z) * n + z * hv;
  }
}

__global__ __launch_bounds__(128) void k_mol(
    const float* __restrict__ hfin,
    float* __restrict__ hcopy,
    const float* __restrict__ amask,
    const float* __restrict__ maw, const float* __restrict__ mab,
    const float* __restrict__ mtw, const float* __restrict__ mtb,
    const float* __restrict__ wih_t, const float* __restrict__ whh_t,
    const float* __restrict__ bih, const float* __restrict__ bhh,
    const float* __restrict__ ow, const float* __restrict__ ob,
    float* __restrict__ pred)
{
  int b = blockIdx.x;
  int tid = threadIdx.x;
  __shared__ float actS[L_][D_ + 1];
  __shared__ float red[D_], wgt[L_], ybv[D_], ctx[D_], mfS[D_], amol[D_];
  __shared__ float msk[L_], mawh[D_];

  msk[tid] = amask[b * L_ + tid];
  mawh[tid] = maw[D_ + tid];
  for (int l = 0; l < L_; l++) {
    float hv = hfin[(size_t)(b * L_ + l) * D_ + tid];
    hcopy[(size_t)(b * L_ + l) * D_ + tid] = hv;
    actS[l][tid] = fmaxf(hv, 0.f);
  }
  __syncthreads();

  float mf = 0.f;
  for (int l = 0; l < L_; l++) mf += actS[l][tid] * msk[l];
  mfS[tid] = mf;
  amol[tid] = fmaxf(mf, 0.f);
  __syncthreads();

  float mabv = mab[0];

  for (int t = 0; t < 2; t++) {
    float s0 = blk_sum(amol[tid] * maw[tid], red, tid);

    float sc = s0 + mabv;
    for (int j = 0; j < D_; j++) sc += actS[tid][j] * mawh[j];
    sc = lrelu(sc);
    if (msk[tid] == 0.f) sc += NEGC;

    float mx = blk_max(sc, red, tid);
    float e = expf(sc - mx);
    float es = blk_sum(e, red, tid);
    float w = (e / es) * msk[tid];
    wgt[tid] = w;
    float wsum = blk_sum(w, red, tid);
    __syncthreads();

    float y = 0.f;
    for (int l = 0; l < L_; l++) y += wgt[l] * actS[l][tid];
    ybv[tid] = y;
    __syncthreads();
    float acc = wsum * mtb[tid];
    for (int j = 0; j < D_; j++) acc += ybv[j] * mtw[j * D_ + tid];
    ctx[tid] = eluf(acc);
    __syncthreads();

    // GRU x-stationary (coalesced transposed weights)
    float gi0 = bih[tid], gi1 = bih[D_ + tid], gi2 = bih[2 * D_ + tid];
    float gh0 = bhh[tid], gh1 = bhh[D_ + tid], gh2 = bhh[2 * D_ + tid];
#pragma unroll 1
    for (int j = 0; j < D_; j++) {
      const float* wi = wih_t + (size_t)j * 384;
      const float* wh = whh_t + (size_t)j * 384;
      float xc = ctx[j], xh = mfS[j];
      gi0 += xc * wi[tid]; gi1 += xc * wi[D_ + tid]; gi2 += xc * wi[2 * D_ + tid];
      gh0 += xh * wh[tid]; gh1 += xh * wh[D_ + tid]; gh2 += xh * wh[2 * D_ + tid];
    }
    float r = sigm(gi0 + gh0);
    float z = sigm(gi1 + gh1);
    float n = tanhf(gi2 + r * gh2);
    float hn = (1.f - z) * n + z * mfS[tid];
    __syncthreads();
    mfS[tid] = hn;
    amol[tid] = fmaxf(hn, 0.f);
    __syncthreads();
  }

  float p = blk_sum(mfS[tid] * ow[tid], red, tid);
  if (tid == 0) pred[b] = p + ob[0];
}

extern "C" void kernel_launch(void* const* d_in, const int* in_sizes, int n_in,
                              void* d_out, int out_size, void* d_ws, size_t ws_size,
                              hipStream_t stream) {
  const float* atom_list    = (const float*)d_in[0];
  const float* bond_list    = (const float*)d_in[1];
  const float* atom_mask    = (const float*)d_in[2];
  const float* atom_fc_w    = (const float*)d_in[3];
  const float* atom_fc_b    = (const float*)d_in[4];
  const float* nbr_fc_w     = (const float*)d_in[5];
  const float* nbr_fc_b     = (const float*)d_in[6];
  const float* align_w      = (const float*)d_in[7];
  const float* align_b      = (const float*)d_in[8];
  const float* attend_w     = (const float*)d_in[9];
  const float* attend_b     = (const float*)d_in[10];
  const float* gru_wih      = (const float*)d_in[11];
  const float* gru_whh      = (const float*)d_in[12];
  const float* gru_bih      = (const float*)d_in[13];
  const float* gru_bhh      = (const float*)d_in[14];
  const float* mol_align_w  = (const float*)d_in[15];
  const float* mol_align_b  = (const float*)d_in[16];
  const float* mol_attend_w = (const float*)d_in[17];
  const float* mol_attend_b = (const float*)d_in[18];
  const float* mol_gru_wih  = (const float*)d_in[19];
  const float* mol_gru_whh  = (const float*)d_in[20];
  const float* mol_gru_bih  = (const float*)d_in[21];
  const float* mol_gru_bhh  = (const float*)d_in[22];
  const float* out_w        = (const float*)d_in[23];
  const float* out_b        = (const float*)d_in[24];
  const int*   adeg         = (const int*)d_in[25];
  const int*   bdeg         = (const int*)d_in[26];

  const size_t NH = (size_t)B_ * L_ * D_;
  float* hW   = (float*)d_ws;              // 16 MB
  float* wT   = hW + NH;                   // 8*128*384 fp32 = 1.57 MB
  float* hOut = (float*)d_out;
  float* pred = hOut + NH;

  k_tr<<<dim3((8 * 128 * 384 + 255) / 256), dim3(256), 0, stream>>>(
      gru_wih, gru_whh, mol_gru_wih, mol_gru_whh, wT);

  dim3 blk(128), grd(B_ * L_ / NA);
  const size_t WM = 128 * 384;   // one transposed matrix

  // r0 -> hW ; r1: hW -> hOut ; r2: hOut -> hW
  k_round<1><<<grd, blk, 0, stream>>>(
      nullptr, hW, atom_list, bond_list, adeg, bdeg,
      atom_fc_w, atom_fc_b, nbr_fc_w, nbr_fc_b,
      align_w, align_b, attend_w, attend_b,
      wT + 0 * WM, wT + 1 * WM, gru_bih, gru_bhh);
  k_round<0><<<grd, blk, 0, stream>>>(
      hW, hOut, atom_list, bond_list, adeg, bdeg,
      atom_fc_w, atom_fc_b, nbr_fc_w, nbr_fc_b,
      align_w + 2 * D_, align_b + 1, attend_w + D_ * D_, attend_b + D_,
      wT + 2 * WM, wT + 3 * WM, gru_bih + 3 * D_, gru_bhh + 3 * D_);
  k_round<0><<<grd, blk, 0, stream>>>(
      hOut, hW, atom_list, bond_list, adeg, bdeg,
      atom_fc_w, atom_fc_b, nbr_fc_w, nbr_fc_b,
      align_w + 4 * D_, align_b + 2, attend_w + 2 * D_ * D_, attend_b + 2 * D_,
      wT + 4 * WM, wT + 5 * WM, gru_bih + 6 * D_, gru_bhh + 6 * D_);

  k_mol<<<dim3(B_), blk, 0, stream>>>(
      hW, hOut, atom_mask, mol_align_w, mol_align_b, mol_attend_w, mol_attend_b,
      wT + 6 * WM, wT + 7 * WM, mol_gru_bih, mol_gru_bhh, out_w, out_b, pred);
}

// Round 7
// 799.373 us; speedup vs baseline: 15.4708x; 1.5681x over previous
//
#include <hip/hip_runtime.h>
#include <cstddef>

// AttentiveFP forward. B=256 L=128 K=6 FA=39 FB=10 D=128 R=3 T=2. fp32 I/O.
// k_round: MFMA bf16 split-precision (hi+lo, 3-MFMA per GEMM tile) for
// ctx/GRU GEMMs; h carried fp32. k_mol: pure fp32 (proven round-5 version).
// ws: h fp32 [B*L*D] (16MB) + split bf16 weights (1.31MB) + fp32 mol wT (0.38MB).

#define B_ 256
#define L_ 128
#define K_ 6
#define FA_ 39
#define FB_ 10
#define D_ 128
#define PAD_ 127
#define NEGC (-9.0e8f)
#define NA 16
#define NPAIR (NA * K_)   // 96

typedef unsigned short u16;
typedef unsigned int u32;
using s8 = __attribute__((ext_vector_type(8))) short;   // 8 x bf16
using f4 = __attribute__((ext_vector_type(4))) float;   // MFMA acc

// per-round split-weight block (shorts): wihH,wihL,whhH,whhL [384][128] each;
// twH,twL [128][128] g-major
#define WIH_H 0
#define WIH_L 49152
#define WHH_H 98304
#define WHH_L 147456
#define TW_H  196608
#define TW_L  212992
#define RND_BLK2 229376
#define NB16 (3 * RND_BLK2)          // 688128 shorts
#define NMOLF (2 * 128 * 384)        // fp32 mol GRU transposed, j-major

__device__ __forceinline__ float lrelu(float x) { return x > 0.f ? x : 0.01f * x; }
__device__ __forceinline__ float eluf(float x)  { return x > 0.f ? x : expm1f(x); }
__device__ __forceinline__ float sigm(float x)  { return 1.f / (1.f + expf(-x)); }
__device__ __forceinline__ float b2f(u16 u) {
  union { u32 i; float f; } v; v.i = ((u32)u) << 16; return v.f;
}
__device__ __forceinline__ short f2b(float f) {  // RNE
  union { float f; u32 i; } v; v.f = f;
  u32 x = v.i;
  return (short)(u16)((x + 0x7FFFu + ((x >> 16) & 1u)) >> 16);
}

__device__ __forceinline__ float blk_sum(float v, float* red, int tid) {
  red[tid] = v; __syncthreads();
  for (int s = 64; s > 0; s >>= 1) {
    if (tid < s) red[tid] += red[tid + s];
    __syncthreads();
  }
  float r = red[0]; __syncthreads();
  return r;
}
__device__ __forceinline__ float blk_max(float v, float* red, int tid) {
  red[tid] = v; __syncthreads();
  for (int s = 64; s > 0; s >>= 1) {
    if (tid < s) red[tid] = fmaxf(red[tid], red[tid + s]);
    __syncthreads();
  }
  float r = red[0]; __syncthreads();
  return r;
}

// Build split bf16 weights + fp32 transposed mol GRU weights.
__global__ __launch_bounds__(256) void k_tr(
    const float* __restrict__ gwih, const float* __restrict__ gwhh,
    const float* __restrict__ attw,
    const float* __restrict__ mwih, const float* __restrict__ mwhh,
    short* __restrict__ wB, float* __restrict__ molT) {
  int idx = blockIdx.x * 256 + threadIdx.x;
  if (idx < NB16) {
    int r = idx / RND_BLK2, o = idx % RND_BLK2;
    float v; int lo;
    if (o < 98304) {                       // wih hi/lo, [384][128] identity
      lo = o / 49152; int e = o % 49152;
      v = gwih[(size_t)r * 49152 + e];
    } else if (o < 196608) {
      int o2 = o - 98304;
      lo = o2 / 49152; int e = o2 % 49152;
      v = gwhh[(size_t)r * 49152 + e];
    } else {                               // twT[g][k] = tw[k][g]
      int o2 = o - 196608;
      lo = o2 / 16384; int e = o2 % 16384;
      int g = e / 128, k = e % 128;
      v = attw[(size_t)r * 16384 + k * 128 + g];
    }
    short hi = f2b(v);
    wB[idx] = lo ? f2b(v - b2f((u16)hi)) : hi;
  } else if (idx < NB16 + NMOLF) {
    int e2 = idx - NB16;
    int m = e2 / 49152, e = e2 % 49152, j = e / 384, g = e % 384;
    molT[e2] = (m ? mwhh : mwih)[g * 128 + j];
  }
}

template <int FIRST>
__global__ __launch_bounds__(256, 2) void k_round(
    const float* __restrict__ hin,
    float* __restrict__ hout,
    const float* __restrict__ atom_list,
    const float* __restrict__ bond_list,
    const int* __restrict__ adeg,
    const int* __restrict__ bdeg,
    const float* __restrict__ afc_w, const float* __restrict__ afc_b,
    const float* __restrict__ nbr_w, const float* __restrict__ nbr_b,
    const float* __restrict__ aw, const float* __restrict__ ab,
    const float* __restrict__ tb,
    const short* __restrict__ wR,     // this round's split-weight block
    const float* __restrict__ bih, const float* __restrict__ bhh)
{
  int tid  = threadIdx.x;
  int t128 = tid & 127;
  int hf   = tid >> 7;
  int lane = tid & 63;
  int wv   = tid >> 6;
  int quad = lane >> 4;
  int col  = lane & 15;
  int a0   = blockIdx.x * NA;
  int bb   = a0 >> 7;

  const short* wihH = wR + WIH_H;
  const short* wihL = wR + WIH_L;
  const short* whhH = wR + WHH_H;
  const short* whhL = wR + WHH_L;
  const short* twH  = wR + TW_H;
  const short* twL  = wR + TW_L;

  __shared__ short nbrS[NPAIR][138];
  __shared__ float hrowS[NA][132];
  __shared__ short hrowH[NA][136];
  __shared__ short hrowL[NA][136];
  __shared__ __align__(16) char arena[17408];
  __shared__ float awS[2 * D_];
  __shared__ float pS[NA], qS[NPAIR], wkS[NPAIR], wsS[NA];
  __shared__ int aidxS[NPAIR];
  __shared__ int bidxS[FIRST ? NPAIR : 1];

  short* ybarH = (short*)arena;               // [16][136]
  short* ybarL = (short*)(arena + 4352);
  short* ctxH  = (short*)(arena + 8704);
  short* ctxL  = (short*)(arena + 13056);
  float* xst   = (float*)arena;               // FIRST staging (aliases, used earlier)

  if (tid < NPAIR) {
    aidxS[tid] = adeg[a0 * K_ + tid];
    if (FIRST) bidxS[tid] = bdeg[a0 * K_ + tid];
  }
  awS[tid] = aw[tid];
  __syncthreads();

  // ---------- Phase 1: hrow + nbr(bf16) ----------
  if (FIRST) {
    for (int hp = 0; hp < 3; hp++) {
      for (int i = tid; i < 32 * 52; i += 256) {
        int r = i / 52, c = i % 52, p = hp * 32 + r;
        xst[i] = (c < FA_)
            ? atom_list[((size_t)bb * L_ + aidxS[p]) * FA_ + c]
            : bond_list[((size_t)bb * L_ + bidxS[p]) * FB_ + (c - FA_)];
      }
      if (hp == 0) {
        for (int i = tid; i < NA * 40; i += 256) {
          int a = i / 40, c = i % 40;
          xst[1664 + i] = (c < FA_) ? atom_list[((size_t)(a0 + a)) * FA_ + c] : 0.f;
        }
      }
      __syncthreads();
      for (int ch = hf * 2; ch < hf * 2 + 2; ch++) {
        float acc[8];
        float bv = nbr_b[t128];
#pragma unroll
        for (int q = 0; q < 8; q++) acc[q] = bv;
#pragma unroll 1
        for (int j = 0; j < FA_ + FB_; j++) {
          float w = nbr_w[j * D_ + t128];
#pragma unroll
          for (int q = 0; q < 8; q++) acc[q] += xst[(ch * 8 + q) * 52 + j] * w;
        }
#pragma unroll
        for (int q = 0; q < 8; q++)
          nbrS[hp * 32 + ch * 8 + q][t128] = f2b(lrelu(acc[q]));
      }
      __syncthreads();
    }
    {
      float acc[8];
      float bv = afc_b[t128];
#pragma unroll
      for (int i = 0; i < 8; i++) acc[i] = bv;
#pragma unroll 1
      for (int j = 0; j < FA_; j++) {
        float w = afc_w[j * D_ + t128];
#pragma unroll
        for (int i = 0; i < 8; i++) acc[i] += xst[1664 + (hf * 8 + i) * 40 + j] * w;
      }
#pragma unroll
      for (int i = 0; i < 8; i++) {
        int a = hf * 8 + i;
        float hv = lrelu(acc[i]);
        hrowS[a][t128] = hv;
        short hh = f2b(hv);
        hrowH[a][t128] = hh;
        hrowL[a][t128] = f2b(hv - b2f((u16)hh));
      }
    }
    __syncthreads();
  } else {
#pragma unroll 1
    for (int it = 0; it < 48; it++) {
      int r = it * 2 + hf;
      float v = hin[((size_t)bb * L_ + aidxS[r]) * D_ + t128];
      nbrS[r][t128] = f2b(fmaxf(v, 0.f));
    }
#pragma unroll 1
    for (int i = 0; i < 8; i++) {
      int a = i * 2 + hf;
      float hv = hin[(size_t)(a0 + a) * D_ + t128];
      hrowS[a][t128] = hv;
      short hh = f2b(hv);
      hrowH[a][t128] = hh;
      hrowL[a][t128] = f2b(hv - b2f((u16)hh));
    }
    __syncthreads();
  }

  // ---------- Phase 2: score dots ----------
  if (tid < NPAIR) {
    float s = 0.f;
    for (int j = 0; j < D_; j++) s += b2f((u16)nbrS[tid][j]) * awS[D_ + j];
    qS[tid] = s;
  } else if (tid >= 128 && tid < 128 + NA) {
    int a = tid - 128;
    float s = 0.f;
    for (int j = 0; j < D_; j++) {
      float v = hrowS[a][j];
      if (!FIRST) v = fmaxf(v, 0.f);
      s += v * awS[j];
    }
    pS[a] = s;
  }
  __syncthreads();

  // ---------- Phase 3: softmax over K ----------
  if (tid < NA) {
    int a = tid;
    float abv = ab[0];
    float sc[K_];
    float m = -3.0e38f;
#pragma unroll
    for (int k = 0; k < K_; k++) {
      float s = lrelu(pS[a] + qS[a * K_ + k] + abv);
      if (aidxS[a * K_ + k] == PAD_) s += NEGC;
      sc[k] = s; m = fmaxf(m, s);
    }
    float es = 0.f;
#pragma unroll
    for (int k = 0; k < K_; k++) { sc[k] = expf(sc[k] - m); es += sc[k]; }
    float ws = 0.f;
#pragma unroll
    for (int k = 0; k < K_; k++) {
      float w = (aidxS[a * K_ + k] == PAD_) ? 0.f : sc[k] / es;
      wkS[a * K_ + k] = w; ws += w;
    }
    wsS[a] = ws;
  }
  __syncthreads();

  // ---------- Phase 4: ybar (hi/lo split) ----------
#pragma unroll 1
  for (int i = 0; i < 8; i++) {
    int a = hf * 8 + i;
    float yb = 0.f;
#pragma unroll
    for (int k = 0; k < K_; k++)
      yb += wkS[a * K_ + k] * b2f((u16)nbrS[a * K_ + k][t128]);
    short yh = f2b(yb);
    ybarH[a * 136 + t128] = yh;
    ybarL[a * 136 + t128] = f2b(yb - b2f((u16)yh));
  }
  __syncthreads();

  // ---------- Phase 5: ctx = elu(ybar @ twT^T + wsum*tb), split MFMA ----------
  {
    f4 c2[2] = {};
#pragma unroll
    for (int k0 = 0; k0 < D_; k0 += 32) {
      s8 ayh = *(const s8*)&ybarH[col * 136 + k0 + quad * 8];
      s8 ayl = *(const s8*)&ybarL[col * 136 + k0 + quad * 8];
#pragma unroll
      for (int t = 0; t < 2; t++) {
        int g = (2 * wv + t) * 16 + col;
        s8 bwh = *(const s8*)&twH[(size_t)g * 128 + k0 + quad * 8];
        s8 bwl = *(const s8*)&twL[(size_t)g * 128 + k0 + quad * 8];
        c2[t] = __builtin_amdgcn_mfma_f32_16x16x32_bf16(ayh, bwh, c2[t], 0, 0, 0);
        c2[t] = __builtin_amdgcn_mfma_f32_16x16x32_bf16(ayl, bwh, c2[t], 0, 0, 0);
        c2[t] = __builtin_amdgcn_mfma_f32_16x16x32_bf16(ayh, bwl, c2[t], 0, 0, 0);
      }
    }
#pragma unroll
    for (int t = 0; t < 2; t++) {
      int g = (2 * wv + t) * 16 + col;
      float tbv = tb[g];
#pragma unroll
      for (int r = 0; r < 4; r++) {
        int a = quad * 4 + r;
        float c = eluf(c2[t][r] + wsS[a] * tbv);
        short chs = f2b(c);
        ctxH[a * 136 + g] = chs;
        ctxL[a * 136 + g] = f2b(c - b2f((u16)chs));
      }
    }
  }
  __syncthreads();

  // ---------- Phase 6: GRU via split MFMA ----------
  {
    f4 gi[2][3] = {}, gh[2][3] = {};
#pragma unroll
    for (int k0 = 0; k0 < D_; k0 += 32) {
      s8 ach = *(const s8*)&ctxH[col * 136 + k0 + quad * 8];
      s8 acl = *(const s8*)&ctxL[col * 136 + k0 + quad * 8];
      s8 ahh = *(const s8*)&hrowH[col][k0 + quad * 8];
      s8 ahl = *(const s8*)&hrowL[col][k0 + quad * 8];
#pragma unroll
      for (int t = 0; t < 2; t++) {
#pragma unroll
        for (int kd = 0; kd < 3; kd++) {
          int g = ((2 * wv + t) + kd * 8) * 16 + col;
          s8 bi_h = *(const s8*)&wihH[(size_t)g * 128 + k0 + quad * 8];
          s8 bi_l = *(const s8*)&wihL[(size_t)g * 128 + k0 + quad * 8];
          s8 bh_h = *(const s8*)&whhH[(size_t)g * 128 + k0 + quad * 8];
          s8 bh_l = *(const s8*)&whhL[(size_t)g * 128 + k0 + quad * 8];
          gi[t][kd] = __builtin_amdgcn_mfma_f32_16x16x32_bf16(ach, bi_h, gi[t][kd], 0, 0, 0);
          gi[t][kd] = __builtin_amdgcn_mfma_f32_16x16x32_bf16(acl, bi_h, gi[t][kd], 0, 0, 0);
          gi[t][kd] = __builtin_amdgcn_mfma_f32_16x16x32_bf16(ach, bi_l, gi[t][kd], 0, 0, 0);
          gh[t][kd] = __builtin_amdgcn_mfma_f32_16x16x32_bf16(ahh, bh_h, gh[t][kd], 0, 0, 0);
          gh[t][kd] = __builtin_amdgcn_mfma_f32_16x16x32_bf16(ahl, bh_h, gh[t][kd], 0, 0, 0);
          gh[t][kd] = __builtin_amdgcn_mfma_f32_16x16x32_bf16(ahh, bh_l, gh[t][kd], 0, 0, 0);
        }
      }
    }
#pragma unroll
    for (int t = 0; t < 2; t++) {
      int ic = (2 * wv + t) * 16 + col;
      float bi0 = bih[ic], bi1 = bih[D_ + ic], bi2 = bih[2 * D_ + ic];
      float bh0 = bhh[ic], bh1 = bhh[D_ + ic], bh2 = bhh[2 * D_ + ic];
#pragma unroll
      for (int r = 0; r < 4; r++) {
        int a = quad * 4 + r;
        float rr = sigm(gi[t][0][r] + bi0 + gh[t][0][r] + bh0);
        float zz = sigm(gi[t][1][r] + bi1 + gh[t][1][r] + bh1);
        float nn = tanhf(gi[t][2][r] + bi2 + rr * (gh[t][2][r] + bh2));
        float hv = hrowS[a][ic];
        hout[(size_t)(a0 + a) * D_ + ic] = (1.f - zz) * nn + zz * hv;
      }
    }
  }
}

__global__ __launch_bounds__(128) void k_mol(
    const float* __restrict__ hfin,
    float* __restrict__ hcopy,
    const float* __restrict__ amask,
    const float* __restrict__ maw, const float* __restrict__ mab,
    const float* __restrict__ mtw, const float* __restrict__ mtb,
    const float* __restrict__ wih_t, const float* __restrict__ whh_t,  // fp32 j-major [128][384]
    const float* __restrict__ bih, const float* __restrict__ bhh,
    const float* __restrict__ ow, const float* __restrict__ ob,
    float* __restrict__ pred)
{
  int b = blockIdx.x;
  int tid = threadIdx.x;
  __shared__ float actS[L_][D_ + 1];
  __shared__ float red[D_], wgt[L_], ybv[D_], ctx[D_], mfS[D_], amol[D_];
  __shared__ float msk[L_], mawh[D_];

  msk[tid] = amask[b * L_ + tid];
  mawh[tid] = maw[D_ + tid];
  for (int l = 0; l < L_; l++) {
    float hv = hfin[(size_t)(b * L_ + l) * D_ + tid];
    hcopy[(size_t)(b * L_ + l) * D_ + tid] = hv;
    actS[l][tid] = fmaxf(hv, 0.f);
  }
  __syncthreads();

  float mf = 0.f;
  for (int l = 0; l < L_; l++) mf += actS[l][tid] * msk[l];
  mfS[tid] = mf;
  amol[tid] = fmaxf(mf, 0.f);
  __syncthreads();

  float mabv = mab[0];

  for (int t = 0; t < 2; t++) {
    float s0 = blk_sum(amol[tid] * maw[tid], red, tid);

    float sc = s0 + mabv;
    for (int j = 0; j < D_; j++) sc += actS[tid][j] * mawh[j];
    sc = lrelu(sc);
    if (msk[tid] == 0.f) sc += NEGC;

    float mx = blk_max(sc, red, tid);
    float e = expf(sc - mx);
    float es = blk_sum(e, red, tid);
    float w = (e / es) * msk[tid];
    wgt[tid] = w;
    float wsum = blk_sum(w, red, tid);
    __syncthreads();

    float y = 0.f;
    for (int l = 0; l < L_; l++) y += wgt[l] * actS[l][tid];
    ybv[tid] = y;
    __syncthreads();
    float acc = wsum * mtb[tid];
    for (int j = 0; j < D_; j++) acc += ybv[j] * mtw[j * D_ + tid];
    ctx[tid] = eluf(acc);
    __syncthreads();

    float gi0 = bih[tid], gi1 = bih[D_ + tid], gi2 = bih[2 * D_ + tid];
    float gh0 = bhh[tid], gh1 = bhh[D_ + tid], gh2 = bhh[2 * D_ + tid];
#pragma unroll 1
    for (int j = 0; j < D_; j++) {
      const float* wi = wih_t + (size_t)j * 384;
      const float* wh = whh_t + (size_t)j * 384;
      float xc = ctx[j], xh = mfS[j];
      gi0 += xc * wi[tid]; gi1 += xc * wi[D_ + tid]; gi2 += xc * wi[2 * D_ + tid];
      gh0 += xh * wh[tid]; gh1 += xh * wh[D_ + tid]; gh2 += xh * wh[2 * D_ + tid];
    }
    float r = sigm(gi0 + gh0);
    float z = sigm(gi1 + gh1);
    float n = tanhf(gi2 + r * gh2);
    float hn = (1.f - z) * n + z * mfS[tid];
    __syncthreads();
    mfS[tid] = hn;
    amol[tid] = fmaxf(hn, 0.f);
    __syncthreads();
  }

  float p = blk_sum(mfS[tid] * ow[tid], red, tid);
  if (tid == 0) pred[b] = p + ob[0];
}

extern "C" void kernel_launch(void* const* d_in, const int* in_sizes, int n_in,
                              void* d_out, int out_size, void* d_ws, size_t ws_size,
                              hipStream_t stream) {
  const float* atom_list    = (const float*)d_in[0];
  const float* bond_list    = (const float*)d_in[1];
  const float* atom_mask    = (const float*)d_in[2];
  const float* atom_fc_w    = (const float*)d_in[3];
  const float* atom_fc_b    = (const float*)d_in[4];
  const float* nbr_fc_w     = (const float*)d_in[5];
  const float* nbr_fc_b     = (const float*)d_in[6];
  const float* align_w      = (const float*)d_in[7];
  const float* align_b      = (const float*)d_in[8];
  const float* attend_w     = (const float*)d_in[9];
  const float* attend_b     = (const float*)d_in[10];
  const float* gru_wih      = (const float*)d_in[11];
  const float* gru_whh      = (const float*)d_in[12];
  const float* gru_bih      = (const float*)d_in[13];
  const float* gru_bhh      = (const float*)d_in[14];
  const float* mol_align_w  = (const float*)d_in[15];
  const float* mol_align_b  = (const float*)d_in[16];
  const float* mol_attend_w = (const float*)d_in[17];
  const float* mol_attend_b = (const float*)d_in[18];
  const float* mol_gru_wih  = (const float*)d_in[19];
  const float* mol_gru_whh  = (const float*)d_in[20];
  const float* mol_gru_bih  = (const float*)d_in[21];
  const float* mol_gru_bhh  = (const float*)d_in[22];
  const float* out_w        = (const float*)d_in[23];
  const float* out_b        = (const float*)d_in[24];
  const int*   adeg         = (const int*)d_in[25];
  const int*   bdeg         = (const int*)d_in[26];

  const size_t NH = (size_t)B_ * L_ * D_;
  float* hW   = (float*)d_ws;           // 16 MB
  short* wB   = (short*)(hW + NH);      // NB16 shorts = 1.31 MB
  float* molT = (float*)(wB + NB16);    // NMOLF floats = 0.38 MB
  float* hOut = (float*)d_out;
  float* pred = hOut + NH;

  k_tr<<<dim3((NB16 + NMOLF + 255) / 256), dim3(256), 0, stream>>>(
      gru_wih, gru_whh, attend_w, mol_gru_wih, mol_gru_whh, wB, molT);

  dim3 blk(256), grd(B_ * L_ / NA);

  // r0 -> hW ; r1: hW -> hOut ; r2: hOut -> hW
  k_round<1><<<grd, blk, 0, stream>>>(
      nullptr, hW, atom_list, bond_list, adeg, bdeg,
      atom_fc_w, atom_fc_b, nbr_fc_w, nbr_fc_b,
      align_w, align_b, attend_b,
      wB + 0 * (size_t)RND_BLK2, gru_bih, gru_bhh);
  k_round<0><<<grd, blk, 0, stream>>>(
      hW, hOut, atom_list, bond_list, adeg, bdeg,
      atom_fc_w, atom_fc_b, nbr_fc_w, nbr_fc_b,
      align_w + 2 * D_, align_b + 1, attend_b + D_,
      wB + 1 * (size_t)RND_BLK2, gru_bih + 3 * D_, gru_bhh + 3 * D_);
  k_round<0><<<grd, blk, 0, stream>>>(
      hOut, hW, atom_list, bond_list, adeg, bdeg,
      atom_fc_w, atom_fc_b, nbr_fc_w, nbr_fc_b,
      align_w + 4 * D_, align_b + 2, attend_b + 2 * D_,
      wB + 2 * (size_t)RND_BLK2, gru_bih + 6 * D_, gru_bhh + 6 * D_);

  k_mol<<<dim3(B_), dim3(128), 0, stream>>>(
      hW, hOut, atom_mask, mol_align_w, mol_align_b, mol_attend_w, mol_attend_b,
      molT, molT + 128 * 384,
      mol_gru_bih, mol_gru_bhh, out_w, out_b, pred);
}

// Round 8
// 701.490 us; speedup vs baseline: 17.6295x; 1.1395x over previous
//
#include <hip/hip_runtime.h>
#include <cstddef>

// AttentiveFP forward. B=256 L=128 K=6 FA=39 FB=10 D=128 R=3 T=2. fp32 I/O.
// k_round: MFMA bf16 split precision (hi+lo) for ctx/GRU GEMMs.
// Rounds>=1: attention score dots precomputed per-atom in previous round's
// epilogue (P=relu(h).awlo, Q=relu(h).awhi, gathered as scalars), and ybar
// computed directly from global fp32 h (no bf16 nbr staging, no nbrS LDS).
// ws: h fp32 16MB + split bf16 weights 1.31MB + fp32 molT 0.38MB + P,Q 256KB.

#define B_ 256
#define L_ 128
#define K_ 6
#define FA_ 39
#define FB_ 10
#define D_ 128
#define PAD_ 127
#define NEGC (-9.0e8f)
#define NA 16
#define NPAIR (NA * K_)   // 96

typedef unsigned short u16;
typedef unsigned int u32;
using s8 = __attribute__((ext_vector_type(8))) short;   // 8 x bf16
using f4 = __attribute__((ext_vector_type(4))) float;   // MFMA acc

#define WIH_H 0
#define WIH_L 49152
#define WHH_H 98304
#define WHH_L 147456
#define TW_H  196608
#define TW_L  212992
#define RND_BLK2 229376
#define NB16 (3 * RND_BLK2)
#define NMOLF (2 * 128 * 384)

__device__ __forceinline__ float lrelu(float x) { return x > 0.f ? x : 0.01f * x; }
__device__ __forceinline__ float eluf(float x)  { return x > 0.f ? x : expm1f(x); }
__device__ __forceinline__ float sigm(float x)  { return 1.f / (1.f + expf(-x)); }
__device__ __forceinline__ float b2f(u16 u) {
  union { u32 i; float f; } v; v.i = ((u32)u) << 16; return v.f;
}
__device__ __forceinline__ short f2b(float f) {  // RNE
  union { float f; u32 i; } v; v.f = f;
  u32 x = v.i;
  return (short)(u16)((x + 0x7FFFu + ((x >> 16) & 1u)) >> 16);
}

__device__ __forceinline__ float blk_sum(float v, float* red, int tid) {
  red[tid] = v; __syncthreads();
  for (int s = 64; s > 0; s >>= 1) {
    if (tid < s) red[tid] += red[tid + s];
    __syncthreads();
  }
  float r = red[0]; __syncthreads();
  return r;
}
__device__ __forceinline__ float blk_max(float v, float* red, int tid) {
  red[tid] = v; __syncthreads();
  for (int s = 64; s > 0; s >>= 1) {
    if (tid < s) red[tid] = fmaxf(red[tid], red[tid + s]);
    __syncthreads();
  }
  float r = red[0]; __syncthreads();
  return r;
}

// Build split bf16 weights + fp32 transposed mol GRU weights.
__global__ __launch_bounds__(256) void k_tr(
    const float* __restrict__ gwih, const float* __restrict__ gwhh,
    const float* __restrict__ attw,
    const float* __restrict__ mwih, const float* __restrict__ mwhh,
    short* __restrict__ wB, float* __restrict__ molT) {
  int idx = blockIdx.x * 256 + threadIdx.x;
  if (idx < NB16) {
    int r = idx / RND_BLK2, o = idx % RND_BLK2;
    float v; int lo;
    if (o < 98304) {
      lo = o / 49152; int e = o % 49152;
      v = gwih[(size_t)r * 49152 + e];
    } else if (o < 196608) {
      int o2 = o - 98304;
      lo = o2 / 49152; int e = o2 % 49152;
      v = gwhh[(size_t)r * 49152 + e];
    } else {
      int o2 = o - 196608;
      lo = o2 / 16384; int e = o2 % 16384;
      int g = e / 128, k = e % 128;
      v = attw[(size_t)r * 16384 + k * 128 + g];
    }
    short hi = f2b(v);
    wB[idx] = lo ? f2b(v - b2f((u16)hi)) : hi;
  } else if (idx < NB16 + NMOLF) {
    int e2 = idx - NB16;
    int m = e2 / 49152, e = e2 % 49152, j = e / 384, g = e % 384;
    molT[e2] = (m ? mwhh : mwih)[g * 128 + j];
  }
}

template <int FIRST>
__global__ __launch_bounds__(256, 4) void k_round(
    const float* __restrict__ hin,
    float* __restrict__ hout,
    const float* __restrict__ atom_list,
    const float* __restrict__ bond_list,
    const int* __restrict__ adeg,
    const int* __restrict__ bdeg,
    const float* __restrict__ afc_w, const float* __restrict__ afc_b,
    const float* __restrict__ nbr_w, const float* __restrict__ nbr_b,
    const float* __restrict__ aw,    // this round's align_w (FIRST only)
    const float* __restrict__ ab,
    const float* __restrict__ awN,   // NEXT round's align_w (for P/Q epilogue)
    const float* __restrict__ tb,
    const short* __restrict__ wR,
    const float* __restrict__ bih, const float* __restrict__ bhh,
    float* __restrict__ Pg, float* __restrict__ Qg)
{
  int tid  = threadIdx.x;
  int t128 = tid & 127;
  int hf   = tid >> 7;
  int lane = tid & 63;
  int wv   = tid >> 6;
  int quad = lane >> 4;
  int col  = lane & 15;
  int a0   = blockIdx.x * NA;
  int bb   = a0 >> 7;

  const short* wihH = wR + WIH_H;
  const short* wihL = wR + WIH_L;
  const short* whhH = wR + WHH_H;
  const short* whhL = wR + WHH_L;
  const short* twH  = wR + TW_H;
  const short* twL  = wR + TW_L;

  __shared__ short nbrS[FIRST ? NPAIR : 1][136];   // FIRST only
  __shared__ short hrowH[NA][136];
  __shared__ short hrowL[NA][136];
  __shared__ __align__(16) char arena[9472];       // ybar/ctx | xst | hnrelu
  __shared__ float awS[FIRST ? 256 : 1];
  __shared__ float awNS[256];
  __shared__ float partials[256];
  __shared__ float pS[NA], qS[NPAIR], wkS[NPAIR], wsS[NA];
  __shared__ int aidxS[NPAIR];
  __shared__ int bidxS[FIRST ? NPAIR : 1];

  short* ybarH = (short*)arena;               // [16][136] (ctx reuses)
  short* ybarL = (short*)(arena + 4352);
  float* xst   = (float*)arena;               // FIRST staging
  float* hnrel = (float*)arena;               // epilogue relu(hn) [16][132]

  if (tid < NPAIR) {
    int av = adeg[a0 * K_ + tid];
    aidxS[tid] = av;
    if (FIRST) bidxS[tid] = bdeg[a0 * K_ + tid];
    else       qS[tid] = Qg[bb * L_ + av];        // gather precomputed dot
  } else if (!FIRST && tid >= 128 && tid < 128 + NA) {
    pS[tid - 128] = Pg[a0 + (tid - 128)];
  }
  if (FIRST) awS[tid] = aw[tid];
  awNS[tid] = awN[tid];
  __syncthreads();

  // ---------- Phase 1: h rows (+ FIRST: nbr features) ----------
  if (FIRST) {
    for (int hp = 0; hp < 3; hp++) {
      for (int i = tid; i < 32 * 52; i += 256) {
        int r = i / 52, c = i % 52, p = hp * 32 + r;
        xst[i] = (c < FA_)
            ? atom_list[((size_t)bb * L_ + aidxS[p]) * FA_ + c]
            : bond_list[((size_t)bb * L_ + bidxS[p]) * FB_ + (c - FA_)];
      }
      if (hp == 0) {
        for (int i = tid; i < NA * 40; i += 256) {
          int a = i / 40, c = i % 40;
          xst[1664 + i] = (c < FA_) ? atom_list[((size_t)(a0 + a)) * FA_ + c] : 0.f;
        }
      }
      __syncthreads();
      for (int ch = hf * 2; ch < hf * 2 + 2; ch++) {
        float acc[8];
        float bv = nbr_b[t128];
#pragma unroll
        for (int q = 0; q < 8; q++) acc[q] = bv;
#pragma unroll 2
        for (int j = 0; j < FA_ + FB_; j++) {
          float w = nbr_w[j * D_ + t128];
#pragma unroll
          for (int q = 0; q < 8; q++) acc[q] += xst[(ch * 8 + q) * 52 + j] * w;
        }
#pragma unroll
        for (int q = 0; q < 8; q++)
          nbrS[hp * 32 + ch * 8 + q][t128] = f2b(lrelu(acc[q]));
      }
      __syncthreads();
    }
    {
      float acc[8];
      float bv = afc_b[t128];
#pragma unroll
      for (int i = 0; i < 8; i++) acc[i] = bv;
#pragma unroll 2
      for (int j = 0; j < FA_; j++) {
        float w = afc_w[j * D_ + t128];
#pragma unroll
        for (int i = 0; i < 8; i++) acc[i] += xst[1664 + (hf * 8 + i) * 40 + j] * w;
      }
#pragma unroll
      for (int i = 0; i < 8; i++) {
        int a = hf * 8 + i;
        float hv = lrelu(acc[i]);
        short hh = f2b(hv);
        hrowH[a][t128] = hh;
        hrowL[a][t128] = f2b(hv - b2f((u16)hh));
      }
    }
    __syncthreads();
  } else {
#pragma unroll 4
    for (int i = 0; i < 8; i++) {
      int a = i * 2 + hf;
      float hv = hin[(size_t)(a0 + a) * D_ + t128];
      short hh = f2b(hv);
      hrowH[a][t128] = hh;
      hrowL[a][t128] = f2b(hv - b2f((u16)hh));
    }
    __syncthreads();
  }

  // ---------- Phase 2 (FIRST only): score dots from staged features ----------
  if (FIRST) {
    if (tid < NPAIR) {
      float s = 0.f;
      for (int j = 0; j < D_; j++) s += b2f((u16)nbrS[tid][j]) * awS[D_ + j];
      qS[tid] = s;
    } else if (tid >= 128 && tid < 128 + NA) {
      int a = tid - 128;
      float s = 0.f;
      for (int j = 0; j < D_; j++) {
        float v = b2f((u16)hrowH[a][j]) + b2f((u16)hrowL[a][j]);
        s += v * awS[j];
      }
      pS[a] = s;
    }
    __syncthreads();
  }

  // ---------- Phase 3: softmax over K ----------
  if (tid < NA) {
    int a = tid;
    float abv = ab[0];
    float sc[K_];
    float m = -3.0e38f;
#pragma unroll
    for (int k = 0; k < K_; k++) {
      float s = lrelu(pS[a] + qS[a * K_ + k] + abv);
      if (aidxS[a * K_ + k] == PAD_) s += NEGC;
      sc[k] = s; m = fmaxf(m, s);
    }
    float es = 0.f;
#pragma unroll
    for (int k = 0; k < K_; k++) { sc[k] = expf(sc[k] - m); es += sc[k]; }
    float ws = 0.f;
#pragma unroll
    for (int k = 0; k < K_; k++) {
      float w = (aidxS[a * K_ + k] == PAD_) ? 0.f : sc[k] / es;
      wkS[a * K_ + k] = w; ws += w;
    }
    wsS[a] = ws;
  }
  __syncthreads();

  // ---------- Phase 4: ybar hi/lo ----------
  if (FIRST) {
#pragma unroll 2
    for (int i = 0; i < 8; i++) {
      int a = hf * 8 + i;
      float yb = 0.f;
#pragma unroll
      for (int k = 0; k < K_; k++)
        yb += wkS[a * K_ + k] * b2f((u16)nbrS[a * K_ + k][t128]);
      short yh = f2b(yb);
      ybarH[a * 136 + t128] = yh;
      ybarL[a * 136 + t128] = f2b(yb - b2f((u16)yh));
    }
  } else {
    // direct from global fp32 h: nbr_k = relu(h[aidx])
#pragma unroll 2
    for (int i = 0; i < 8; i++) {
      int a = hf * 8 + i;
      float yb = 0.f;
#pragma unroll
      for (int k = 0; k < K_; k++) {
        float v = hin[((size_t)bb * L_ + aidxS[a * K_ + k]) * D_ + t128];
        yb += wkS[a * K_ + k] * fmaxf(v, 0.f);
      }
      short yh = f2b(yb);
      ybarH[a * 136 + t128] = yh;
      ybarL[a * 136 + t128] = f2b(yb - b2f((u16)yh));
    }
  }
  __syncthreads();

  // ---------- Phase 5: ctx = elu(ybar @ twT^T + wsum*tb), split MFMA ----------
  {
    f4 c2[2] = {};
#pragma unroll
    for (int k0 = 0; k0 < D_; k0 += 32) {
      s8 ayh = *(const s8*)&ybarH[col * 136 + k0 + quad * 8];
      s8 ayl = *(const s8*)&ybarL[col * 136 + k0 + quad * 8];
#pragma unroll
      for (int t = 0; t < 2; t++) {
        int g = (2 * wv + t) * 16 + col;
        s8 bwh = *(const s8*)&twH[(size_t)g * 128 + k0 + quad * 8];
        s8 bwl = *(const s8*)&twL[(size_t)g * 128 + k0 + quad * 8];
        c2[t] = __builtin_amdgcn_mfma_f32_16x16x32_bf16(ayh, bwh, c2[t], 0, 0, 0);
        c2[t] = __builtin_amdgcn_mfma_f32_16x16x32_bf16(ayl, bwh, c2[t], 0, 0, 0);
        c2[t] = __builtin_amdgcn_mfma_f32_16x16x32_bf16(ayh, bwl, c2[t], 0, 0, 0);
      }
    }
    __syncthreads();   // all waves done reading ybar; reuse buffers for ctx
#pragma unroll
    for (int t = 0; t < 2; t++) {
      int g = (2 * wv + t) * 16 + col;
      float tbv = tb[g];
#pragma unroll
      for (int r = 0; r < 4; r++) {
        int a = quad * 4 + r;
        float c = eluf(c2[t][r] + wsS[a] * tbv);
        short chs = f2b(c);
        ybarH[a * 136 + g] = chs;                   // ctxH
        ybarL[a * 136 + g] = f2b(c - b2f((u16)chs)); // ctxL
      }
    }
  }
  __syncthreads();

  // ---------- Phase 6: GRU via split MFMA ----------
  {
    const short* ctxH = ybarH;
    const short* ctxL = ybarL;
    f4 gi[2][3] = {}, gh[2][3] = {};
#pragma unroll
    for (int k0 = 0; k0 < D_; k0 += 32) {
      s8 ach = *(const s8*)&ctxH[col * 136 + k0 + quad * 8];
      s8 acl = *(const s8*)&ctxL[col * 136 + k0 + quad * 8];
      s8 ahh = *(const s8*)&hrowH[col][k0 + quad * 8];
      s8 ahl = *(const s8*)&hrowL[col][k0 + quad * 8];
#pragma unroll
      for (int t = 0; t < 2; t++) {
#pragma unroll
        for (int kd = 0; kd < 3; kd++) {
          int g = ((2 * wv + t) + kd * 8) * 16 + col;
          s8 bi_h = *(const s8*)&wihH[(size_t)g * 128 + k0 + quad * 8];
          s8 bi_l = *(const s8*)&wihL[(size_t)g * 128 + k0 + quad * 8];
          s8 bh_h = *(const s8*)&whhH[(size_t)g * 128 + k0 + quad * 8];
          s8 bh_l = *(const s8*)&whhL[(size_t)g * 128 + k0 + quad * 8];
          gi[t][kd] = __builtin_amdgcn_mfma_f32_16x16x32_bf16(ach, bi_h, gi[t][kd], 0, 0, 0);
          gi[t][kd] = __builtin_amdgcn_mfma_f32_16x16x32_bf16(acl, bi_h, gi[t][kd], 0, 0, 0);
          gi[t][kd] = __builtin_amdgcn_mfma_f32_16x16x32_bf16(ach, bi_l, gi[t][kd], 0, 0, 0);
          gh[t][kd] = __builtin_amdgcn_mfma_f32_16x16x32_bf16(ahh, bh_h, gh[t][kd], 0, 0, 0);
          gh[t][kd] = __builtin_amdgcn_mfma_f32_16x16x32_bf16(ahl, bh_h, gh[t][kd], 0, 0, 0);
          gh[t][kd] = __builtin_amdgcn_mfma_f32_16x16x32_bf16(ahh, bh_l, gh[t][kd], 0, 0, 0);
        }
      }
    }
    __syncthreads();   // all MFMA LDS reads done; arena will be reused

#pragma unroll
    for (int t = 0; t < 2; t++) {
      int ic = (2 * wv + t) * 16 + col;
      float bi0 = bih[ic], bi1 = bih[D_ + ic], bi2 = bih[2 * D_ + ic];
      float bh0 = bhh[ic], bh1 = bhh[D_ + ic], bh2 = bhh[2 * D_ + ic];
#pragma unroll
      for (int r = 0; r < 4; r++) {
        int a = quad * 4 + r;
        float rr = sigm(gi[t][0][r] + bi0 + gh[t][0][r] + bh0);
        float zz = sigm(gi[t][1][r] + bi1 + gh[t][1][r] + bh1);
        float nn = tanhf(gi[t][2][r] + bi2 + rr * (gh[t][2][r] + bh2));
        float hv = b2f((u16)hrowH[a][ic]) + b2f((u16)hrowL[a][ic]);
        float hn = (1.f - zz) * nn + zz * hv;
        hout[(size_t)(a0 + a) * D_ + ic] = hn;
        hnrel[a * 132 + ic] = fmaxf(hn, 0.f);
      }
    }
  }
  __syncthreads();

  // ---------- Epilogue: P/Q for next round ----------
  {
    int a = tid >> 4, dt = (tid >> 3) & 1, seg = tid & 7;
    float s = 0.f;
#pragma unroll
    for (int j = 0; j < 16; j++)
      s += hnrel[a * 132 + seg * 16 + j] * awNS[dt * 128 + seg * 16 + j];
    partials[tid] = s;
  }
  __syncthreads();
  if (tid < 32) {
    int a = tid >> 1, dt = tid & 1;
    float s = 0.f;
#pragma unroll
    for (int seg = 0; seg < 8; seg++) s += partials[a * 16 + dt * 8 + seg];
    if (dt) Qg[a0 + a] = s; else Pg[a0 + a] = s;
  }
}

__global__ __launch_bounds__(128) void k_mol(
    const float* __restrict__ hfin,
    float* __restrict__ hcopy,
    const float* __restrict__ amask,
    const float* __restrict__ maw, const float* __restrict__ mab,
    const float* __restrict__ mtw, const float* __restrict__ mtb,
    const float* __restrict__ wih_t, const float* __restrict__ whh_t,
    const float* __restrict__ bih, const float* __restrict__ bhh,
    const float* __restrict__ ow, const float* __restrict__ ob,
    float* __restrict__ pred)
{
  int b = blockIdx.x;
  int tid = threadIdx.x;
  __shared__ float actS[L_][D_ + 1];
  __shared__ float red[D_], wgt[L_], ybv[D_], ctx[D_], mfS[D_], amol[D_];
  __shared__ float msk[L_], mawh[D_];

  msk[tid] = amask[b * L_ + tid];
  mawh[tid] = maw[D_ + tid];
  for (int l = 0; l < L_; l++) {
    float hv = hfin[(size_t)(b * L_ + l) * D_ + tid];
    hcopy[(size_t)(b * L_ + l) * D_ + tid] = hv;
    actS[l][tid] = fmaxf(hv, 0.f);
  }
  __syncthreads();

  float mf = 0.f;
  for (int l = 0; l < L_; l++) mf += actS[l][tid] * msk[l];
  mfS[tid] = mf;
  amol[tid] = fmaxf(mf, 0.f);
  __syncthreads();

  float mabv = mab[0];

  for (int t = 0; t < 2; t++) {
    float s0 = blk_sum(amol[tid] * maw[tid], red, tid);

    float sc = s0 + mabv;
    for (int j = 0; j < D_; j++) sc += actS[tid][j] * mawh[j];
    sc = lrelu(sc);
    if (msk[tid] == 0.f) sc += NEGC;

    float mx = blk_max(sc, red, tid);
    float e = expf(sc - mx);
    float es = blk_sum(e, red, tid);
    float w = (e / es) * msk[tid];
    wgt[tid] = w;
    float wsum = blk_sum(w, red, tid);
    __syncthreads();

    float y = 0.f;
    for (int l = 0; l < L_; l++) y += wgt[l] * actS[l][tid];
    ybv[tid] = y;
    __syncthreads();
    float acc = wsum * mtb[tid];
    for (int j = 0; j < D_; j++) acc += ybv[j] * mtw[j * D_ + tid];
    ctx[tid] = eluf(acc);
    __syncthreads();

    float gi0 = bih[tid], gi1 = bih[D_ + tid], gi2 = bih[2 * D_ + tid];
    float gh0 = bhh[tid], gh1 = bhh[D_ + tid], gh2 = bhh[2 * D_ + tid];
#pragma unroll 2
    for (int j = 0; j < D_; j++) {
      const float* wi = wih_t + (size_t)j * 384;
      const float* wh = whh_t + (size_t)j * 384;
      float xc = ctx[j], xh = mfS[j];
      gi0 += xc * wi[tid]; gi1 += xc * wi[D_ + tid]; gi2 += xc * wi[2 * D_ + tid];
      gh0 += xh * wh[tid]; gh1 += xh * wh[D_ + tid]; gh2 += xh * wh[2 * D_ + tid];
    }
    float r = sigm(gi0 + gh0);
    float z = sigm(gi1 + gh1);
    float n = tanhf(gi2 + r * gh2);
    float hn = (1.f - z) * n + z * mfS[tid];
    __syncthreads();
    mfS[tid] = hn;
    amol[tid] = fmaxf(hn, 0.f);
    __syncthreads();
  }

  float p = blk_sum(mfS[tid] * ow[tid], red, tid);
  if (tid == 0) pred[b] = p + ob[0];
}

extern "C" void kernel_launch(void* const* d_in, const int* in_sizes, int n_in,
                              void* d_out, int out_size, void* d_ws, size_t ws_size,
                              hipStream_t stream) {
  const float* atom_list    = (const float*)d_in[0];
  const float* bond_list    = (const float*)d_in[1];
  const float* atom_mask    = (const float*)d_in[2];
  const float* atom_fc_w    = (const float*)d_in[3];
  const float* atom_fc_b    = (const float*)d_in[4];
  const float* nbr_fc_w     = (const float*)d_in[5];
  const float* nbr_fc_b     = (const float*)d_in[6];
  const float* align_w      = (const float*)d_in[7];
  const float* align_b      = (const float*)d_in[8];
  const float* attend_w     = (const float*)d_in[9];
  const float* attend_b     = (const float*)d_in[10];
  const float* gru_wih      = (const float*)d_in[11];
  const float* gru_whh      = (const float*)d_in[12];
  const float* gru_bih      = (const float*)d_in[13];
  const float* gru_bhh      = (const float*)d_in[14];
  const float* mol_align_w  = (const float*)d_in[15];
  const float* mol_align_b  = (const float*)d_in[16];
  const float* mol_attend_w = (const float*)d_in[17];
  const float* mol_attend_b = (const float*)d_in[18];
  const float* mol_gru_wih  = (const float*)d_in[19];
  const float* mol_gru_whh  = (const float*)d_in[20];
  const float* mol_gru_bih  = (const float*)d_in[21];
  const float* mol_gru_bhh  = (const float*)d_in[22];
  const float* out_w        = (const float*)d_in[23];
  const float* out_b        = (const float*)d_in[24];
  const int*   adeg         = (const int*)d_in[25];
  const int*   bdeg         = (const int*)d_in[26];

  const size_t NH = (size_t)B_ * L_ * D_;
  float* hW   = (float*)d_ws;            // 16 MB
  short* wB   = (short*)(hW + NH);       // 1.31 MB
  float* molT = (float*)(wB + NB16);     // 0.38 MB
  float* Pg   = molT + NMOLF;            // 128 KB
  float* Qg   = Pg + NH / D_;            // 128 KB
  float* hOut = (float*)d_out;
  float* pred = hOut + NH;

  k_tr<<<dim3((NB16 + NMOLF + 255) / 256), dim3(256), 0, stream>>>(
      gru_wih, gru_whh, attend_w, mol_gru_wih, mol_gru_whh, wB, molT);

  dim3 blk(256), grd(B_ * L_ / NA);

  // r0 -> hW ; r1: hW -> hOut ; r2: hOut -> hW
  k_round<1><<<grd, blk, 0, stream>>>(
      nullptr, hW, atom_list, bond_list, adeg, bdeg,
      atom_fc_w, atom_fc_b, nbr_fc_w, nbr_fc_b,
      align_w, align_b, align_w + 2 * D_, attend_b,
      wB + 0 * (size_t)RND_BLK2, gru_bih, gru_bhh, Pg, Qg);
  k_round<0><<<grd, blk, 0, stream>>>(
      hW, hOut, atom_list, bond_list, adeg, bdeg,
      atom_fc_w, atom_fc_b, nbr_fc_w, nbr_fc_b,
      align_w + 2 * D_, align_b + 1, align_w + 4 * D_, attend_b + D_,
      wB + 1 * (size_t)RND_BLK2, gru_bih + 3 * D_, gru_bhh + 3 * D_, Pg, Qg);
  k_round<0><<<grd, blk, 0, stream>>>(
      hOut, hW, atom_list, bond_list, adeg, bdeg,
      atom_fc_w, atom_fc_b, nbr_fc_w, nbr_fc_b,
      align_w + 4 * D_, align_b + 2, align_w + 4 * D_, attend_b + 2 * D_,
      wB + 2 * (size_t)RND_BLK2, gru_bih + 6 * D_, gru_bhh + 6 * D_, Pg, Qg);

  k_mol<<<dim3(B_), dim3(128), 0, stream>>>(
      hW, hOut, atom_mask, mol_align_w, mol_align_b, mol_attend_w, mol_attend_b,
      molT, molT + 128 * 384,
      mol_gru_bih, mol_gru_bhh, out_w, out_b, pred);
}

// Round 9
// 579.463 us; speedup vs baseline: 21.3420x; 1.2106x over previous
//
#include <hip/hip_runtime.h>
#include <cstddef>

// AttentiveFP forward. B=256 L=128 K=6 FA=39 FB=10 D=128 R=3 T=2. fp32 I/O.
// MFMA bf16 split precision (hi+lo) for ctx/GRU GEMMs; h carried fp32.
// Round-0 specials hoisted out: k_pre (h0, AP=atom@Wa bf16, P0), k_q0 (per-pair Q0).
// k_round unified for all rounds; P/Q score dots precomputed (prev epilogue or
// k_pre/k_q0), double-buffered A/B (race-free). ws ~27.5 MB.

#define B_ 256
#define L_ 128
#define K_ 6
#define FA_ 39
#define FB_ 10
#define D_ 128
#define PAD_ 127
#define NEGC (-9.0e8f)
#define NA 16
#define NPAIR (NA * K_)   // 96

typedef unsigned short u16;
typedef unsigned int u32;
using s8 = __attribute__((ext_vector_type(8))) short;   // 8 x bf16
using f4 = __attribute__((ext_vector_type(4))) float;   // MFMA acc

#define WIH_H 0
#define WIH_L 49152
#define WHH_H 98304
#define WHH_L 147456
#define TW_H  196608
#define TW_L  212992
#define RND_BLK2 229376
#define NB16 (3 * RND_BLK2)
#define NMOLF (2 * 128 * 384)

__device__ __forceinline__ float lrelu(float x) { return x > 0.f ? x : 0.01f * x; }
__device__ __forceinline__ float eluf(float x)  { return x > 0.f ? x : expm1f(x); }
__device__ __forceinline__ float sigm(float x)  { return 1.f / (1.f + expf(-x)); }
__device__ __forceinline__ float b2f(u16 u) {
  union { u32 i; float f; } v; v.i = ((u32)u) << 16; return v.f;
}
__device__ __forceinline__ short f2b(float f) {  // RNE
  union { float f; u32 i; } v; v.f = f;
  u32 x = v.i;
  return (short)(u16)((x + 0x7FFFu + ((x >> 16) & 1u)) >> 16);
}

__device__ __forceinline__ float blk_sum(float v, float* red, int tid) {
  red[tid] = v; __syncthreads();
  for (int s = 64; s > 0; s >>= 1) {
    if (tid < s) red[tid] += red[tid + s];
    __syncthreads();
  }
  float r = red[0]; __syncthreads();
  return r;
}
__device__ __forceinline__ float blk_max(float v, float* red, int tid) {
  red[tid] = v; __syncthreads();
  for (int s = 64; s > 0; s >>= 1) {
    if (tid < s) red[tid] = fmaxf(red[tid], red[tid + s]);
    __syncthreads();
  }
  float r = red[0]; __syncthreads();
  return r;
}

// Build split bf16 weights + fp32 transposed mol GRU weights.
__global__ __launch_bounds__(256) void k_tr(
    const float* __restrict__ gwih, const float* __restrict__ gwhh,
    const float* __restrict__ attw,
    const float* __restrict__ mwih, const float* __restrict__ mwhh,
    short* __restrict__ wB, float* __restrict__ molT) {
  int idx = blockIdx.x * 256 + threadIdx.x;
  if (idx < NB16) {
    int r = idx / RND_BLK2, o = idx % RND_BLK2;
    float v; int lo;
    if (o < 98304) {
      lo = o / 49152; int e = o % 49152;
      v = gwih[(size_t)r * 49152 + e];
    } else if (o < 196608) {
      int o2 = o - 98304;
      lo = o2 / 49152; int e = o2 % 49152;
      v = gwhh[(size_t)r * 49152 + e];
    } else {
      int o2 = o - 196608;
      lo = o2 / 16384; int e = o2 % 16384;
      int g = e / 128, k = e % 128;
      v = attw[(size_t)r * 16384 + k * 128 + g];
    }
    short hi = f2b(v);
    wB[idx] = lo ? f2b(v - b2f((u16)hi)) : hi;
  } else if (idx < NB16 + NMOLF) {
    int e2 = idx - NB16;
    int m = e2 / 49152, e = e2 % 49152, j = e / 384, g = e % 384;
    molT[e2] = (m ? mwhh : mwih)[g * 128 + j];
  }
}

// Per-atom precompute: h0 = lrelu(atom@afc_w+b) -> h0out; AP = atom@Wa (bf16);
// P0 = h0 . awlo0.  16 atoms/block, 128 threads, 2048 blocks.
__global__ __launch_bounds__(128) void k_pre(
    const float* __restrict__ atom_list,
    const float* __restrict__ afc_w, const float* __restrict__ afc_b,
    const float* __restrict__ nbr_w,
    const float* __restrict__ aw0,
    float* __restrict__ h0out, short* __restrict__ APg, float* __restrict__ PgA)
{
  int tid = threadIdx.x;
  int a0 = blockIdx.x * 16;
  __shared__ float xa[16 * 40];
  __shared__ float h0S[16][132];
  __shared__ float awS[128];
  __shared__ float partials[128];

  for (int i = tid; i < 16 * FA_; i += 128) {
    int a = i / FA_, c = i % FA_;
    xa[a * 40 + c] = atom_list[((size_t)(a0 + a)) * FA_ + c];
  }
  awS[tid] = aw0[tid];
  __syncthreads();

  {
    float acc[16];
    float bv = afc_b[tid];
#pragma unroll
    for (int a = 0; a < 16; a++) acc[a] = bv;
#pragma unroll 2
    for (int j = 0; j < FA_; j++) {
      float w = afc_w[j * D_ + tid];
#pragma unroll
      for (int a = 0; a < 16; a++) acc[a] += xa[a * 40 + j] * w;
    }
#pragma unroll
    for (int a = 0; a < 16; a++) {
      float hv = lrelu(acc[a]);
      h0out[(size_t)(a0 + a) * D_ + tid] = hv;
      h0S[a][tid] = hv;
    }
  }
  {
    float acc[16];
#pragma unroll
    for (int a = 0; a < 16; a++) acc[a] = 0.f;
#pragma unroll 2
    for (int j = 0; j < FA_; j++) {
      float w = nbr_w[j * D_ + tid];
#pragma unroll
      for (int a = 0; a < 16; a++) acc[a] += xa[a * 40 + j] * w;
    }
#pragma unroll
    for (int a = 0; a < 16; a++)
      APg[(size_t)(a0 + a) * D_ + tid] = f2b(acc[a]);
  }
  __syncthreads();
  {
    int a = tid >> 3, seg = tid & 7;
    float s = 0.f;
#pragma unroll
    for (int j = 0; j < 16; j++) s += h0S[a][seg * 16 + j] * awS[seg * 16 + j];
    partials[tid] = s;
  }
  __syncthreads();
  if (tid < 16) {
    float s = 0.f;
#pragma unroll
    for (int g = 0; g < 8; g++) s += partials[tid * 8 + g];
    PgA[a0 + tid] = s;
  }
}

// Per-pair Q0 = sum_d lrelu(AP[aidx]+bond[bidx]@Wb+nb) * awhi0.
// 64 pairs/block x 4 threads, 3072 blocks.
__global__ __launch_bounds__(256) void k_q0(
    const float* __restrict__ bond_list,
    const float* __restrict__ nbr_w, const float* __restrict__ nbr_b,
    const float* __restrict__ aw0,
    const int* __restrict__ adeg, const int* __restrict__ bdeg,
    const short* __restrict__ APg, float* __restrict__ Q0g)
{
  int tid = threadIdx.x;
  __shared__ float WbS[10 * 128];
  __shared__ float nbS[128], ahS[128];
  for (int i = tid; i < 10 * 128; i += 256)
    WbS[i] = nbr_w[(FA_ + i / 128) * D_ + (i % 128)];
  if (tid < 128) { nbS[tid] = nbr_b[tid]; ahS[tid] = aw0[D_ + tid]; }
  __syncthreads();

  int p = blockIdx.x * 64 + (tid >> 2);
  int seg = tid & 3;
  int aidx = adeg[p], bidx = bdeg[p];
  int bb = p / (L_ * K_);
  const short* rowA = APg + ((size_t)bb * L_ + aidx) * D_;
  const float* brow = bond_list + ((size_t)bb * L_ + bidx) * FB_;
  float bnd[10];
#pragma unroll
  for (int m = 0; m < 10; m++) bnd[m] = brow[m];
  float s = 0.f;
  int j0 = seg * 32;
#pragma unroll 4
  for (int j = j0; j < j0 + 32; j++) {
    float v = b2f((u16)rowA[j]) + nbS[j];
#pragma unroll
    for (int m = 0; m < 10; m++) v += bnd[m] * WbS[m * 128 + j];
    s += lrelu(v) * ahS[j];
  }
  s += __shfl_xor(s, 1, 64);
  s += __shfl_xor(s, 2, 64);
  if (seg == 0) Q0g[p] = s;
}

template <int FIRST>
__global__ __launch_bounds__(256, 4) void k_round(
    const float* __restrict__ hin,
    float* __restrict__ hout,
    const float* __restrict__ bond_list,
    const int* __restrict__ adeg, const int* __restrict__ bdeg,
    const float* __restrict__ nbr_w, const float* __restrict__ nbr_b,
    const short* __restrict__ APg,
    const float* __restrict__ ab,
    const float* __restrict__ awN,   // NEXT round's align_w (for P/Q epilogue)
    const float* __restrict__ tb,
    const short* __restrict__ wR,
    const float* __restrict__ bih, const float* __restrict__ bhh,
    const float* __restrict__ Pr, const float* __restrict__ Qr,
    float* __restrict__ Pw, float* __restrict__ Qw)
{
  int tid  = threadIdx.x;
  int t128 = tid & 127;
  int hf   = tid >> 7;
  int lane = tid & 63;
  int wv   = tid >> 6;
  int quad = lane >> 4;
  int col  = lane & 15;
  int a0   = blockIdx.x * NA;
  int bb   = a0 >> 7;

  const short* wihH = wR + WIH_H;
  const short* wihL = wR + WIH_L;
  const short* whhH = wR + WHH_H;
  const short* whhL = wR + WHH_L;
  const short* twH  = wR + TW_H;
  const short* twL  = wR + TW_L;

  __shared__ short hrowH[NA][136];
  __shared__ short hrowL[NA][136];
  __shared__ __align__(16) char arena[9472];       // ybar/ctx | hnrelu
  __shared__ float awNS[256];
  __shared__ float partials[256];
  __shared__ float pS[NA], qS[NPAIR], wkS[NPAIR], wsS[NA];
  __shared__ int aidxS[NPAIR];
  __shared__ int bidxS[FIRST ? NPAIR : 1];
  __shared__ float bwS[FIRST ? 2368 : 1];          // bond[96][10] | Wb[10][128] | nb[128]

  short* ybarH = (short*)arena;               // [16][136] (ctx reuses)
  short* ybarL = (short*)(arena + 4352);
  float* hnrel = (float*)arena;               // epilogue relu(hn) [16][132]

  if (tid < NPAIR) {
    int av = adeg[a0 * K_ + tid];
    aidxS[tid] = av;
    if (FIRST) { bidxS[tid] = bdeg[a0 * K_ + tid]; qS[tid] = Qr[a0 * K_ + tid]; }
    else       qS[tid] = Qr[bb * L_ + av];
  } else if (tid >= 128 && tid < 128 + NA) {
    pS[tid - 128] = Pr[a0 + (tid - 128)];
  }
  awNS[tid] = awN[tid];
  __syncthreads();

  // ---------- Phase 1: h rows (+ FIRST: bond/Wb staging) ----------
  if (FIRST) {
    for (int i = tid; i < 960; i += 256) {
      int p = i / 10, m = i % 10;
      bwS[p * 10 + m] = bond_list[((size_t)bb * L_ + bidxS[p]) * FB_ + m];
    }
    for (int i = tid; i < 1280; i += 256)
      bwS[960 + i] = nbr_w[(FA_ + i / 128) * D_ + (i % 128)];
    if (tid < 128) bwS[2240 + tid] = nbr_b[tid];
  }
#pragma unroll 4
  for (int i = 0; i < 8; i++) {
    int a = i * 2 + hf;
    float hv = hin[(size_t)(a0 + a) * D_ + t128];
    short hh = f2b(hv);
    hrowH[a][t128] = hh;
    hrowL[a][t128] = f2b(hv - b2f((u16)hh));
  }
  __syncthreads();

  // ---------- Phase 3: softmax over K ----------
  if (tid < NA) {
    int a = tid;
    float abv = ab[0];
    float sc[K_];
    float m = -3.0e38f;
#pragma unroll
    for (int k = 0; k < K_; k++) {
      float s = lrelu(pS[a] + qS[a * K_ + k] + abv);
      if (aidxS[a * K_ + k] == PAD_) s += NEGC;
      sc[k] = s; m = fmaxf(m, s);
    }
    float es = 0.f;
#pragma unroll
    for (int k = 0; k < K_; k++) { sc[k] = expf(sc[k] - m); es += sc[k]; }
    float ws = 0.f;
#pragma unroll
    for (int k = 0; k < K_; k++) {
      float w = (aidxS[a * K_ + k] == PAD_) ? 0.f : sc[k] / es;
      wkS[a * K_ + k] = w; ws += w;
    }
    wsS[a] = ws;
  }
  __syncthreads();

  // ---------- Phase 4: ybar hi/lo ----------
  if (FIRST) {
    const float* bondS = bwS;
    const float* WbS   = bwS + 960;
    const float* nbS   = bwS + 2240;
    float nbv = nbS[t128];
#pragma unroll 2
    for (int i = 0; i < 8; i++) {
      int a = hf * 8 + i;
      float yb = 0.f;
#pragma unroll
      for (int k = 0; k < K_; k++) {
        int p = a * K_ + k;
        float nf = b2f((u16)APg[((size_t)bb * L_ + aidxS[p]) * D_ + t128]) + nbv;
#pragma unroll
        for (int m = 0; m < 10; m++) nf += bondS[p * 10 + m] * WbS[m * 128 + t128];
        yb += wkS[p] * lrelu(nf);
      }
      short yh = f2b(yb);
      ybarH[a * 136 + t128] = yh;
      ybarL[a * 136 + t128] = f2b(yb - b2f((u16)yh));
    }
  } else {
#pragma unroll 2
    for (int i = 0; i < 8; i++) {
      int a = hf * 8 + i;
      float yb = 0.f;
#pragma unroll
      for (int k = 0; k < K_; k++) {
        float v = hin[((size_t)bb * L_ + aidxS[a * K_ + k]) * D_ + t128];
        yb += wkS[a * K_ + k] * fmaxf(v, 0.f);
      }
      short yh = f2b(yb);
      ybarH[a * 136 + t128] = yh;
      ybarL[a * 136 + t128] = f2b(yb - b2f((u16)yh));
    }
  }
  __syncthreads();

  // ---------- Phase 5: ctx = elu(ybar @ twT^T + wsum*tb), split MFMA ----------
  {
    f4 c2[2] = {};
#pragma unroll
    for (int k0 = 0; k0 < D_; k0 += 32) {
      s8 ayh = *(const s8*)&ybarH[col * 136 + k0 + quad * 8];
      s8 ayl = *(const s8*)&ybarL[col * 136 + k0 + quad * 8];
#pragma unroll
      for (int t = 0; t < 2; t++) {
        int g = (2 * wv + t) * 16 + col;
        s8 bwh = *(const s8*)&twH[(size_t)g * 128 + k0 + quad * 8];
        s8 bwl = *(const s8*)&twL[(size_t)g * 128 + k0 + quad * 8];
        c2[t] = __builtin_amdgcn_mfma_f32_16x16x32_bf16(ayh, bwh, c2[t], 0, 0, 0);
        c2[t] = __builtin_amdgcn_mfma_f32_16x16x32_bf16(ayl, bwh, c2[t], 0, 0, 0);
        c2[t] = __builtin_amdgcn_mfma_f32_16x16x32_bf16(ayh, bwl, c2[t], 0, 0, 0);
      }
    }
    __syncthreads();   // all waves done reading ybar; reuse buffers for ctx
#pragma unroll
    for (int t = 0; t < 2; t++) {
      int g = (2 * wv + t) * 16 + col;
      float tbv = tb[g];
#pragma unroll
      for (int r = 0; r < 4; r++) {
        int a = quad * 4 + r;
        float c = eluf(c2[t][r] + wsS[a] * tbv);
        short chs = f2b(c);
        ybarH[a * 136 + g] = chs;                    // ctxH
        ybarL[a * 136 + g] = f2b(c - b2f((u16)chs)); // ctxL
      }
    }
  }
  __syncthreads();

  // ---------- Phase 6: GRU via split MFMA ----------
  {
    const short* ctxH = ybarH;
    const short* ctxL = ybarL;
    f4 gi[2][3] = {}, gh[2][3] = {};
#pragma unroll
    for (int k0 = 0; k0 < D_; k0 += 32) {
      s8 ach = *(const s8*)&ctxH[col * 136 + k0 + quad * 8];
      s8 acl = *(const s8*)&ctxL[col * 136 + k0 + quad * 8];
      s8 ahh = *(const s8*)&hrowH[col][k0 + quad * 8];
      s8 ahl = *(const s8*)&hrowL[col][k0 + quad * 8];
#pragma unroll
      for (int t = 0; t < 2; t++) {
#pragma unroll
        for (int kd = 0; kd < 3; kd++) {
          int g = ((2 * wv + t) + kd * 8) * 16 + col;
          s8 bi_h = *(const s8*)&wihH[(size_t)g * 128 + k0 + quad * 8];
          s8 bi_l = *(const s8*)&wihL[(size_t)g * 128 + k0 + quad * 8];
          s8 bh_h = *(const s8*)&whhH[(size_t)g * 128 + k0 + quad * 8];
          s8 bh_l = *(const s8*)&whhL[(size_t)g * 128 + k0 + quad * 8];
          gi[t][kd] = __builtin_amdgcn_mfma_f32_16x16x32_bf16(ach, bi_h, gi[t][kd], 0, 0, 0);
          gi[t][kd] = __builtin_amdgcn_mfma_f32_16x16x32_bf16(acl, bi_h, gi[t][kd], 0, 0, 0);
          gi[t][kd] = __builtin_amdgcn_mfma_f32_16x16x32_bf16(ach, bi_l, gi[t][kd], 0, 0, 0);
          gh[t][kd] = __builtin_amdgcn_mfma_f32_16x16x32_bf16(ahh, bh_h, gh[t][kd], 0, 0, 0);
          gh[t][kd] = __builtin_amdgcn_mfma_f32_16x16x32_bf16(ahl, bh_h, gh[t][kd], 0, 0, 0);
          gh[t][kd] = __builtin_amdgcn_mfma_f32_16x16x32_bf16(ahh, bh_l, gh[t][kd], 0, 0, 0);
        }
      }
    }
    __syncthreads();   // all MFMA LDS reads done; arena will be reused

#pragma unroll
    for (int t = 0; t < 2; t++) {
      int ic = (2 * wv + t) * 16 + col;
      float bi0 = bih[ic], bi1 = bih[D_ + ic], bi2 = bih[2 * D_ + ic];
      float bh0 = bhh[ic], bh1 = bhh[D_ + ic], bh2 = bhh[2 * D_ + ic];
#pragma unroll
      for (int r = 0; r < 4; r++) {
        int a = quad * 4 + r;
        float rr = sigm(gi[t][0][r] + bi0 + gh[t][0][r] + bh0);
        float zz = sigm(gi[t][1][r] + bi1 + gh[t][1][r] + bh1);
        float nn = tanhf(gi[t][2][r] + bi2 + rr * (gh[t][2][r] + bh2));
        float hv = b2f((u16)hrowH[a][ic]) + b2f((u16)hrowL[a][ic]);
        float hn = (1.f - zz) * nn + zz * hv;
        hout[(size_t)(a0 + a) * D_ + ic] = hn;
        hnrel[a * 132 + ic] = fmaxf(hn, 0.f);
      }
    }
  }
  __syncthreads();

  // ---------- Epilogue: P/Q for next round ----------
  {
    int a = tid >> 4, dt = (tid >> 3) & 1, seg = tid & 7;
    float s = 0.f;
#pragma unroll
    for (int j = 0; j < 16; j++)
      s += hnrel[a * 132 + seg * 16 + j] * awNS[dt * 128 + seg * 16 + j];
    partials[tid] = s;
  }
  __syncthreads();
  if (tid < 32) {
    int a = tid >> 1, dt = tid & 1;
    float s = 0.f;
#pragma unroll
    for (int seg = 0; seg < 8; seg++) s += partials[a * 16 + dt * 8 + seg];
    if (dt) Qw[a0 + a] = s; else Pw[a0 + a] = s;
  }
}

__global__ __launch_bounds__(128) void k_mol(
    const float* __restrict__ hfin,
    float* __restrict__ hcopy,
    const float* __restrict__ amask,
    const float* __restrict__ maw, const float* __restrict__ mab,
    const float* __restrict__ mtw, const float* __restrict__ mtb,
    const float* __restrict__ wih_t, const float* __restrict__ whh_t,
    const float* __restrict__ bih, const float* __restrict__ bhh,
    const float* __restrict__ ow, const float* __restrict__ ob,
    float* __restrict__ pred)
{
  int b = blockIdx.x;
  int tid = threadIdx.x;
  __shared__ float actS[L_][D_ + 1];
  __shared__ float red[D_], wgt[L_], ybv[D_], ctx[D_], mfS[D_], amol[D_];
  __shared__ float msk[L_], mawh[D_];

  msk[tid] = amask[b * L_ + tid];
  mawh[tid] = maw[D_ + tid];
  for (int l = 0; l < L_; l++) {
    float hv = hfin[(size_t)(b * L_ + l) * D_ + tid];
    hcopy[(size_t)(b * L_ + l) * D_ + tid] = hv;
    actS[l][tid] = fmaxf(hv, 0.f);
  }
  __syncthreads();

  float mf = 0.f;
  for (int l = 0; l < L_; l++) mf += actS[l][tid] * msk[l];
  mfS[tid] = mf;
  amol[tid] = fmaxf(mf, 0.f);
  __syncthreads();

  float mabv = mab[0];

  for (int t = 0; t < 2; t++) {
    float s0 = blk_sum(amol[tid] * maw[tid], red, tid);

    float sc = s0 + mabv;
    for (int j = 0; j < D_; j++) sc += actS[tid][j] * mawh[j];
    sc = lrelu(sc);
    if (msk[tid] == 0.f) sc += NEGC;

    float mx = blk_max(sc, red, tid);
    float e = expf(sc - mx);
    float es = blk_sum(e, red, tid);
    float w = (e / es) * msk[tid];
    wgt[tid] = w;
    float wsum = blk_sum(w, red, tid);
    __syncthreads();

    float y = 0.f;
    for (int l = 0; l < L_; l++) y += wgt[l] * actS[l][tid];
    ybv[tid] = y;
    __syncthreads();
    float acc = wsum * mtb[tid];
    for (int j = 0; j < D_; j++) acc += ybv[j] * mtw[j * D_ + tid];
    ctx[tid] = eluf(acc);
    __syncthreads();

    float gi0 = bih[tid], gi1 = bih[D_ + tid], gi2 = bih[2 * D_ + tid];
    float gh0 = bhh[tid], gh1 = bhh[D_ + tid], gh2 = bhh[2 * D_ + tid];
#pragma unroll 2
    for (int j = 0; j < D_; j++) {
      const float* wi = wih_t + (size_t)j * 384;
      const float* wh = whh_t + (size_t)j * 384;
      float xc = ctx[j], xh = mfS[j];
      gi0 += xc * wi[tid]; gi1 += xc * wi[D_ + tid]; gi2 += xc * wi[2 * D_ + tid];
      gh0 += xh * wh[tid]; gh1 += xh * wh[D_ + tid]; gh2 += xh * wh[2 * D_ + tid];
    }
    float r = sigm(gi0 + gh0);
    float z = sigm(gi1 + gh1);
    float n = tanhf(gi2 + r * gh2);
    float hn = (1.f - z) * n + z * mfS[tid];
    __syncthreads();
    mfS[tid] = hn;
    amol[tid] = fmaxf(hn, 0.f);
    __syncthreads();
  }

  float p = blk_sum(mfS[tid] * ow[tid], red, tid);
  if (tid == 0) pred[b] = p + ob[0];
}

extern "C" void kernel_launch(void* const* d_in, const int* in_sizes, int n_in,
                              void* d_out, int out_size, void* d_ws, size_t ws_size,
                              hipStream_t stream) {
  const float* atom_list    = (const float*)d_in[0];
  const float* bond_list    = (const float*)d_in[1];
  const float* atom_mask    = (const float*)d_in[2];
  const float* atom_fc_w    = (const float*)d_in[3];
  const float* atom_fc_b    = (const float*)d_in[4];
  const float* nbr_fc_w     = (const float*)d_in[5];
  const float* nbr_fc_b     = (const float*)d_in[6];
  const float* align_w      = (const float*)d_in[7];
  const float* align_b      = (const float*)d_in[8];
  const float* attend_w     = (const float*)d_in[9];
  const float* attend_b     = (const float*)d_in[10];
  const float* gru_wih      = (const float*)d_in[11];
  const float* gru_whh      = (const float*)d_in[12];
  const float* gru_bih      = (const float*)d_in[13];
  const float* gru_bhh      = (const float*)d_in[14];
  const float* mol_align_w  = (const float*)d_in[15];
  const float* mol_align_b  = (const float*)d_in[16];
  const float* mol_attend_w = (const float*)d_in[17];
  const float* mol_attend_b = (const float*)d_in[18];
  const float* mol_gru_wih  = (const float*)d_in[19];
  const float* mol_gru_whh  = (const float*)d_in[20];
  const float* mol_gru_bih  = (const float*)d_in[21];
  const float* mol_gru_bhh  = (const float*)d_in[22];
  const float* out_w        = (const float*)d_in[23];
  const float* out_b        = (const float*)d_in[24];
  const int*   adeg         = (const int*)d_in[25];
  const int*   bdeg         = (const int*)d_in[26];

  const size_t NH = (size_t)B_ * L_ * D_;
  float* hW   = (float*)d_ws;            // 16 MB
  short* wB   = (short*)(hW + NH);       // 1.38 MB
  float* molT = (float*)(wB + NB16);     // 0.39 MB
  short* APg  = (short*)(molT + NMOLF);  // NH shorts = 8.39 MB
  float* Q0g  = (float*)(APg + NH);      // B*L*K floats = 0.79 MB
  float* PgA  = Q0g + (size_t)B_ * L_ * K_;
  float* QgA  = PgA + B_ * L_;
  float* PgB  = QgA + B_ * L_;
  float* QgB  = PgB + B_ * L_;
  float* hOut = (float*)d_out;
  float* pred = hOut + NH;

  k_tr<<<dim3((NB16 + NMOLF + 255) / 256), dim3(256), 0, stream>>>(
      gru_wih, gru_whh, attend_w, mol_gru_wih, mol_gru_whh, wB, molT);

  // h0 -> hOut (d_out region); AP bf16; P0 -> PgA
  k_pre<<<dim3(B_ * L_ / 16), dim3(128), 0, stream>>>(
      atom_list, atom_fc_w, atom_fc_b, nbr_fc_w, align_w, hOut, APg, PgA);
  // per-pair Q0
  k_q0<<<dim3(B_ * L_ * K_ / 64), dim3(256), 0, stream>>>(
      bond_list, nbr_fc_w, nbr_fc_b, align_w, adeg, bdeg, APg, Q0g);

  dim3 blk(256), grd(B_ * L_ / NA);

  // r0: hOut(h0) -> hW ; r1: hW -> hOut ; r2: hOut -> hW
  k_round<1><<<grd, blk, 0, stream>>>(
      hOut, hW, bond_list, adeg, bdeg, nbr_fc_w, nbr_fc_b, APg,
      align_b, align_w + 2 * D_, attend_b,
      wB + 0 * (size_t)RND_BLK2, gru_bih, gru_bhh,
      PgA, Q0g, PgB, QgB);
  k_round<0><<<grd, blk, 0, stream>>>(
      hW, hOut, bond_list, adeg, bdeg, nbr_fc_w, nbr_fc_b, APg,
      align_b + 1, align_w + 4 * D_, attend_b + D_,
      wB + 1 * (size_t)RND_BLK2, gru_bih + 3 * D_, gru_bhh + 3 * D_,
      PgB, QgB, PgA, QgA);
  k_round<0><<<grd, blk, 0, stream>>>(
      hOut, hW, bond_list, adeg, bdeg, nbr_fc_w, nbr_fc_b, APg,
      align_b + 2, align_w + 4 * D_, attend_b + 2 * D_,
      wB + 2 * (size_t)RND_BLK2, gru_bih + 6 * D_, gru_bhh + 6 * D_,
      PgA, QgA, PgB, QgB);

  k_mol<<<dim3(B_), dim3(128), 0, stream>>>(
      hW, hOut, atom_mask, mol_align_w, mol_align_b, mol_attend_w, mol_attend_b,
      molT, molT + 128 * 384,
      mol_gru_bih, mol_gru_bhh, out_w, out_b, pred);
}

// Round 10
// 561.927 us; speedup vs baseline: 22.0080x; 1.0312x over previous
//
#include <hip/hip_runtime.h>
#include <cstddef>

// AttentiveFP forward. B=256 L=128 K=6 FA=39 FB=10 D=128 R=3 T=2. fp32 I/O.
// MFMA bf16 split precision (hi+lo) for ctx/GRU GEMMs; h carried fp32.
// k_pre (h0, AP=atom@Wa bf16, P0), k_q0 (per-pair Q0) hoist round-0 specials.
// k_round: ybar gather rows PREFETCHED into 48 VGPRs at kernel entry.
// k_mol: 256 threads, half-block split of all 128-iter loops.

#define B_ 256
#define L_ 128
#define K_ 6
#define FA_ 39
#define FB_ 10
#define D_ 128
#define PAD_ 127
#define NEGC (-9.0e8f)
#define NA 16
#define NPAIR (NA * K_)   // 96

typedef unsigned short u16;
typedef unsigned int u32;
using s8 = __attribute__((ext_vector_type(8))) short;   // 8 x bf16
using f4 = __attribute__((ext_vector_type(4))) float;   // MFMA acc

#define WIH_H 0
#define WIH_L 49152
#define WHH_H 98304
#define WHH_L 147456
#define TW_H  196608
#define TW_L  212992
#define RND_BLK2 229376
#define NB16 (3 * RND_BLK2)
#define NMOLF (2 * 128 * 384)

__device__ __forceinline__ float lrelu(float x) { return x > 0.f ? x : 0.01f * x; }
__device__ __forceinline__ float eluf(float x)  { return x > 0.f ? x : expm1f(x); }
__device__ __forceinline__ float sigm(float x)  { return 1.f / (1.f + expf(-x)); }
__device__ __forceinline__ float b2f(u16 u) {
  union { u32 i; float f; } v; v.i = ((u32)u) << 16; return v.f;
}
__device__ __forceinline__ short f2b(float f) {  // RNE
  union { float f; u32 i; } v; v.f = f;
  u32 x = v.i;
  return (short)(u16)((x + 0x7FFFu + ((x >> 16) & 1u)) >> 16);
}

// Build split bf16 weights + fp32 transposed mol GRU weights.
__global__ __launch_bounds__(256) void k_tr(
    const float* __restrict__ gwih, const float* __restrict__ gwhh,
    const float* __restrict__ attw,
    const float* __restrict__ mwih, const float* __restrict__ mwhh,
    short* __restrict__ wB, float* __restrict__ molT) {
  int idx = blockIdx.x * 256 + threadIdx.x;
  if (idx < NB16) {
    int r = idx / RND_BLK2, o = idx % RND_BLK2;
    float v; int lo;
    if (o < 98304) {
      lo = o / 49152; int e = o % 49152;
      v = gwih[(size_t)r * 49152 + e];
    } else if (o < 196608) {
      int o2 = o - 98304;
      lo = o2 / 49152; int e = o2 % 49152;
      v = gwhh[(size_t)r * 49152 + e];
    } else {
      int o2 = o - 196608;
      lo = o2 / 16384; int e = o2 % 16384;
      int g = e / 128, k = e % 128;
      v = attw[(size_t)r * 16384 + k * 128 + g];
    }
    short hi = f2b(v);
    wB[idx] = lo ? f2b(v - b2f((u16)hi)) : hi;
  } else if (idx < NB16 + NMOLF) {
    int e2 = idx - NB16;
    int m = e2 / 49152, e = e2 % 49152, j = e / 384, g = e % 384;
    molT[e2] = (m ? mwhh : mwih)[g * 128 + j];
  }
}

// Per-atom precompute: h0, AP = atom@Wa (bf16), P0 = h0.awlo0.
__global__ __launch_bounds__(128) void k_pre(
    const float* __restrict__ atom_list,
    const float* __restrict__ afc_w, const float* __restrict__ afc_b,
    const float* __restrict__ nbr_w,
    const float* __restrict__ aw0,
    float* __restrict__ h0out, short* __restrict__ APg, float* __restrict__ PgA)
{
  int tid = threadIdx.x;
  int a0 = blockIdx.x * 16;
  __shared__ float xa[16 * 40];
  __shared__ float h0S[16][132];
  __shared__ float awS[128];
  __shared__ float partials[128];

  for (int i = tid; i < 16 * FA_; i += 128) {
    int a = i / FA_, c = i % FA_;
    xa[a * 40 + c] = atom_list[((size_t)(a0 + a)) * FA_ + c];
  }
  awS[tid] = aw0[tid];
  __syncthreads();

  {
    float acc[16];
    float bv = afc_b[tid];
#pragma unroll
    for (int a = 0; a < 16; a++) acc[a] = bv;
#pragma unroll 2
    for (int j = 0; j < FA_; j++) {
      float w = afc_w[j * D_ + tid];
#pragma unroll
      for (int a = 0; a < 16; a++) acc[a] += xa[a * 40 + j] * w;
    }
#pragma unroll
    for (int a = 0; a < 16; a++) {
      float hv = lrelu(acc[a]);
      h0out[(size_t)(a0 + a) * D_ + tid] = hv;
      h0S[a][tid] = hv;
    }
  }
  {
    float acc[16];
#pragma unroll
    for (int a = 0; a < 16; a++) acc[a] = 0.f;
#pragma unroll 2
    for (int j = 0; j < FA_; j++) {
      float w = nbr_w[j * D_ + tid];
#pragma unroll
      for (int a = 0; a < 16; a++) acc[a] += xa[a * 40 + j] * w;
    }
#pragma unroll
    for (int a = 0; a < 16; a++)
      APg[(size_t)(a0 + a) * D_ + tid] = f2b(acc[a]);
  }
  __syncthreads();
  {
    int a = tid >> 3, seg = tid & 7;
    float s = 0.f;
#pragma unroll
    for (int j = 0; j < 16; j++) s += h0S[a][seg * 16 + j] * awS[seg * 16 + j];
    partials[tid] = s;
  }
  __syncthreads();
  if (tid < 16) {
    float s = 0.f;
#pragma unroll
    for (int g = 0; g < 8; g++) s += partials[tid * 8 + g];
    PgA[a0 + tid] = s;
  }
}

// Per-pair Q0 = sum_d lrelu(AP[aidx]+bond[bidx]@Wb+nb) * awhi0.
__global__ __launch_bounds__(256) void k_q0(
    const float* __restrict__ bond_list,
    const float* __restrict__ nbr_w, const float* __restrict__ nbr_b,
    const float* __restrict__ aw0,
    const int* __restrict__ adeg, const int* __restrict__ bdeg,
    const short* __restrict__ APg, float* __restrict__ Q0g)
{
  int tid = threadIdx.x;
  __shared__ float WbS[10 * 128];
  __shared__ float nbS[128], ahS[128];
  for (int i = tid; i < 10 * 128; i += 256)
    WbS[i] = nbr_w[(FA_ + i / 128) * D_ + (i % 128)];
  if (tid < 128) { nbS[tid] = nbr_b[tid]; ahS[tid] = aw0[D_ + tid]; }
  __syncthreads();

  int p = blockIdx.x * 64 + (tid >> 2);
  int seg = tid & 3;
  int aidx = adeg[p], bidx = bdeg[p];
  int bb = p / (L_ * K_);
  const short* rowA = APg + ((size_t)bb * L_ + aidx) * D_;
  const float* brow = bond_list + ((size_t)bb * L_ + bidx) * FB_;
  float bnd[10];
#pragma unroll
  for (int m = 0; m < 10; m++) bnd[m] = brow[m];
  float s = 0.f;
  int j0 = seg * 32;
#pragma unroll 4
  for (int j = j0; j < j0 + 32; j++) {
    float v = b2f((u16)rowA[j]) + nbS[j];
#pragma unroll
    for (int m = 0; m < 10; m++) v += bnd[m] * WbS[m * 128 + j];
    s += lrelu(v) * ahS[j];
  }
  s += __shfl_xor(s, 1, 64);
  s += __shfl_xor(s, 2, 64);
  if (seg == 0) Q0g[p] = s;
}

template <int FIRST>
__global__ __launch_bounds__(256, 4) void k_round(
    const float* __restrict__ hin,
    float* __restrict__ hout,
    const float* __restrict__ bond_list,
    const int* __restrict__ adeg, const int* __restrict__ bdeg,
    const float* __restrict__ nbr_w, const float* __restrict__ nbr_b,
    const short* __restrict__ APg,
    const float* __restrict__ ab,
    const float* __restrict__ awN,
    const float* __restrict__ tb,
    const short* __restrict__ wR,
    const float* __restrict__ bih, const float* __restrict__ bhh,
    const float* __restrict__ Pr, const float* __restrict__ Qr,
    float* __restrict__ Pw, float* __restrict__ Qw)
{
  int tid  = threadIdx.x;
  int t128 = tid & 127;
  int hf   = tid >> 7;
  int lane = tid & 63;
  int wv   = tid >> 6;
  int quad = lane >> 4;
  int col  = lane & 15;
  int a0   = blockIdx.x * NA;
  int bb   = a0 >> 7;

  const short* wihH = wR + WIH_H;
  const short* wihL = wR + WIH_L;
  const short* whhH = wR + WHH_H;
  const short* whhL = wR + WHH_L;
  const short* twH  = wR + TW_H;
  const short* twL  = wR + TW_L;

  __shared__ short hrowH[NA][136];
  __shared__ short hrowL[NA][136];
  __shared__ __align__(16) char arena[9472];       // ybar/ctx | hnrelu
  __shared__ float awNS[256];
  __shared__ float partials[256];
  __shared__ float pS[NA], qS[NPAIR], wkS[NPAIR], wsS[NA];
  __shared__ int aidxS[NPAIR];
  __shared__ int bidxS[FIRST ? NPAIR : 1];
  __shared__ float bwS[FIRST ? 2368 : 1];          // bond[96][10] | Wb[10][128] | nb[128]

  short* ybarH = (short*)arena;               // [16][136] (ctx reuses)
  short* ybarL = (short*)(arena + 4352);
  float* hnrel = (float*)arena;               // epilogue relu(hn) [16][132]

  if (tid < NPAIR) {
    int av = adeg[a0 * K_ + tid];
    aidxS[tid] = av;
    if (FIRST) { bidxS[tid] = bdeg[a0 * K_ + tid]; qS[tid] = Qr[a0 * K_ + tid]; }
    else       qS[tid] = Qr[bb * L_ + av];
  } else if (tid >= 128 && tid < 128 + NA) {
    pS[tid - 128] = Pr[a0 + (tid - 128)];
  }
  awNS[tid] = awN[tid];
  __syncthreads();

  // ---------- Prefetch ybar gather rows into registers (48 per thread) ----------
  float vf[48];
#pragma unroll
  for (int i = 0; i < 48; i++) {
    int row = aidxS[hf * 48 + i];
    if (FIRST)
      vf[i] = b2f((u16)APg[((size_t)bb * L_ + row) * D_ + t128]);
    else
      vf[i] = fmaxf(hin[((size_t)bb * L_ + row) * D_ + t128], 0.f);
  }

  // ---------- Phase 1: h rows (+ FIRST: bond/Wb staging) ----------
  if (FIRST) {
    for (int i = tid; i < 960; i += 256) {
      int p = i / 10, m = i % 10;
      bwS[p * 10 + m] = bond_list[((size_t)bb * L_ + bidxS[p]) * FB_ + m];
    }
    for (int i = tid; i < 1280; i += 256)
      bwS[960 + i] = nbr_w[(FA_ + i / 128) * D_ + (i % 128)];
    if (tid < 128) bwS[2240 + tid] = nbr_b[tid];
  }
#pragma unroll 4
  for (int i = 0; i < 8; i++) {
    int a = i * 2 + hf;
    float hv = hin[(size_t)(a0 + a) * D_ + t128];
    short hh = f2b(hv);
    hrowH[a][t128] = hh;
    hrowL[a][t128] = f2b(hv - b2f((u16)hh));
  }
  __syncthreads();

  // ---------- Softmax over K ----------
  if (tid < NA) {
    int a = tid;
    float abv = ab[0];
    float sc[K_];
    float m = -3.0e38f;
#pragma unroll
    for (int k = 0; k < K_; k++) {
      float s = lrelu(pS[a] + qS[a * K_ + k] + abv);
      if (aidxS[a * K_ + k] == PAD_) s += NEGC;
      sc[k] = s; m = fmaxf(m, s);
    }
    float es = 0.f;
#pragma unroll
    for (int k = 0; k < K_; k++) { sc[k] = expf(sc[k] - m); es += sc[k]; }
    float ws = 0.f;
#pragma unroll
    for (int k = 0; k < K_; k++) {
      float w = (aidxS[a * K_ + k] == PAD_) ? 0.f : sc[k] / es;
      wkS[a * K_ + k] = w; ws += w;
    }
    wsS[a] = ws;
  }
  __syncthreads();

  // ---------- ybar hi/lo from prefetched registers ----------
  if (FIRST) {
    const float* bondS = bwS;
    const float* WbS   = bwS + 960;
    float nbv = bwS[2240 + t128];
#pragma unroll
    for (int i = 0; i < 8; i++) {
      int a = hf * 8 + i;
      float yb = 0.f;
#pragma unroll
      for (int k = 0; k < K_; k++) {
        int p = a * K_ + k;
        float nf = vf[i * K_ + k] + nbv;
#pragma unroll
        for (int m = 0; m < 10; m++) nf += bondS[p * 10 + m] * WbS[m * 128 + t128];
        yb += wkS[p] * lrelu(nf);
      }
      short yh = f2b(yb);
      ybarH[a * 136 + t128] = yh;
      ybarL[a * 136 + t128] = f2b(yb - b2f((u16)yh));
    }
  } else {
#pragma unroll
    for (int i = 0; i < 8; i++) {
      int a = hf * 8 + i;
      float yb = 0.f;
#pragma unroll
      for (int k = 0; k < K_; k++)
        yb += wkS[a * K_ + k] * vf[i * K_ + k];
      short yh = f2b(yb);
      ybarH[a * 136 + t128] = yh;
      ybarL[a * 136 + t128] = f2b(yb - b2f((u16)yh));
    }
  }
  __syncthreads();

  // ---------- ctx = elu(ybar @ twT^T + wsum*tb), split MFMA ----------
  {
    f4 c2[2] = {};
#pragma unroll
    for (int k0 = 0; k0 < D_; k0 += 32) {
      s8 ayh = *(const s8*)&ybarH[col * 136 + k0 + quad * 8];
      s8 ayl = *(const s8*)&ybarL[col * 136 + k0 + quad * 8];
#pragma unroll
      for (int t = 0; t < 2; t++) {
        int g = (2 * wv + t) * 16 + col;
        s8 bwh = *(const s8*)&twH[(size_t)g * 128 + k0 + quad * 8];
        s8 bwl = *(const s8*)&twL[(size_t)g * 128 + k0 + quad * 8];
        c2[t] = __builtin_amdgcn_mfma_f32_16x16x32_bf16(ayh, bwh, c2[t], 0, 0, 0);
        c2[t] = __builtin_amdgcn_mfma_f32_16x16x32_bf16(ayl, bwh, c2[t], 0, 0, 0);
        c2[t] = __builtin_amdgcn_mfma_f32_16x16x32_bf16(ayh, bwl, c2[t], 0, 0, 0);
      }
    }
    __syncthreads();
#pragma unroll
    for (int t = 0; t < 2; t++) {
      int g = (2 * wv + t) * 16 + col;
      float tbv = tb[g];
#pragma unroll
      for (int r = 0; r < 4; r++) {
        int a = quad * 4 + r;
        float c = eluf(c2[t][r] + wsS[a] * tbv);
        short chs = f2b(c);
        ybarH[a * 136 + g] = chs;                    // ctxH
        ybarL[a * 136 + g] = f2b(c - b2f((u16)chs)); // ctxL
      }
    }
  }
  __syncthreads();

  // ---------- GRU via split MFMA ----------
  {
    const short* ctxH = ybarH;
    const short* ctxL = ybarL;
    f4 gi[2][3] = {}, gh[2][3] = {};
#pragma unroll
    for (int k0 = 0; k0 < D_; k0 += 32) {
      s8 ach = *(const s8*)&ctxH[col * 136 + k0 + quad * 8];
      s8 acl = *(const s8*)&ctxL[col * 136 + k0 + quad * 8];
      s8 ahh = *(const s8*)&hrowH[col][k0 + quad * 8];
      s8 ahl = *(const s8*)&hrowL[col][k0 + quad * 8];
#pragma unroll
      for (int t = 0; t < 2; t++) {
#pragma unroll
        for (int kd = 0; kd < 3; kd++) {
          int g = ((2 * wv + t) + kd * 8) * 16 + col;
          s8 bi_h = *(const s8*)&wihH[(size_t)g * 128 + k0 + quad * 8];
          s8 bi_l = *(const s8*)&wihL[(size_t)g * 128 + k0 + quad * 8];
          s8 bh_h = *(const s8*)&whhH[(size_t)g * 128 + k0 + quad * 8];
          s8 bh_l = *(const s8*)&whhL[(size_t)g * 128 + k0 + quad * 8];
          gi[t][kd] = __builtin_amdgcn_mfma_f32_16x16x32_bf16(ach, bi_h, gi[t][kd], 0, 0, 0);
          gi[t][kd] = __builtin_amdgcn_mfma_f32_16x16x32_bf16(acl, bi_h, gi[t][kd], 0, 0, 0);
          gi[t][kd] = __builtin_amdgcn_mfma_f32_16x16x32_bf16(ach, bi_l, gi[t][kd], 0, 0, 0);
          gh[t][kd] = __builtin_amdgcn_mfma_f32_16x16x32_bf16(ahh, bh_h, gh[t][kd], 0, 0, 0);
          gh[t][kd] = __builtin_amdgcn_mfma_f32_16x16x32_bf16(ahl, bh_h, gh[t][kd], 0, 0, 0);
          gh[t][kd] = __builtin_amdgcn_mfma_f32_16x16x32_bf16(ahh, bh_l, gh[t][kd], 0, 0, 0);
        }
      }
    }
    __syncthreads();

#pragma unroll
    for (int t = 0; t < 2; t++) {
      int ic = (2 * wv + t) * 16 + col;
      float bi0 = bih[ic], bi1 = bih[D_ + ic], bi2 = bih[2 * D_ + ic];
      float bh0 = bhh[ic], bh1 = bhh[D_ + ic], bh2 = bhh[2 * D_ + ic];
#pragma unroll
      for (int r = 0; r < 4; r++) {
        int a = quad * 4 + r;
        float rr = sigm(gi[t][0][r] + bi0 + gh[t][0][r] + bh0);
        float zz = sigm(gi[t][1][r] + bi1 + gh[t][1][r] + bh1);
        float nn = tanhf(gi[t][2][r] + bi2 + rr * (gh[t][2][r] + bh2));
        float hv = b2f((u16)hrowH[a][ic]) + b2f((u16)hrowL[a][ic]);
        float hn = (1.f - zz) * nn + zz * hv;
        hout[(size_t)(a0 + a) * D_ + ic] = hn;
        if (Pw) hnrel[a * 132 + ic] = fmaxf(hn, 0.f);
      }
    }
  }

  // ---------- Epilogue: P/Q for next round (skipped on last round) ----------
  if (Pw) {
    __syncthreads();
    {
      int a = tid >> 4, dt = (tid >> 3) & 1, seg = tid & 7;
      float s = 0.f;
#pragma unroll
      for (int j = 0; j < 16; j++)
        s += hnrel[a * 132 + seg * 16 + j] * awNS[dt * 128 + seg * 16 + j];
      partials[tid] = s;
    }
    __syncthreads();
    if (tid < 32) {
      int a = tid >> 1, dt = tid & 1;
      float s = 0.f;
#pragma unroll
      for (int seg = 0; seg < 8; seg++) s += partials[a * 16 + dt * 8 + seg];
      if (dt) Qw[a0 + a] = s; else Pw[a0 + a] = s;
    }
  }
}

__global__ __launch_bounds__(256) void k_mol(
    const float* __restrict__ hfin,
    float* __restrict__ hcopy,
    const float* __restrict__ amask,
    const float* __restrict__ maw, const float* __restrict__ mab,
    const float* __restrict__ mtw, const float* __restrict__ mtb,
    const float* __restrict__ wih_t, const float* __restrict__ whh_t,
    const float* __restrict__ bih, const float* __restrict__ bhh,
    const float* __restrict__ ow, const float* __restrict__ ob,
    float* __restrict__ pred)
{
  int b = blockIdx.x;
  int tid = threadIdx.x;
  int t128 = tid & 127;
  int hf = tid >> 7;
  __shared__ float actS[L_][D_ + 1];
  __shared__ float red[256];
  __shared__ float par2[2][132];
  __shared__ float pg[6][132];
  __shared__ float wgt[128], ybv[132], ctx[132], mfS[132], amol[132];
  __shared__ float msk[128], mawh[128], scf[128];

  if (hf == 0) { msk[t128] = amask[b * L_ + t128]; mawh[t128] = maw[D_ + t128]; }
  for (int i = 0; i < 64; i++) {
    int l = hf * 64 + i;
    float hv = hfin[(size_t)(b * L_ + l) * D_ + t128];
    hcopy[(size_t)(b * L_ + l) * D_ + t128] = hv;
    actS[l][t128] = fmaxf(hv, 0.f);
  }
  __syncthreads();

  // mol_feature (l-split)
  {
    float s = 0.f;
    for (int i = 0; i < 64; i++) { int l = hf * 64 + i; s += actS[l][t128] * msk[l]; }
    par2[hf][t128] = s;
  }
  __syncthreads();
  if (hf == 0) {
    float mf = par2[0][t128] + par2[1][t128];
    mfS[t128] = mf; amol[t128] = fmaxf(mf, 0.f);
  }
  __syncthreads();

  float mabv = mab[0];

  for (int t = 0; t < 2; t++) {
    // s0 (256-thread reduction over 128 payload)
    red[tid] = (tid < 128) ? amol[tid] * maw[tid] : 0.f;
    __syncthreads();
    for (int s = 128; s > 0; s >>= 1) { if (tid < s) red[tid] += red[tid + s]; __syncthreads(); }
    float s0 = red[0]; __syncthreads();

    // sc[l=t128] (j-split)
    {
      float s = 0.f;
      for (int i = 0; i < 64; i++) { int j = hf * 64 + i; s += actS[t128][j] * mawh[j]; }
      par2[hf][t128] = s;
    }
    __syncthreads();
    if (hf == 0) {
      float sc = lrelu(s0 + mabv + par2[0][t128] + par2[1][t128]);
      if (msk[t128] == 0.f) sc += NEGC;
      scf[t128] = sc;
    }
    __syncthreads();

    // softmax over l
    float scv = scf[t128];
    red[tid] = (tid < 128) ? scv : -3.0e38f;
    __syncthreads();
    for (int s = 128; s > 0; s >>= 1) { if (tid < s) red[tid] = fmaxf(red[tid], red[tid + s]); __syncthreads(); }
    float mx = red[0]; __syncthreads();
    float e = expf(scv - mx);
    red[tid] = (tid < 128) ? e : 0.f;
    __syncthreads();
    for (int s = 128; s > 0; s >>= 1) { if (tid < s) red[tid] += red[tid + s]; __syncthreads(); }
    float es = red[0]; __syncthreads();
    float w = (e / es) * msk[t128];
    if (hf == 0) wgt[t128] = w;
    red[tid] = (tid < 128) ? w : 0.f;
    __syncthreads();
    for (int s = 128; s > 0; s >>= 1) { if (tid < s) red[tid] += red[tid + s]; __syncthreads(); }
    float wsum = red[0]; __syncthreads();

    // y[j=t128] (l-split)
    {
      float s = 0.f;
      for (int i = 0; i < 64; i++) { int l = hf * 64 + i; s += wgt[l] * actS[l][t128]; }
      par2[hf][t128] = s;
    }
    __syncthreads();
    if (hf == 0) ybv[t128] = par2[0][t128] + par2[1][t128];
    __syncthreads();

    // ctx[g=t128] (j-split)
    {
      float s = 0.f;
#pragma unroll 2
      for (int i = 0; i < 64; i++) { int j = hf * 64 + i; s += ybv[j] * mtw[j * D_ + t128]; }
      par2[hf][t128] = s;
    }
    __syncthreads();
    if (hf == 0) ctx[t128] = eluf(par2[0][t128] + par2[1][t128] + wsum * mtb[t128]);
    __syncthreads();

    // GRU (j-split, x-stationary)
    {
      float gi0 = 0, gi1 = 0, gi2 = 0, gh0 = 0, gh1 = 0, gh2 = 0;
#pragma unroll 2
      for (int i = 0; i < 64; i++) {
        int j = hf * 64 + i;
        const float* wi = wih_t + (size_t)j * 384;
        const float* wh = whh_t + (size_t)j * 384;
        float xc = ctx[j], xh = mfS[j];
        gi0 += xc * wi[t128]; gi1 += xc * wi[128 + t128]; gi2 += xc * wi[256 + t128];
        gh0 += xh * wh[t128]; gh1 += xh * wh[128 + t128]; gh2 += xh * wh[256 + t128];
      }
      if (hf == 1) {
        pg[0][t128] = gi0; pg[1][t128] = gi1; pg[2][t128] = gi2;
        pg[3][t128] = gh0; pg[4][t128] = gh1; pg[5][t128] = gh2;
      }
      __syncthreads();
      if (hf == 0) {
        gi0 += pg[0][t128] + bih[t128];
        gi1 += pg[1][t128] + bih[128 + t128];
        gi2 += pg[2][t128] + bih[256 + t128];
        gh0 += pg[3][t128] + bhh[t128];
        gh1 += pg[4][t128] + bhh[128 + t128];
        gh2 += pg[5][t128] + bhh[256 + t128];
        float r = sigm(gi0 + gh0);
        float z = sigm(gi1 + gh1);
        float n = tanhf(gi2 + r * gh2);
        float hn = (1.f - z) * n + z * mfS[t128];
        mfS[t128] = hn;
        amol[t128] = fmaxf(hn, 0.f);
      }
      __syncthreads();
    }
  }

  red[tid] = (tid < 128) ? mfS[tid] * ow[tid] : 0.f;
  __syncthreads();
  for (int s = 128; s > 0; s >>= 1) { if (tid < s) red[tid] += red[tid + s]; __syncthreads(); }
  if (tid == 0) pred[b] = red[0] + ob[0];
}

extern "C" void kernel_launch(void* const* d_in, const int* in_sizes, int n_in,
                              void* d_out, int out_size, void* d_ws, size_t ws_size,
                              hipStream_t stream) {
  const float* atom_list    = (const float*)d_in[0];
  const float* bond_list    = (const float*)d_in[1];
  const float* atom_mask    = (const float*)d_in[2];
  const float* atom_fc_w    = (const float*)d_in[3];
  const float* atom_fc_b    = (const float*)d_in[4];
  const float* nbr_fc_w     = (const float*)d_in[5];
  const float* nbr_fc_b     = (const float*)d_in[6];
  const float* align_w      = (const float*)d_in[7];
  const float* align_b      = (const float*)d_in[8];
  const float* attend_w     = (const float*)d_in[9];
  const float* attend_b     = (const float*)d_in[10];
  const float* gru_wih      = (const float*)d_in[11];
  const float* gru_whh      = (const float*)d_in[12];
  const float* gru_bih      = (const float*)d_in[13];
  const float* gru_bhh      = (const float*)d_in[14];
  const float* mol_align_w  = (const float*)d_in[15];
  const float* mol_align_b  = (const float*)d_in[16];
  const float* mol_attend_w = (const float*)d_in[17];
  const float* mol_attend_b = (const float*)d_in[18];
  const float* mol_gru_wih  = (const float*)d_in[19];
  const float* mol_gru_whh  = (const float*)d_in[20];
  const float* mol_gru_bih  = (const float*)d_in[21];
  const float* mol_gru_bhh  = (const float*)d_in[22];
  const float* out_w        = (const float*)d_in[23];
  const float* out_b        = (const float*)d_in[24];
  const int*   adeg         = (const int*)d_in[25];
  const int*   bdeg         = (const int*)d_in[26];

  const size_t NH = (size_t)B_ * L_ * D_;
  float* hW   = (float*)d_ws;            // 16 MB
  short* wB   = (short*)(hW + NH);       // 1.38 MB
  float* molT = (float*)(wB + NB16);     // 0.39 MB
  short* APg  = (short*)(molT + NMOLF);  // NH shorts = 8.39 MB
  float* Q0g  = (float*)(APg + NH);      // B*L*K floats = 0.79 MB
  float* PgA  = Q0g + (size_t)B_ * L_ * K_;
  float* QgA  = PgA + B_ * L_;
  float* PgB  = QgA + B_ * L_;
  float* QgB  = PgB + B_ * L_;
  float* hOut = (float*)d_out;
  float* pred = hOut + NH;

  k_tr<<<dim3((NB16 + NMOLF + 255) / 256), dim3(256), 0, stream>>>(
      gru_wih, gru_whh, attend_w, mol_gru_wih, mol_gru_whh, wB, molT);

  k_pre<<<dim3(B_ * L_ / 16), dim3(128), 0, stream>>>(
      atom_list, atom_fc_w, atom_fc_b, nbr_fc_w, align_w, hOut, APg, PgA);
  k_q0<<<dim3(B_ * L_ * K_ / 64), dim3(256), 0, stream>>>(
      bond_list, nbr_fc_w, nbr_fc_b, align_w, adeg, bdeg, APg, Q0g);

  dim3 blk(256), grd(B_ * L_ / NA);

  // r0: hOut(h0) -> hW ; r1: hW -> hOut ; r2: hOut -> hW
  k_round<1><<<grd, blk, 0, stream>>>(
      hOut, hW, bond_list, adeg, bdeg, nbr_fc_w, nbr_fc_b, APg,
      align_b, align_w + 2 * D_, attend_b,
      wB + 0 * (size_t)RND_BLK2, gru_bih, gru_bhh,
      PgA, Q0g, PgB, QgB);
  k_round<0><<<grd, blk, 0, stream>>>(
      hW, hOut, bond_list, adeg, bdeg, nbr_fc_w, nbr_fc_b, APg,
      align_b + 1, align_w + 4 * D_, attend_b + D_,
      wB + 1 * (size_t)RND_BLK2, gru_bih + 3 * D_, gru_bhh + 3 * D_,
      PgB, QgB, PgA, QgA);
  k_round<0><<<grd, blk, 0, stream>>>(
      hOut, hW, bond_list, adeg, bdeg, nbr_fc_w, nbr_fc_b, APg,
      align_b + 2, align_w + 4 * D_, attend_b + 2 * D_,
      wB + 2 * (size_t)RND_BLK2, gru_bih + 6 * D_, gru_bhh + 6 * D_,
      PgA, QgA, (float*)nullptr, (float*)nullptr);

  k_mol<<<dim3(B_), dim3(256), 0, stream>>>(
      hW, hOut, atom_mask, mol_align_w, mol_align_b, mol_attend_w, mol_attend_b,
      molT, molT + 128 * 384,
      mol_gru_bih, mol_gru_bhh, out_w, out_b, pred);
}

// Round 11
// 465.660 us; speedup vs baseline: 26.5578x; 1.2067x over previous
//
#include <hip/hip_runtime.h>
#include <cstddef>

// AttentiveFP forward. B=256 L=128 K=6 FA=39 FB=10 D=128 R=3 T=2. fp32 I/O.
// MFMA bf16 split precision (hi+lo) for ctx/GRU GEMMs; h carried fp32.
// Weights stored FRAG-SWIZZLED: each MFMA B-fragment is lane-contiguous
// (1024B/wave coalesced loads). k_pre/k_q0 hoist round-0; P/Q precomputed.
// k_mol: 512 threads, quarter-split loops.

#define B_ 256
#define L_ 128
#define K_ 6
#define FA_ 39
#define FB_ 10
#define D_ 128
#define PAD_ 127
#define NEGC (-9.0e8f)
#define NA 16
#define NPAIR (NA * K_)   // 96

typedef unsigned short u16;
typedef unsigned int u32;
using s8 = __attribute__((ext_vector_type(8))) short;   // 8 x bf16
using f4 = __attribute__((ext_vector_type(4))) float;   // MFMA acc

#define WIH_H 0
#define WIH_L 49152
#define WHH_H 98304
#define WHH_L 147456
#define TW_H  196608
#define TW_L  212992
#define RND_BLK2 229376
#define NB16 (3 * RND_BLK2)
#define NMOLF (2 * 128 * 384)

__device__ __forceinline__ float lrelu(float x) { return x > 0.f ? x : 0.01f * x; }
__device__ __forceinline__ float eluf(float x)  { return x > 0.f ? x : expm1f(x); }
__device__ __forceinline__ float sigm(float x)  { return 1.f / (1.f + expf(-x)); }
__device__ __forceinline__ float b2f(u16 u) {
  union { u32 i; float f; } v; v.i = ((u32)u) << 16; return v.f;
}
__device__ __forceinline__ short f2b(float f) {  // RNE
  union { float f; u32 i; } v; v.f = f;
  u32 x = v.i;
  return (short)(u16)((x + 0x7FFFu + ((x >> 16) & 1u)) >> 16);
}

// Build frag-swizzled split bf16 weights + fp32 transposed mol GRU weights.
// Swizzle: element ((gt*4+kc)*64+lane)*8+j  <=  W[gt*16+(lane&15)][kc*32+(lane>>4)*8+j]
__global__ __launch_bounds__(256) void k_tr(
    const float* __restrict__ gwih, const float* __restrict__ gwhh,
    const float* __restrict__ attw,
    const float* __restrict__ mwih, const float* __restrict__ mwhh,
    short* __restrict__ wB, float* __restrict__ molT) {
  int idx = blockIdx.x * 256 + threadIdx.x;
  if (idx < NB16) {
    int r = idx / RND_BLK2, o = idx % RND_BLK2;
    float v; int lo;
    int e, kind;          // kind 0=wih, 1=whh, 2=tw
    if (o < 98304)      { kind = 0; lo = o / 49152; e = o % 49152; }
    else if (o < 196608){ kind = 1; int o2 = o - 98304; lo = o2 / 49152; e = o2 % 49152; }
    else                { kind = 2; int o2 = o - 196608; lo = o2 / 16384; e = o2 % 16384; }
    int gt = e >> 11, rem = e & 2047;
    int kc = rem >> 9, rem2 = rem & 511;
    int lane = rem2 >> 3, j = rem2 & 7;
    int col = lane & 15, quad = lane >> 4;
    int g = gt * 16 + col;
    int k = kc * 32 + quad * 8 + j;
    if (kind == 0)      v = gwih[(size_t)r * 49152 + g * 128 + k];
    else if (kind == 1) v = gwhh[(size_t)r * 49152 + g * 128 + k];
    else                v = attw[(size_t)r * 16384 + k * 128 + g];
    short hi = f2b(v);
    wB[idx] = lo ? f2b(v - b2f((u16)hi)) : hi;
  } else if (idx < NB16 + NMOLF) {
    int e2 = idx - NB16;
    int m = e2 / 49152, e = e2 % 49152, j = e / 384, g = e % 384;
    molT[e2] = (m ? mwhh : mwih)[g * 128 + j];
  }
}

// Per-atom precompute: h0, AP = atom@Wa (bf16), P0 = h0.awlo0.
__global__ __launch_bounds__(128) void k_pre(
    const float* __restrict__ atom_list,
    const float* __restrict__ afc_w, const float* __restrict__ afc_b,
    const float* __restrict__ nbr_w,
    const float* __restrict__ aw0,
    float* __restrict__ h0out, short* __restrict__ APg, float* __restrict__ PgA)
{
  int tid = threadIdx.x;
  int a0 = blockIdx.x * 16;
  __shared__ float xa[16 * 40];
  __shared__ float h0S[16][132];
  __shared__ float awS[128];
  __shared__ float partials[128];

  for (int i = tid; i < 16 * FA_; i += 128) {
    int a = i / FA_, c = i % FA_;
    xa[a * 40 + c] = atom_list[((size_t)(a0 + a)) * FA_ + c];
  }
  awS[tid] = aw0[tid];
  __syncthreads();

  {
    float acc[16];
    float bv = afc_b[tid];
#pragma unroll
    for (int a = 0; a < 16; a++) acc[a] = bv;
#pragma unroll 2
    for (int j = 0; j < FA_; j++) {
      float w = afc_w[j * D_ + tid];
#pragma unroll
      for (int a = 0; a < 16; a++) acc[a] += xa[a * 40 + j] * w;
    }
#pragma unroll
    for (int a = 0; a < 16; a++) {
      float hv = lrelu(acc[a]);
      h0out[(size_t)(a0 + a) * D_ + tid] = hv;
      h0S[a][tid] = hv;
    }
  }
  {
    float acc[16];
#pragma unroll
    for (int a = 0; a < 16; a++) acc[a] = 0.f;
#pragma unroll 2
    for (int j = 0; j < FA_; j++) {
      float w = nbr_w[j * D_ + tid];
#pragma unroll
      for (int a = 0; a < 16; a++) acc[a] += xa[a * 40 + j] * w;
    }
#pragma unroll
    for (int a = 0; a < 16; a++)
      APg[(size_t)(a0 + a) * D_ + tid] = f2b(acc[a]);
  }
  __syncthreads();
  {
    int a = tid >> 3, seg = tid & 7;
    float s = 0.f;
#pragma unroll
    for (int j = 0; j < 16; j++) s += h0S[a][seg * 16 + j] * awS[seg * 16 + j];
    partials[tid] = s;
  }
  __syncthreads();
  if (tid < 16) {
    float s = 0.f;
#pragma unroll
    for (int g = 0; g < 8; g++) s += partials[tid * 8 + g];
    PgA[a0 + tid] = s;
  }
}

// Per-pair Q0 = sum_d lrelu(AP[aidx]+bond[bidx]@Wb+nb) * awhi0.
__global__ __launch_bounds__(256) void k_q0(
    const float* __restrict__ bond_list,
    const float* __restrict__ nbr_w, const float* __restrict__ nbr_b,
    const float* __restrict__ aw0,
    const int* __restrict__ adeg, const int* __restrict__ bdeg,
    const short* __restrict__ APg, float* __restrict__ Q0g)
{
  int tid = threadIdx.x;
  __shared__ float WbS[10 * 128];
  __shared__ float nbS[128], ahS[128];
  for (int i = tid; i < 10 * 128; i += 256)
    WbS[i] = nbr_w[(FA_ + i / 128) * D_ + (i % 128)];
  if (tid < 128) { nbS[tid] = nbr_b[tid]; ahS[tid] = aw0[D_ + tid]; }
  __syncthreads();

  int p = blockIdx.x * 64 + (tid >> 2);
  int seg = tid & 3;
  int aidx = adeg[p], bidx = bdeg[p];
  int bb = p / (L_ * K_);
  const short* rowA = APg + ((size_t)bb * L_ + aidx) * D_;
  const float* brow = bond_list + ((size_t)bb * L_ + bidx) * FB_;
  float bnd[10];
#pragma unroll
  for (int m = 0; m < 10; m++) bnd[m] = brow[m];
  float s = 0.f;
  int j0 = seg * 32;
#pragma unroll 4
  for (int j = j0; j < j0 + 32; j++) {
    float v = b2f((u16)rowA[j]) + nbS[j];
#pragma unroll
    for (int m = 0; m < 10; m++) v += bnd[m] * WbS[m * 128 + j];
    s += lrelu(v) * ahS[j];
  }
  s += __shfl_xor(s, 1, 64);
  s += __shfl_xor(s, 2, 64);
  if (seg == 0) Q0g[p] = s;
}

template <int FIRST>
__global__ __launch_bounds__(256, 5) void k_round(
    const float* __restrict__ hin,
    float* __restrict__ hout,
    const float* __restrict__ bond_list,
    const int* __restrict__ adeg, const int* __restrict__ bdeg,
    const float* __restrict__ nbr_w, const float* __restrict__ nbr_b,
    const short* __restrict__ APg,
    const float* __restrict__ ab,
    const float* __restrict__ awN,
    const float* __restrict__ tb,
    const short* __restrict__ wR,
    const float* __restrict__ bih, const float* __restrict__ bhh,
    const float* __restrict__ Pr, const float* __restrict__ Qr,
    float* __restrict__ Pw, float* __restrict__ Qw)
{
  int tid  = threadIdx.x;
  int t128 = tid & 127;
  int hf   = tid >> 7;
  int lane = tid & 63;
  int wv   = tid >> 6;
  int quad = lane >> 4;
  int col  = lane & 15;
  int a0   = blockIdx.x * NA;
  int bb   = a0 >> 7;

  const short* wihH = wR + WIH_H;
  const short* wihL = wR + WIH_L;
  const short* whhH = wR + WHH_H;
  const short* whhL = wR + WHH_L;
  const short* twH  = wR + TW_H;
  const short* twL  = wR + TW_L;

  __shared__ short hrowH[NA][136];
  __shared__ short hrowL[NA][136];
  __shared__ __align__(16) char arena[9472];       // ybar/ctx | hnrelu
  __shared__ float awNS[256];
  __shared__ float partials[256];
  __shared__ float pS[NA], qS[NPAIR], wkS[NPAIR], wsS[NA];
  __shared__ int aidxS[NPAIR];
  __shared__ int bidxS[FIRST ? NPAIR : 1];
  __shared__ float bwS[FIRST ? 2368 : 1];          // bond[96][10] | Wb[10][128] | nb[128]

  short* ybarH = (short*)arena;               // [16][136] (ctx reuses)
  short* ybarL = (short*)(arena + 4352);
  float* hnrel = (float*)arena;               // epilogue relu(hn) [16][132]

  if (tid < NPAIR) {
    int av = adeg[a0 * K_ + tid];
    aidxS[tid] = av;
    if (FIRST) { bidxS[tid] = bdeg[a0 * K_ + tid]; qS[tid] = Qr[a0 * K_ + tid]; }
    else       qS[tid] = Qr[bb * L_ + av];
  } else if (tid >= 128 && tid < 128 + NA) {
    pS[tid - 128] = Pr[a0 + (tid - 128)];
  }
  awNS[tid] = awN[tid];
  __syncthreads();

  // ---------- Prefetch ybar gather rows into registers (48 per thread) ----------
  float vf[48];
#pragma unroll
  for (int i = 0; i < 48; i++) {
    int row = aidxS[hf * 48 + i];
    if (FIRST)
      vf[i] = b2f((u16)APg[((size_t)bb * L_ + row) * D_ + t128]);
    else
      vf[i] = fmaxf(hin[((size_t)bb * L_ + row) * D_ + t128], 0.f);
  }

  // ---------- Phase 1: h rows (+ FIRST: bond/Wb staging) ----------
  if (FIRST) {
    for (int i = tid; i < 960; i += 256) {
      int p = i / 10, m = i % 10;
      bwS[p * 10 + m] = bond_list[((size_t)bb * L_ + bidxS[p]) * FB_ + m];
    }
    for (int i = tid; i < 1280; i += 256)
      bwS[960 + i] = nbr_w[(FA_ + i / 128) * D_ + (i % 128)];
    if (tid < 128) bwS[2240 + tid] = nbr_b[tid];
  }
#pragma unroll 4
  for (int i = 0; i < 8; i++) {
    int a = i * 2 + hf;
    float hv = hin[(size_t)(a0 + a) * D_ + t128];
    short hh = f2b(hv);
    hrowH[a][t128] = hh;
    hrowL[a][t128] = f2b(hv - b2f((u16)hh));
  }
  __syncthreads();

  // ---------- Softmax over K ----------
  if (tid < NA) {
    int a = tid;
    float abv = ab[0];
    float sc[K_];
    float m = -3.0e38f;
#pragma unroll
    for (int k = 0; k < K_; k++) {
      float s = lrelu(pS[a] + qS[a * K_ + k] + abv);
      if (aidxS[a * K_ + k] == PAD_) s += NEGC;
      sc[k] = s; m = fmaxf(m, s);
    }
    float es = 0.f;
#pragma unroll
    for (int k = 0; k < K_; k++) { sc[k] = expf(sc[k] - m); es += sc[k]; }
    float ws = 0.f;
#pragma unroll
    for (int k = 0; k < K_; k++) {
      float w = (aidxS[a * K_ + k] == PAD_) ? 0.f : sc[k] / es;
      wkS[a * K_ + k] = w; ws += w;
    }
    wsS[a] = ws;
  }
  __syncthreads();

  // ---------- ybar hi/lo from prefetched registers ----------
  if (FIRST) {
    const float* bondS = bwS;
    const float* WbS   = bwS + 960;
    float nbv = bwS[2240 + t128];
#pragma unroll
    for (int i = 0; i < 8; i++) {
      int a = hf * 8 + i;
      float yb = 0.f;
#pragma unroll
      for (int k = 0; k < K_; k++) {
        int p = a * K_ + k;
        float nf = vf[i * K_ + k] + nbv;
#pragma unroll
        for (int m = 0; m < 10; m++) nf += bondS[p * 10 + m] * WbS[m * 128 + t128];
        yb += wkS[p] * lrelu(nf);
      }
      short yh = f2b(yb);
      ybarH[a * 136 + t128] = yh;
      ybarL[a * 136 + t128] = f2b(yb - b2f((u16)yh));
    }
  } else {
#pragma unroll
    for (int i = 0; i < 8; i++) {
      int a = hf * 8 + i;
      float yb = 0.f;
#pragma unroll
      for (int k = 0; k < K_; k++)
        yb += wkS[a * K_ + k] * vf[i * K_ + k];
      short yh = f2b(yb);
      ybarH[a * 136 + t128] = yh;
      ybarL[a * 136 + t128] = f2b(yb - b2f((u16)yh));
    }
  }
  __syncthreads();

  // ---------- ctx = elu(ybar @ twT^T + wsum*tb), split MFMA (swizzled B) ----------
  {
    f4 c2[2] = {};
#pragma unroll
    for (int k0c = 0; k0c < 4; k0c++) {
      s8 ayh = *(const s8*)&ybarH[col * 136 + k0c * 32 + quad * 8];
      s8 ayl = *(const s8*)&ybarL[col * 136 + k0c * 32 + quad * 8];
#pragma unroll
      for (int t = 0; t < 2; t++) {
        int gt = 2 * wv + t;
        int fo = ((gt * 4 + k0c) * 64 + lane) * 8;
        s8 bwh = *(const s8*)&twH[fo];
        s8 bwl = *(const s8*)&twL[fo];
        c2[t] = __builtin_amdgcn_mfma_f32_16x16x32_bf16(ayh, bwh, c2[t], 0, 0, 0);
        c2[t] = __builtin_amdgcn_mfma_f32_16x16x32_bf16(ayl, bwh, c2[t], 0, 0, 0);
        c2[t] = __builtin_amdgcn_mfma_f32_16x16x32_bf16(ayh, bwl, c2[t], 0, 0, 0);
      }
    }
    __syncthreads();
#pragma unroll
    for (int t = 0; t < 2; t++) {
      int g = (2 * wv + t) * 16 + col;
      float tbv = tb[g];
#pragma unroll
      for (int r = 0; r < 4; r++) {
        int a = quad * 4 + r;
        float c = eluf(c2[t][r] + wsS[a] * tbv);
        short chs = f2b(c);
        ybarH[a * 136 + g] = chs;                    // ctxH
        ybarL[a * 136 + g] = f2b(c - b2f((u16)chs)); // ctxL
      }
    }
  }
  __syncthreads();

  // ---------- GRU via split MFMA (swizzled B) ----------
  {
    const short* ctxH = ybarH;
    const short* ctxL = ybarL;
    f4 gi[2][3] = {}, gh[2][3] = {};
#pragma unroll
    for (int k0c = 0; k0c < 4; k0c++) {
      s8 ach = *(const s8*)&ctxH[col * 136 + k0c * 32 + quad * 8];
      s8 acl = *(const s8*)&ctxL[col * 136 + k0c * 32 + quad * 8];
      s8 ahh = *(const s8*)&hrowH[col][k0c * 32 + quad * 8];
      s8 ahl = *(const s8*)&hrowL[col][k0c * 32 + quad * 8];
#pragma unroll
      for (int t = 0; t < 2; t++) {
#pragma unroll
        for (int kd = 0; kd < 3; kd++) {
          int gt = (2 * wv + t) + kd * 8;
          int fo = ((gt * 4 + k0c) * 64 + lane) * 8;
          s8 bi_h = *(const s8*)&wihH[fo];
          s8 bi_l = *(const s8*)&wihL[fo];
          s8 bh_h = *(const s8*)&whhH[fo];
          s8 bh_l = *(const s8*)&whhL[fo];
          gi[t][kd] = __builtin_amdgcn_mfma_f32_16x16x32_bf16(ach, bi_h, gi[t][kd], 0, 0, 0);
          gi[t][kd] = __builtin_amdgcn_mfma_f32_16x16x32_bf16(acl, bi_h, gi[t][kd], 0, 0, 0);
          gi[t][kd] = __builtin_amdgcn_mfma_f32_16x16x32_bf16(ach, bi_l, gi[t][kd], 0, 0, 0);
          gh[t][kd] = __builtin_amdgcn_mfma_f32_16x16x32_bf16(ahh, bh_h, gh[t][kd], 0, 0, 0);
          gh[t][kd] = __builtin_amdgcn_mfma_f32_16x16x32_bf16(ahl, bh_h, gh[t][kd], 0, 0, 0);
          gh[t][kd] = __builtin_amdgcn_mfma_f32_16x16x32_bf16(ahh, bh_l, gh[t][kd], 0, 0, 0);
        }
      }
    }
    __syncthreads();

#pragma unroll
    for (int t = 0; t < 2; t++) {
      int ic = (2 * wv + t) * 16 + col;
      float bi0 = bih[ic], bi1 = bih[D_ + ic], bi2 = bih[2 * D_ + ic];
      float bh0 = bhh[ic], bh1 = bhh[D_ + ic], bh2 = bhh[2 * D_ + ic];
#pragma unroll
      for (int r = 0; r < 4; r++) {
        int a = quad * 4 + r;
        float rr = sigm(gi[t][0][r] + bi0 + gh[t][0][r] + bh0);
        float zz = sigm(gi[t][1][r] + bi1 + gh[t][1][r] + bh1);
        float nn = tanhf(gi[t][2][r] + bi2 + rr * (gh[t][2][r] + bh2));
        float hv = b2f((u16)hrowH[a][ic]) + b2f((u16)hrowL[a][ic]);
        float hn = (1.f - zz) * nn + zz * hv;
        hout[(size_t)(a0 + a) * D_ + ic] = hn;
        if (Pw) hnrel[a * 132 + ic] = fmaxf(hn, 0.f);
      }
    }
  }

  // ---------- Epilogue: P/Q for next round (skipped on last round) ----------
  if (Pw) {
    __syncthreads();
    {
      int a = tid >> 4, dt = (tid >> 3) & 1, seg = tid & 7;
      float s = 0.f;
#pragma unroll
      for (int j = 0; j < 16; j++)
        s += hnrel[a * 132 + seg * 16 + j] * awNS[dt * 128 + seg * 16 + j];
      partials[tid] = s;
    }
    __syncthreads();
    if (tid < 32) {
      int a = tid >> 1, dt = tid & 1;
      float s = 0.f;
#pragma unroll
      for (int seg = 0; seg < 8; seg++) s += partials[a * 16 + dt * 8 + seg];
      if (dt) Qw[a0 + a] = s; else Pw[a0 + a] = s;
    }
  }
}

__global__ __launch_bounds__(512) void k_mol(
    const float* __restrict__ hfin,
    float* __restrict__ hcopy,
    const float* __restrict__ amask,
    const float* __restrict__ maw, const float* __restrict__ mab,
    const float* __restrict__ mtw, const float* __restrict__ mtb,
    const float* __restrict__ wih_t, const float* __restrict__ whh_t,
    const float* __restrict__ bih, const float* __restrict__ bhh,
    const float* __restrict__ ow, const float* __restrict__ ob,
    float* __restrict__ pred)
{
  int b = blockIdx.x;
  int tid = threadIdx.x;
  int t128 = tid & 127;
  int qf = tid >> 7;           // quarter 0..3
  __shared__ float actS[L_][D_ + 1];
  __shared__ float red[512];
  __shared__ float par4[4][132];
  __shared__ float pg[3][6][132];
  __shared__ float wgt[128], ybv[132], ctx[132], mfS[132], amol[132];
  __shared__ float msk[128], mawh[128], scf[128];

  if (qf == 0) { msk[t128] = amask[b * L_ + t128]; mawh[t128] = maw[D_ + t128]; }
  for (int i = 0; i < 32; i++) {
    int l = qf * 32 + i;
    float hv = hfin[(size_t)(b * L_ + l) * D_ + t128];
    hcopy[(size_t)(b * L_ + l) * D_ + t128] = hv;
    actS[l][t128] = fmaxf(hv, 0.f);
  }
  __syncthreads();

  // mol_feature (l-split quarters)
  {
    float s = 0.f;
    for (int i = 0; i < 32; i++) { int l = qf * 32 + i; s += actS[l][t128] * msk[l]; }
    par4[qf][t128] = s;
  }
  __syncthreads();
  if (qf == 0) {
    float mf = par4[0][t128] + par4[1][t128] + par4[2][t128] + par4[3][t128];
    mfS[t128] = mf; amol[t128] = fmaxf(mf, 0.f);
  }
  __syncthreads();

  float mabv = mab[0];

  for (int t = 0; t < 2; t++) {
    // s0
    red[tid] = (tid < 128) ? amol[tid] * maw[tid] : 0.f;
    __syncthreads();
    for (int s = 256; s > 0; s >>= 1) { if (tid < s) red[tid] += red[tid + s]; __syncthreads(); }
    float s0 = red[0]; __syncthreads();

    // sc[l=t128] (j-split quarters)
    {
      float s = 0.f;
      for (int i = 0; i < 32; i++) { int j = qf * 32 + i; s += actS[t128][j] * mawh[j]; }
      par4[qf][t128] = s;
    }
    __syncthreads();
    if (qf == 0) {
      float sc = lrelu(s0 + mabv + par4[0][t128] + par4[1][t128] + par4[2][t128] + par4[3][t128]);
      if (msk[t128] == 0.f) sc += NEGC;
      scf[t128] = sc;
    }
    __syncthreads();

    // softmax over l
    float scv = scf[t128];
    red[tid] = (tid < 128) ? scv : -3.0e38f;
    __syncthreads();
    for (int s = 256; s > 0; s >>= 1) { if (tid < s) red[tid] = fmaxf(red[tid], red[tid + s]); __syncthreads(); }
    float mx = red[0]; __syncthreads();
    float e = expf(scv - mx);
    red[tid] = (tid < 128) ? e : 0.f;
    __syncthreads();
    for (int s = 256; s > 0; s >>= 1) { if (tid < s) red[tid] += red[tid + s]; __syncthreads(); }
    float es = red[0]; __syncthreads();
    float w = (e / es) * msk[t128];
    if (qf == 0) wgt[t128] = w;
    red[tid] = (tid < 128) ? w : 0.f;
    __syncthreads();
    for (int s = 256; s > 0; s >>= 1) { if (tid < s) red[tid] += red[tid + s]; __syncthreads(); }
    float wsum = red[0]; __syncthreads();

    // y[j=t128] (l-split quarters)
    {
      float s = 0.f;
      for (int i = 0; i < 32; i++) { int l = qf * 32 + i; s += wgt[l] * actS[l][t128]; }
      par4[qf][t128] = s;
    }
    __syncthreads();
    if (qf == 0) ybv[t128] = par4[0][t128] + par4[1][t128] + par4[2][t128] + par4[3][t128];
    __syncthreads();

    // ctx[g=t128] (j-split quarters)
    {
      float s = 0.f;
#pragma unroll 2
      for (int i = 0; i < 32; i++) { int j = qf * 32 + i; s += ybv[j] * mtw[j * D_ + t128]; }
      par4[qf][t128] = s;
    }
    __syncthreads();
    if (qf == 0)
      ctx[t128] = eluf(par4[0][t128] + par4[1][t128] + par4[2][t128] + par4[3][t128]
                       + wsum * mtb[t128]);
    __syncthreads();

    // GRU (j-split quarters, x-stationary)
    {
      float gi0 = 0, gi1 = 0, gi2 = 0, gh0 = 0, gh1 = 0, gh2 = 0;
#pragma unroll 2
      for (int i = 0; i < 32; i++) {
        int j = qf * 32 + i;
        const float* wi = wih_t + (size_t)j * 384;
        const float* wh = whh_t + (size_t)j * 384;
        float xc = ctx[j], xh = mfS[j];
        gi0 += xc * wi[t128]; gi1 += xc * wi[128 + t128]; gi2 += xc * wi[256 + t128];
        gh0 += xh * wh[t128]; gh1 += xh * wh[128 + t128]; gh2 += xh * wh[256 + t128];
      }
      if (qf > 0) {
        pg[qf - 1][0][t128] = gi0; pg[qf - 1][1][t128] = gi1; pg[qf - 1][2][t128] = gi2;
        pg[qf - 1][3][t128] = gh0; pg[qf - 1][4][t128] = gh1; pg[qf - 1][5][t128] = gh2;
      }
      __syncthreads();
      if (qf == 0) {
        gi0 += pg[0][0][t128] + pg[1][0][t128] + pg[2][0][t128] + bih[t128];
        gi1 += pg[0][1][t128] + pg[1][1][t128] + pg[2][1][t128] + bih[128 + t128];
        gi2 += pg[0][2][t128] + pg[1][2][t128] + pg[2][2][t128] + bih[256 + t128];
        gh0 += pg[0][3][t128] + pg[1][3][t128] + pg[2][3][t128] + bhh[t128];
        gh1 += pg[0][4][t128] + pg[1][4][t128] + pg[2][4][t128] + bhh[128 + t128];
        gh2 += pg[0][5][t128] + pg[1][5][t128] + pg[2][5][t128] + bhh[256 + t128];
        float r = sigm(gi0 + gh0);
        float z = sigm(gi1 + gh1);
        float n = tanhf(gi2 + r * gh2);
        float hn = (1.f - z) * n + z * mfS[t128];
        mfS[t128] = hn;
        amol[t128] = fmaxf(hn, 0.f);
      }
      __syncthreads();
    }
  }

  red[tid] = (tid < 128) ? mfS[tid] * ow[tid] : 0.f;
  __syncthreads();
  for (int s = 256; s > 0; s >>= 1) { if (tid < s) red[tid] += red[tid + s]; __syncthreads(); }
  if (tid == 0) pred[b] = red[0] + ob[0];
}

extern "C" void kernel_launch(void* const* d_in, const int* in_sizes, int n_in,
                              void* d_out, int out_size, void* d_ws, size_t ws_size,
                              hipStream_t stream) {
  const float* atom_list    = (const float*)d_in[0];
  const float* bond_list    = (const float*)d_in[1];
  const float* atom_mask    = (const float*)d_in[2];
  const float* atom_fc_w    = (const float*)d_in[3];
  const float* atom_fc_b    = (const float*)d_in[4];
  const float* nbr_fc_w     = (const float*)d_in[5];
  const float* nbr_fc_b     = (const float*)d_in[6];
  const float* align_w      = (const float*)d_in[7];
  const float* align_b      = (const float*)d_in[8];
  const float* attend_w     = (const float*)d_in[9];
  const float* attend_b     = (const float*)d_in[10];
  const float* gru_wih      = (const float*)d_in[11];
  const float* gru_whh      = (const float*)d_in[12];
  const float* gru_bih      = (const float*)d_in[13];
  const float* gru_bhh      = (const float*)d_in[14];
  const float* mol_align_w  = (const float*)d_in[15];
  const float* mol_align_b  = (const float*)d_in[16];
  const float* mol_attend_w = (const float*)d_in[17];
  const float* mol_attend_b = (const float*)d_in[18];
  const float* mol_gru_wih  = (const float*)d_in[19];
  const float* mol_gru_whh  = (const float*)d_in[20];
  const float* mol_gru_bih  = (const float*)d_in[21];
  const float* mol_gru_bhh  = (const float*)d_in[22];
  const float* out_w        = (const float*)d_in[23];
  const float* out_b        = (const float*)d_in[24];
  const int*   adeg         = (const int*)d_in[25];
  const int*   bdeg         = (const int*)d_in[26];

  const size_t NH = (size_t)B_ * L_ * D_;
  float* hW   = (float*)d_ws;            // 16 MB
  short* wB   = (short*)(hW + NH);       // 1.38 MB
  float* molT = (float*)(wB + NB16);     // 0.39 MB
  short* APg  = (short*)(molT + NMOLF);  // NH shorts = 8.39 MB
  float* Q0g  = (float*)(APg + NH);      // B*L*K floats = 0.79 MB
  float* PgA  = Q0g + (size_t)B_ * L_ * K_;
  float* QgA  = PgA + B_ * L_;
  float* PgB  = QgA + B_ * L_;
  float* QgB  = PgB + B_ * L_;
  float* hOut = (float*)d_out;
  float* pred = hOut + NH;

  k_tr<<<dim3((NB16 + NMOLF + 255) / 256), dim3(256), 0, stream>>>(
      gru_wih, gru_whh, attend_w, mol_gru_wih, mol_gru_whh, wB, molT);

  k_pre<<<dim3(B_ * L_ / 16), dim3(128), 0, stream>>>(
      atom_list, atom_fc_w, atom_fc_b, nbr_fc_w, align_w, hOut, APg, PgA);
  k_q0<<<dim3(B_ * L_ * K_ / 64), dim3(256), 0, stream>>>(
      bond_list, nbr_fc_w, nbr_fc_b, align_w, adeg, bdeg, APg, Q0g);

  dim3 blk(256), grd(B_ * L_ / NA);

  // r0: hOut(h0) -> hW ; r1: hW -> hOut ; r2: hOut -> hW
  k_round<1><<<grd, blk, 0, stream>>>(
      hOut, hW, bond_list, adeg, bdeg, nbr_fc_w, nbr_fc_b, APg,
      align_b, align_w + 2 * D_, attend_b,
      wB + 0 * (size_t)RND_BLK2, gru_bih, gru_bhh,
      PgA, Q0g, PgB, QgB);
  k_round<0><<<grd, blk, 0, stream>>>(
      hW, hOut, bond_list, adeg, bdeg, nbr_fc_w, nbr_fc_b, APg,
      align_b + 1, align_w + 4 * D_, attend_b + D_,
      wB + 1 * (size_t)RND_BLK2, gru_bih + 3 * D_, gru_bhh + 3 * D_,
      PgB, QgB, PgA, QgA);
  k_round<0><<<grd, blk, 0, stream>>>(
      hOut, hW, bond_list, adeg, bdeg, nbr_fc_w, nbr_fc_b, APg,
      align_b + 2, align_w + 4 * D_, attend_b + 2 * D_,
      wB + 2 * (size_t)RND_BLK2, gru_bih + 6 * D_, gru_bhh + 6 * D_,
      PgA, QgA, (float*)nullptr, (float*)nullptr);

  k_mol<<<dim3(B_), dim3(512), 0, stream>>>(
      hW, hOut, atom_mask, mol_align_w, mol_align_b, mol_attend_w, mol_attend_b,
      molT, molT + 128 * 384,
      mol_gru_bih, mol_gru_bhh, out_w, out_b, pred);
}

// Round 12
// 445.714 us; speedup vs baseline: 27.7463x; 1.0448x over previous
//
#include <hip/hip_runtime.h>
#include <cstddef>

// AttentiveFP forward. B=256 L=128 K=6 FA=39 FB=10 D=128 R=3 T=2. fp32 I/O.
// MFMA bf16 split precision (hi+lo) for ctx/GRU GEMMs; h carried fp32.
// Weights FRAG-SWIZZLED (lane-contiguous B-fragments, 1024B/wave loads).
// k_pre/k_q0 hoist round-0 specials; P/Q score dots precomputed.
// Gather rows loaded inline in ybar phase (NO register prefetch — it spills).
// k_mol: 512 threads, quarter-split loops.

#define B_ 256
#define L_ 128
#define K_ 6
#define FA_ 39
#define FB_ 10
#define D_ 128
#define PAD_ 127
#define NEGC (-9.0e8f)
#define NA 16
#define NPAIR (NA * K_)   // 96

typedef unsigned short u16;
typedef unsigned int u32;
using s8 = __attribute__((ext_vector_type(8))) short;   // 8 x bf16
using f4 = __attribute__((ext_vector_type(4))) float;   // MFMA acc

#define WIH_H 0
#define WIH_L 49152
#define WHH_H 98304
#define WHH_L 147456
#define TW_H  196608
#define TW_L  212992
#define RND_BLK2 229376
#define NB16 (3 * RND_BLK2)
#define NMOLF (2 * 128 * 384)

__device__ __forceinline__ float lrelu(float x) { return x > 0.f ? x : 0.01f * x; }
__device__ __forceinline__ float eluf(float x)  { return x > 0.f ? x : expm1f(x); }
__device__ __forceinline__ float sigm(float x)  { return 1.f / (1.f + expf(-x)); }
__device__ __forceinline__ float b2f(u16 u) {
  union { u32 i; float f; } v; v.i = ((u32)u) << 16; return v.f;
}
__device__ __forceinline__ short f2b(float f) {  // RNE
  union { float f; u32 i; } v; v.f = f;
  u32 x = v.i;
  return (short)(u16)((x + 0x7FFFu + ((x >> 16) & 1u)) >> 16);
}

// Build frag-swizzled split bf16 weights + fp32 transposed mol GRU weights.
// Swizzle: element ((gt*4+kc)*64+lane)*8+j  <=  W[gt*16+(lane&15)][kc*32+(lane>>4)*8+j]
__global__ __launch_bounds__(256) void k_tr(
    const float* __restrict__ gwih, const float* __restrict__ gwhh,
    const float* __restrict__ attw,
    const float* __restrict__ mwih, const float* __restrict__ mwhh,
    short* __restrict__ wB, float* __restrict__ molT) {
  int idx = blockIdx.x * 256 + threadIdx.x;
  if (idx < NB16) {
    int r = idx / RND_BLK2, o = idx % RND_BLK2;
    float v; int lo;
    int e, kind;          // kind 0=wih, 1=whh, 2=tw
    if (o < 98304)      { kind = 0; lo = o / 49152; e = o % 49152; }
    else if (o < 196608){ kind = 1; int o2 = o - 98304; lo = o2 / 49152; e = o2 % 49152; }
    else                { kind = 2; int o2 = o - 196608; lo = o2 / 16384; e = o2 % 16384; }
    int gt = e >> 11, rem = e & 2047;
    int kc = rem >> 9, rem2 = rem & 511;
    int lane = rem2 >> 3, j = rem2 & 7;
    int col = lane & 15, quad = lane >> 4;
    int g = gt * 16 + col;
    int k = kc * 32 + quad * 8 + j;
    if (kind == 0)      v = gwih[(size_t)r * 49152 + g * 128 + k];
    else if (kind == 1) v = gwhh[(size_t)r * 49152 + g * 128 + k];
    else                v = attw[(size_t)r * 16384 + k * 128 + g];
    short hi = f2b(v);
    wB[idx] = lo ? f2b(v - b2f((u16)hi)) : hi;
  } else if (idx < NB16 + NMOLF) {
    int e2 = idx - NB16;
    int m = e2 / 49152, e = e2 % 49152, j = e / 384, g = e % 384;
    molT[e2] = (m ? mwhh : mwih)[g * 128 + j];
  }
}

// Per-atom precompute: h0, AP = atom@Wa (bf16), P0 = h0.awlo0.
__global__ __launch_bounds__(128) void k_pre(
    const float* __restrict__ atom_list,
    const float* __restrict__ afc_w, const float* __restrict__ afc_b,
    const float* __restrict__ nbr_w,
    const float* __restrict__ aw0,
    float* __restrict__ h0out, short* __restrict__ APg, float* __restrict__ PgA)
{
  int tid = threadIdx.x;
  int a0 = blockIdx.x * 16;
  __shared__ float xa[16 * 40];
  __shared__ float h0S[16][132];
  __shared__ float awS[128];
  __shared__ float partials[128];

  for (int i = tid; i < 16 * FA_; i += 128) {
    int a = i / FA_, c = i % FA_;
    xa[a * 40 + c] = atom_list[((size_t)(a0 + a)) * FA_ + c];
  }
  awS[tid] = aw0[tid];
  __syncthreads();

  {
    float acc[16];
    float bv = afc_b[tid];
#pragma unroll
    for (int a = 0; a < 16; a++) acc[a] = bv;
#pragma unroll 2
    for (int j = 0; j < FA_; j++) {
      float w = afc_w[j * D_ + tid];
#pragma unroll
      for (int a = 0; a < 16; a++) acc[a] += xa[a * 40 + j] * w;
    }
#pragma unroll
    for (int a = 0; a < 16; a++) {
      float hv = lrelu(acc[a]);
      h0out[(size_t)(a0 + a) * D_ + tid] = hv;
      h0S[a][tid] = hv;
    }
  }
  {
    float acc[16];
#pragma unroll
    for (int a = 0; a < 16; a++) acc[a] = 0.f;
#pragma unroll 2
    for (int j = 0; j < FA_; j++) {
      float w = nbr_w[j * D_ + tid];
#pragma unroll
      for (int a = 0; a < 16; a++) acc[a] += xa[a * 40 + j] * w;
    }
#pragma unroll
    for (int a = 0; a < 16; a++)
      APg[(size_t)(a0 + a) * D_ + tid] = f2b(acc[a]);
  }
  __syncthreads();
  {
    int a = tid >> 3, seg = tid & 7;
    float s = 0.f;
#pragma unroll
    for (int j = 0; j < 16; j++) s += h0S[a][seg * 16 + j] * awS[seg * 16 + j];
    partials[tid] = s;
  }
  __syncthreads();
  if (tid < 16) {
    float s = 0.f;
#pragma unroll
    for (int g = 0; g < 8; g++) s += partials[tid * 8 + g];
    PgA[a0 + tid] = s;
  }
}

// Per-pair Q0 = sum_d lrelu(AP[aidx]+bond[bidx]@Wb+nb) * awhi0.
__global__ __launch_bounds__(256) void k_q0(
    const float* __restrict__ bond_list,
    const float* __restrict__ nbr_w, const float* __restrict__ nbr_b,
    const float* __restrict__ aw0,
    const int* __restrict__ adeg, const int* __restrict__ bdeg,
    const short* __restrict__ APg, float* __restrict__ Q0g)
{
  int tid = threadIdx.x;
  __shared__ float WbS[10 * 128];
  __shared__ float nbS[128], ahS[128];
  for (int i = tid; i < 10 * 128; i += 256)
    WbS[i] = nbr_w[(FA_ + i / 128) * D_ + (i % 128)];
  if (tid < 128) { nbS[tid] = nbr_b[tid]; ahS[tid] = aw0[D_ + tid]; }
  __syncthreads();

  int p = blockIdx.x * 64 + (tid >> 2);
  int seg = tid & 3;
  int aidx = adeg[p], bidx = bdeg[p];
  int bb = p / (L_ * K_);
  const short* rowA = APg + ((size_t)bb * L_ + aidx) * D_;
  const float* brow = bond_list + ((size_t)bb * L_ + bidx) * FB_;
  float bnd[10];
#pragma unroll
  for (int m = 0; m < 10; m++) bnd[m] = brow[m];
  float s = 0.f;
  int j0 = seg * 32;
#pragma unroll 4
  for (int j = j0; j < j0 + 32; j++) {
    float v = b2f((u16)rowA[j]) + nbS[j];
#pragma unroll
    for (int m = 0; m < 10; m++) v += bnd[m] * WbS[m * 128 + j];
    s += lrelu(v) * ahS[j];
  }
  s += __shfl_xor(s, 1, 64);
  s += __shfl_xor(s, 2, 64);
  if (seg == 0) Q0g[p] = s;
}

template <int FIRST>
__global__ __launch_bounds__(256, 5) void k_round(
    const float* __restrict__ hin,
    float* __restrict__ hout,
    const float* __restrict__ bond_list,
    const int* __restrict__ adeg, const int* __restrict__ bdeg,
    const float* __restrict__ nbr_w, const float* __restrict__ nbr_b,
    const short* __restrict__ APg,
    const float* __restrict__ ab,
    const float* __restrict__ awN,
    const float* __restrict__ tb,
    const short* __restrict__ wR,
    const float* __restrict__ bih, const float* __restrict__ bhh,
    const float* __restrict__ Pr, const float* __restrict__ Qr,
    float* __restrict__ Pw, float* __restrict__ Qw)
{
  int tid  = threadIdx.x;
  int t128 = tid & 127;
  int hf   = tid >> 7;
  int lane = tid & 63;
  int wv   = tid >> 6;
  int quad = lane >> 4;
  int col  = lane & 15;
  int a0   = blockIdx.x * NA;
  int bb   = a0 >> 7;

  const short* wihH = wR + WIH_H;
  const short* wihL = wR + WIH_L;
  const short* whhH = wR + WHH_H;
  const short* whhL = wR + WHH_L;
  const short* twH  = wR + TW_H;
  const short* twL  = wR + TW_L;

  __shared__ short hrowH[NA][136];
  __shared__ short hrowL[NA][136];
  __shared__ __align__(16) char arena[9472];       // ybar/ctx | hnrelu
  __shared__ float awNS[256];
  __shared__ float partials[256];
  __shared__ float pS[NA], qS[NPAIR], wkS[NPAIR], wsS[NA];
  __shared__ int aidxS[NPAIR];
  __shared__ int bidxS[FIRST ? NPAIR : 1];
  __shared__ float bwS[FIRST ? 2368 : 1];          // bond[96][10] | Wb[10][128] | nb[128]

  short* ybarH = (short*)arena;               // [16][136] (ctx reuses)
  short* ybarL = (short*)(arena + 4352);
  float* hnrel = (float*)arena;               // epilogue relu(hn) [16][132]

  if (tid < NPAIR) {
    int av = adeg[a0 * K_ + tid];
    aidxS[tid] = av;
    if (FIRST) { bidxS[tid] = bdeg[a0 * K_ + tid]; qS[tid] = Qr[a0 * K_ + tid]; }
    else       qS[tid] = Qr[bb * L_ + av];
  } else if (tid >= 128 && tid < 128 + NA) {
    pS[tid - 128] = Pr[a0 + (tid - 128)];
  }
  awNS[tid] = awN[tid];
  __syncthreads();

  // ---------- Phase 1: h rows (+ FIRST: bond/Wb staging) ----------
  if (FIRST) {
    for (int i = tid; i < 960; i += 256) {
      int p = i / 10, m = i % 10;
      bwS[p * 10 + m] = bond_list[((size_t)bb * L_ + bidxS[p]) * FB_ + m];
    }
    for (int i = tid; i < 1280; i += 256)
      bwS[960 + i] = nbr_w[(FA_ + i / 128) * D_ + (i % 128)];
    if (tid < 128) bwS[2240 + tid] = nbr_b[tid];
  }
#pragma unroll 4
  for (int i = 0; i < 8; i++) {
    int a = i * 2 + hf;
    float hv = hin[(size_t)(a0 + a) * D_ + t128];
    short hh = f2b(hv);
    hrowH[a][t128] = hh;
    hrowL[a][t128] = f2b(hv - b2f((u16)hh));
  }
  __syncthreads();

  // ---------- Softmax over K ----------
  if (tid < NA) {
    int a = tid;
    float abv = ab[0];
    float sc[K_];
    float m = -3.0e38f;
#pragma unroll
    for (int k = 0; k < K_; k++) {
      float s = lrelu(pS[a] + qS[a * K_ + k] + abv);
      if (aidxS[a * K_ + k] == PAD_) s += NEGC;
      sc[k] = s; m = fmaxf(m, s);
    }
    float es = 0.f;
#pragma unroll
    for (int k = 0; k < K_; k++) { sc[k] = expf(sc[k] - m); es += sc[k]; }
    float ws = 0.f;
#pragma unroll
    for (int k = 0; k < K_; k++) {
      float w = (aidxS[a * K_ + k] == PAD_) ? 0.f : sc[k] / es;
      wkS[a * K_ + k] = w; ws += w;
    }
    wsS[a] = ws;
  }
  __syncthreads();

  // ---------- ybar hi/lo (gather rows loaded inline) ----------
  if (FIRST) {
    const float* bondS = bwS;
    const float* WbS   = bwS + 960;
    float nbv = bwS[2240 + t128];
#pragma unroll
    for (int i = 0; i < 8; i++) {
      int a = hf * 8 + i;
      float yb = 0.f;
#pragma unroll
      for (int k = 0; k < K_; k++) {
        int p = a * K_ + k;
        float nf = b2f((u16)APg[((size_t)bb * L_ + aidxS[p]) * D_ + t128]) + nbv;
#pragma unroll
        for (int m = 0; m < 10; m++) nf += bondS[p * 10 + m] * WbS[m * 128 + t128];
        yb += wkS[p] * lrelu(nf);
      }
      short yh = f2b(yb);
      ybarH[a * 136 + t128] = yh;
      ybarL[a * 136 + t128] = f2b(yb - b2f((u16)yh));
    }
  } else {
#pragma unroll
    for (int i = 0; i < 8; i++) {
      int a = hf * 8 + i;
      float yb = 0.f;
#pragma unroll
      for (int k = 0; k < K_; k++) {
        float v = hin[((size_t)bb * L_ + aidxS[a * K_ + k]) * D_ + t128];
        yb += wkS[a * K_ + k] * fmaxf(v, 0.f);
      }
      short yh = f2b(yb);
      ybarH[a * 136 + t128] = yh;
      ybarL[a * 136 + t128] = f2b(yb - b2f((u16)yh));
    }
  }
  __syncthreads();

  // ---------- ctx = elu(ybar @ twT^T + wsum*tb), split MFMA (swizzled B) ----------
  {
    f4 c2[2] = {};
#pragma unroll
    for (int k0c = 0; k0c < 4; k0c++) {
      s8 ayh = *(const s8*)&ybarH[col * 136 + k0c * 32 + quad * 8];
      s8 ayl = *(const s8*)&ybarL[col * 136 + k0c * 32 + quad * 8];
#pragma unroll
      for (int t = 0; t < 2; t++) {
        int gt = 2 * wv + t;
        int fo = ((gt * 4 + k0c) * 64 + lane) * 8;
        s8 bwh = *(const s8*)&twH[fo];
        s8 bwl = *(const s8*)&twL[fo];
        c2[t] = __builtin_amdgcn_mfma_f32_16x16x32_bf16(ayh, bwh, c2[t], 0, 0, 0);
        c2[t] = __builtin_amdgcn_mfma_f32_16x16x32_bf16(ayl, bwh, c2[t], 0, 0, 0);
        c2[t] = __builtin_amdgcn_mfma_f32_16x16x32_bf16(ayh, bwl, c2[t], 0, 0, 0);
      }
    }
    __syncthreads();
#pragma unroll
    for (int t = 0; t < 2; t++) {
      int g = (2 * wv + t) * 16 + col;
      float tbv = tb[g];
#pragma unroll
      for (int r = 0; r < 4; r++) {
        int a = quad * 4 + r;
        float c = eluf(c2[t][r] + wsS[a] * tbv);
        short chs = f2b(c);
        ybarH[a * 136 + g] = chs;                    // ctxH
        ybarL[a * 136 + g] = f2b(c - b2f((u16)chs)); // ctxL
      }
    }
  }
  __syncthreads();

  // ---------- GRU via split MFMA (swizzled B) ----------
  {
    const short* ctxH = ybarH;
    const short* ctxL = ybarL;
    f4 gi[2][3] = {}, gh[2][3] = {};
#pragma unroll
    for (int k0c = 0; k0c < 4; k0c++) {
      s8 ach = *(const s8*)&ctxH[col * 136 + k0c * 32 + quad * 8];
      s8 acl = *(const s8*)&ctxL[col * 136 + k0c * 32 + quad * 8];
      s8 ahh = *(const s8*)&hrowH[col][k0c * 32 + quad * 8];
      s8 ahl = *(const s8*)&hrowL[col][k0c * 32 + quad * 8];
#pragma unroll
      for (int t = 0; t < 2; t++) {
#pragma unroll
        for (int kd = 0; kd < 3; kd++) {
          int gt = (2 * wv + t) + kd * 8;
          int fo = ((gt * 4 + k0c) * 64 + lane) * 8;
          s8 bi_h = *(const s8*)&wihH[fo];
          s8 bi_l = *(const s8*)&wihL[fo];
          s8 bh_h = *(const s8*)&whhH[fo];
          s8 bh_l = *(const s8*)&whhL[fo];
          gi[t][kd] = __builtin_amdgcn_mfma_f32_16x16x32_bf16(ach, bi_h, gi[t][kd], 0, 0, 0);
          gi[t][kd] = __builtin_amdgcn_mfma_f32_16x16x32_bf16(acl, bi_h, gi[t][kd], 0, 0, 0);
          gi[t][kd] = __builtin_amdgcn_mfma_f32_16x16x32_bf16(ach, bi_l, gi[t][kd], 0, 0, 0);
          gh[t][kd] = __builtin_amdgcn_mfma_f32_16x16x32_bf16(ahh, bh_h, gh[t][kd], 0, 0, 0);
          gh[t][kd] = __builtin_amdgcn_mfma_f32_16x16x32_bf16(ahl, bh_h, gh[t][kd], 0, 0, 0);
          gh[t][kd] = __builtin_amdgcn_mfma_f32_16x16x32_bf16(ahh, bh_l, gh[t][kd], 0, 0, 0);
        }
      }
    }
    __syncthreads();

#pragma unroll
    for (int t = 0; t < 2; t++) {
      int ic = (2 * wv + t) * 16 + col;
      float bi0 = bih[ic], bi1 = bih[D_ + ic], bi2 = bih[2 * D_ + ic];
      float bh0 = bhh[ic], bh1 = bhh[D_ + ic], bh2 = bhh[2 * D_ + ic];
#pragma unroll
      for (int r = 0; r < 4; r++) {
        int a = quad * 4 + r;
        float rr = sigm(gi[t][0][r] + bi0 + gh[t][0][r] + bh0);
        float zz = sigm(gi[t][1][r] + bi1 + gh[t][1][r] + bh1);
        float nn = tanhf(gi[t][2][r] + bi2 + rr * (gh[t][2][r] + bh2));
        float hv = b2f((u16)hrowH[a][ic]) + b2f((u16)hrowL[a][ic]);
        float hn = (1.f - zz) * nn + zz * hv;
        hout[(size_t)(a0 + a) * D_ + ic] = hn;
        if (Pw) hnrel[a * 132 + ic] = fmaxf(hn, 0.f);
      }
    }
  }

  // ---------- Epilogue: P/Q for next round (skipped on last round) ----------
  if (Pw) {
    __syncthreads();
    {
      int a = tid >> 4, dt = (tid >> 3) & 1, seg = tid & 7;
      float s = 0.f;
#pragma unroll
      for (int j = 0; j < 16; j++)
        s += hnrel[a * 132 + seg * 16 + j] * awNS[dt * 128 + seg * 16 + j];
      partials[tid] = s;
    }
    __syncthreads();
    if (tid < 32) {
      int a = tid >> 1, dt = tid & 1;
      float s = 0.f;
#pragma unroll
      for (int seg = 0; seg < 8; seg++) s += partials[a * 16 + dt * 8 + seg];
      if (dt) Qw[a0 + a] = s; else Pw[a0 + a] = s;
    }
  }
}

__global__ __launch_bounds__(512) void k_mol(
    const float* __restrict__ hfin,
    float* __restrict__ hcopy,
    const float* __restrict__ amask,
    const float* __restrict__ maw, const float* __restrict__ mab,
    const float* __restrict__ mtw, const float* __restrict__ mtb,
    const float* __restrict__ wih_t, const float* __restrict__ whh_t,
    const float* __restrict__ bih, const float* __restrict__ bhh,
    const float* __restrict__ ow, const float* __restrict__ ob,
    float* __restrict__ pred)
{
  int b = blockIdx.x;
  int tid = threadIdx.x;
  int t128 = tid & 127;
  int qf = tid >> 7;           // quarter 0..3
  __shared__ float actS[L_][D_ + 1];
  __shared__ float red[512];
  __shared__ float par4[4][132];
  __shared__ float pg[3][6][132];
  __shared__ float wgt[128], ybv[132], ctx[132], mfS[132], amol[132];
  __shared__ float msk[128], mawh[128], scf[128];

  if (qf == 0) { msk[t128] = amask[b * L_ + t128]; mawh[t128] = maw[D_ + t128]; }
  for (int i = 0; i < 32; i++) {
    int l = qf * 32 + i;
    float hv = hfin[(size_t)(b * L_ + l) * D_ + t128];
    hcopy[(size_t)(b * L_ + l) * D_ + t128] = hv;
    actS[l][t128] = fmaxf(hv, 0.f);
  }
  __syncthreads();

  // mol_feature (l-split quarters)
  {
    float s = 0.f;
    for (int i = 0; i < 32; i++) { int l = qf * 32 + i; s += actS[l][t128] * msk[l]; }
    par4[qf][t128] = s;
  }
  __syncthreads();
  if (qf == 0) {
    float mf = par4[0][t128] + par4[1][t128] + par4[2][t128] + par4[3][t128];
    mfS[t128] = mf; amol[t128] = fmaxf(mf, 0.f);
  }
  __syncthreads();

  float mabv = mab[0];

  for (int t = 0; t < 2; t++) {
    // s0
    red[tid] = (tid < 128) ? amol[tid] * maw[tid] : 0.f;
    __syncthreads();
    for (int s = 256; s > 0; s >>= 1) { if (tid < s) red[tid] += red[tid + s]; __syncthreads(); }
    float s0 = red[0]; __syncthreads();

    // sc[l=t128] (j-split quarters)
    {
      float s = 0.f;
      for (int i = 0; i < 32; i++) { int j = qf * 32 + i; s += actS[t128][j] * mawh[j]; }
      par4[qf][t128] = s;
    }
    __syncthreads();
    if (qf == 0) {
      float sc = lrelu(s0 + mabv + par4[0][t128] + par4[1][t128] + par4[2][t128] + par4[3][t128]);
      if (msk[t128] == 0.f) sc += NEGC;
      scf[t128] = sc;
    }
    __syncthreads();

    // softmax over l
    float scv = scf[t128];
    red[tid] = (tid < 128) ? scv : -3.0e38f;
    __syncthreads();
    for (int s = 256; s > 0; s >>= 1) { if (tid < s) red[tid] = fmaxf(red[tid], red[tid + s]); __syncthreads(); }
    float mx = red[0]; __syncthreads();
    float e = expf(scv - mx);
    red[tid] = (tid < 128) ? e : 0.f;
    __syncthreads();
    for (int s = 256; s > 0; s >>= 1) { if (tid < s) red[tid] += red[tid + s]; __syncthreads(); }
    float es = red[0]; __syncthreads();
    float w = (e / es) * msk[t128];
    if (qf == 0) wgt[t128] = w;
    red[tid] = (tid < 128) ? w : 0.f;
    __syncthreads();
    for (int s = 256; s > 0; s >>= 1) { if (tid < s) red[tid] += red[tid + s]; __syncthreads(); }
    float wsum = red[0]; __syncthreads();

    // y[j=t128] (l-split quarters)
    {
      float s = 0.f;
      for (int i = 0; i < 32; i++) { int l = qf * 32 + i; s += wgt[l] * actS[l][t128]; }
      par4[qf][t128] = s;
    }
    __syncthreads();
    if (qf == 0) ybv[t128] = par4[0][t128] + par4[1][t128] + par4[2][t128] + par4[3][t128];
    __syncthreads();

    // ctx[g=t128] (j-split quarters)
    {
      float s = 0.f;
#pragma unroll 2
      for (int i = 0; i < 32; i++) { int j = qf * 32 + i; s += ybv[j] * mtw[j * D_ + t128]; }
      par4[qf][t128] = s;
    }
    __syncthreads();
    if (qf == 0)
      ctx[t128] = eluf(par4[0][t128] + par4[1][t128] + par4[2][t128] + par4[3][t128]
                       + wsum * mtb[t128]);
    __syncthreads();

    // GRU (j-split quarters, x-stationary)
    {
      float gi0 = 0, gi1 = 0, gi2 = 0, gh0 = 0, gh1 = 0, gh2 = 0;
#pragma unroll 2
      for (int i = 0; i < 32; i++) {
        int j = qf * 32 + i;
        const float* wi = wih_t + (size_t)j * 384;
        const float* wh = whh_t + (size_t)j * 384;
        float xc = ctx[j], xh = mfS[j];
        gi0 += xc * wi[t128]; gi1 += xc * wi[128 + t128]; gi2 += xc * wi[256 + t128];
        gh0 += xh * wh[t128]; gh1 += xh * wh[128 + t128]; gh2 += xh * wh[256 + t128];
      }
      if (qf > 0) {
        pg[qf - 1][0][t128] = gi0; pg[qf - 1][1][t128] = gi1; pg[qf - 1][2][t128] = gi2;
        pg[qf - 1][3][t128] = gh0; pg[qf - 1][4][t128] = gh1; pg[qf - 1][5][t128] = gh2;
      }
      __syncthreads();
      if (qf == 0) {
        gi0 += pg[0][0][t128] + pg[1][0][t128] + pg[2][0][t128] + bih[t128];
        gi1 += pg[0][1][t128] + pg[1][1][t128] + pg[2][1][t128] + bih[128 + t128];
        gi2 += pg[0][2][t128] + pg[1][2][t128] + pg[2][2][t128] + bih[256 + t128];
        gh0 += pg[0][3][t128] + pg[1][3][t128] + pg[2][3][t128] + bhh[t128];
        gh1 += pg[0][4][t128] + pg[1][4][t128] + pg[2][4][t128] + bhh[128 + t128];
        gh2 += pg[0][5][t128] + pg[1][5][t128] + pg[2][5][t128] + bhh[256 + t128];
        float r = sigm(gi0 + gh0);
        float z = sigm(gi1 + gh1);
        float n = tanhf(gi2 + r * gh2);
        float hn = (1.f - z) * n + z * mfS[t128];
        mfS[t128] = hn;
        amol[t128] = fmaxf(hn, 0.f);
      }
      __syncthreads();
    }
  }

  red[tid] = (tid < 128) ? mfS[tid] * ow[tid] : 0.f;
  __syncthreads();
  for (int s = 256; s > 0; s >>= 1) { if (tid < s) red[tid] += red[tid + s]; __syncthreads(); }
  if (tid == 0) pred[b] = red[0] + ob[0];
}

extern "C" void kernel_launch(void* const* d_in, const int* in_sizes, int n_in,
                              void* d_out, int out_size, void* d_ws, size_t ws_size,
                              hipStream_t stream) {
  const float* atom_list    = (const float*)d_in[0];
  const float* bond_list    = (const float*)d_in[1];
  const float* atom_mask    = (const float*)d_in[2];
  const float* atom_fc_w    = (const float*)d_in[3];
  const float* atom_fc_b    = (const float*)d_in[4];
  const float* nbr_fc_w     = (const float*)d_in[5];
  const float* nbr_fc_b     = (const float*)d_in[6];
  const float* align_w      = (const float*)d_in[7];
  const float* align_b      = (const float*)d_in[8];
  const float* attend_w     = (const float*)d_in[9];
  const float* attend_b     = (const float*)d_in[10];
  const float* gru_wih      = (const float*)d_in[11];
  const float* gru_whh      = (const float*)d_in[12];
  const float* gru_bih      = (const float*)d_in[13];
  const float* gru_bhh      = (const float*)d_in[14];
  const float* mol_align_w  = (const float*)d_in[15];
  const float* mol_align_b  = (const float*)d_in[16];
  const float* mol_attend_w = (const float*)d_in[17];
  const float* mol_attend_b = (const float*)d_in[18];
  const float* mol_gru_wih  = (const float*)d_in[19];
  const float* mol_gru_whh  = (const float*)d_in[20];
  const float* mol_gru_bih  = (const float*)d_in[21];
  const float* mol_gru_bhh  = (const float*)d_in[22];
  const float* out_w        = (const float*)d_in[23];
  const float* out_b        = (const float*)d_in[24];
  const int*   adeg         = (const int*)d_in[25];
  const int*   bdeg         = (const int*)d_in[26];

  const size_t NH = (size_t)B_ * L_ * D_;
  float* hW   = (float*)d_ws;            // 16 MB
  short* wB   = (short*)(hW + NH);       // 1.38 MB
  float* molT = (float*)(wB + NB16);     // 0.39 MB
  short* APg  = (short*)(molT + NMOLF);  // NH shorts = 8.39 MB
  float* Q0g  = (float*)(APg + NH);      // B*L*K floats = 0.79 MB
  float* PgA  = Q0g + (size_t)B_ * L_ * K_;
  float* QgA  = PgA + B_ * L_;
  float* PgB  = QgA + B_ * L_;
  float* QgB  = PgB + B_ * L_;
  float* hOut = (float*)d_out;
  float* pred = hOut + NH;

  k_tr<<<dim3((NB16 + NMOLF + 255) / 256), dim3(256), 0, stream>>>(
      gru_wih, gru_whh, attend_w, mol_gru_wih, mol_gru_whh, wB, molT);

  k_pre<<<dim3(B_ * L_ / 16), dim3(128), 0, stream>>>(
      atom_list, atom_fc_w, atom_fc_b, nbr_fc_w, align_w, hOut, APg, PgA);
  k_q0<<<dim3(B_ * L_ * K_ / 64), dim3(256), 0, stream>>>(
      bond_list, nbr_fc_w, nbr_fc_b, align_w, adeg, bdeg, APg, Q0g);

  dim3 blk(256), grd(B_ * L_ / NA);

  // r0: hOut(h0) -> hW ; r1: hW -> hOut ; r2: hOut -> hW
  k_round<1><<<grd, blk, 0, stream>>>(
      hOut, hW, bond_list, adeg, bdeg, nbr_fc_w, nbr_fc_b, APg,
      align_b, align_w + 2 * D_, attend_b,
      wB + 0 * (size_t)RND_BLK2, gru_bih, gru_bhh,
      PgA, Q0g, PgB, QgB);
  k_round<0><<<grd, blk, 0, stream>>>(
      hW, hOut, bond_list, adeg, bdeg, nbr_fc_w, nbr_fc_b, APg,
      align_b + 1, align_w + 4 * D_, attend_b + D_,
      wB + 1 * (size_t)RND_BLK2, gru_bih + 3 * D_, gru_bhh + 3 * D_,
      PgB, QgB, PgA, QgA);
  k_round<0><<<grd, blk, 0, stream>>>(
      hOut, hW, bond_list, adeg, bdeg, nbr_fc_w, nbr_fc_b, APg,
      align_b + 2, align_w + 4 * D_, attend_b + 2 * D_,
      wB + 2 * (size_t)RND_BLK2, gru_bih + 6 * D_, gru_bhh + 6 * D_,
      PgA, QgA, (float*)nullptr, (float*)nullptr);

  k_mol<<<dim3(B_), dim3(512), 0, stream>>>(
      hW, hOut, atom_mask, mol_align_w, mol_align_b, mol_attend_w, mol_attend_b,
      molT, molT + 128 * 384,
      mol_gru_bih, mol_gru_bhh, out_w, out_b, pred);
}

// Round 13
// 403.050 us; speedup vs baseline: 30.6833x; 1.1059x over previous
//
#include <hip/hip_runtime.h>
#include <cstddef>

// AttentiveFP forward. B=256 L=128 K=6 FA=39 FB=10 D=128 R=3 T=2. fp32 I/O.
// h carried BF16 (hA/hB ping-pong entirely in ws; d_out touched only by k_mol).
// MFMA split precision: ctx hi/lo x weight hi/lo (3 MFMA); GRU h-path exact
// (h is bf16) -> 5 MFMA per (t,kd). Weights frag-swizzled (lane-contiguous).
// ws = hA 8.4 + hB 8.4 + wB 1.38 + molT 0.39 + P/Q 0.52 + APg 8.39 + Q0g 0.79
//    = 28.25 MB (same as proven footprint).

#define B_ 256
#define L_ 128
#define K_ 6
#define FA_ 39
#define FB_ 10
#define D_ 128
#define PAD_ 127
#define NEGC (-9.0e8f)
#define NA 16
#define NPAIR (NA * K_)   // 96

typedef unsigned short u16;
typedef unsigned int u32;
using s8 = __attribute__((ext_vector_type(8))) short;   // 8 x bf16
using f4 = __attribute__((ext_vector_type(4))) float;   // MFMA acc

#define WIH_H 0
#define WIH_L 49152
#define WHH_H 98304
#define WHH_L 147456
#define TW_H  196608
#define TW_L  212992
#define RND_BLK2 229376
#define NB16 (3 * RND_BLK2)
#define NMOLF (2 * 128 * 384)

__device__ __forceinline__ float lrelu(float x) { return x > 0.f ? x : 0.01f * x; }
__device__ __forceinline__ float eluf(float x)  { return x > 0.f ? x : expm1f(x); }
__device__ __forceinline__ float sigm(float x)  { return 1.f / (1.f + expf(-x)); }
__device__ __forceinline__ float b2f(u16 u) {
  union { u32 i; float f; } v; v.i = ((u32)u) << 16; return v.f;
}
__device__ __forceinline__ short f2b(float f) {  // RNE
  union { float f; u32 i; } v; v.f = f;
  u32 x = v.i;
  return (short)(u16)((x + 0x7FFFu + ((x >> 16) & 1u)) >> 16);
}

// Build frag-swizzled split bf16 weights + fp32 transposed mol GRU weights.
// Swizzle: element ((gt*4+kc)*64+lane)*8+j  <=  W[gt*16+(lane&15)][kc*32+(lane>>4)*8+j]
__global__ __launch_bounds__(256) void k_tr(
    const float* __restrict__ gwih, const float* __restrict__ gwhh,
    const float* __restrict__ attw,
    const float* __restrict__ mwih, const float* __restrict__ mwhh,
    short* __restrict__ wB, float* __restrict__ molT) {
  int idx = blockIdx.x * 256 + threadIdx.x;
  if (idx < NB16) {
    int r = idx / RND_BLK2, o = idx % RND_BLK2;
    float v; int lo;
    int e, kind;          // kind 0=wih, 1=whh, 2=tw
    if (o < 98304)      { kind = 0; lo = o / 49152; e = o % 49152; }
    else if (o < 196608){ kind = 1; int o2 = o - 98304; lo = o2 / 49152; e = o2 % 49152; }
    else                { kind = 2; int o2 = o - 196608; lo = o2 / 16384; e = o2 % 16384; }
    int gt = e >> 11, rem = e & 2047;
    int kc = rem >> 9, rem2 = rem & 511;
    int lane = rem2 >> 3, j = rem2 & 7;
    int col = lane & 15, quad = lane >> 4;
    int g = gt * 16 + col;
    int k = kc * 32 + quad * 8 + j;
    if (kind == 0)      v = gwih[(size_t)r * 49152 + g * 128 + k];
    else if (kind == 1) v = gwhh[(size_t)r * 49152 + g * 128 + k];
    else                v = attw[(size_t)r * 16384 + k * 128 + g];
    short hi = f2b(v);
    wB[idx] = lo ? f2b(v - b2f((u16)hi)) : hi;
  } else if (idx < NB16 + NMOLF) {
    int e2 = idx - NB16;
    int m = e2 / 49152, e = e2 % 49152, j = e / 384, g = e % 384;
    molT[e2] = (m ? mwhh : mwih)[g * 128 + j];
  }
}

// Per-atom precompute: h0 (bf16), AP = atom@Wa (bf16), P0 = h0.awlo0.
__global__ __launch_bounds__(128) void k_pre(
    const float* __restrict__ atom_list,
    const float* __restrict__ afc_w, const float* __restrict__ afc_b,
    const float* __restrict__ nbr_w,
    const float* __restrict__ aw0,
    u16* __restrict__ h0out, short* __restrict__ APg, float* __restrict__ PgA)
{
  int tid = threadIdx.x;
  int a0 = blockIdx.x * 16;
  __shared__ float xa[16 * 40];
  __shared__ float h0S[16][132];
  __shared__ float awS[128];
  __shared__ float partials[128];

  for (int i = tid; i < 16 * FA_; i += 128) {
    int a = i / FA_, c = i % FA_;
    xa[a * 40 + c] = atom_list[((size_t)(a0 + a)) * FA_ + c];
  }
  awS[tid] = aw0[tid];
  __syncthreads();

  {
    float acc[16];
    float bv = afc_b[tid];
#pragma unroll
    for (int a = 0; a < 16; a++) acc[a] = bv;
#pragma unroll 2
    for (int j = 0; j < FA_; j++) {
      float w = afc_w[j * D_ + tid];
#pragma unroll
      for (int a = 0; a < 16; a++) acc[a] += xa[a * 40 + j] * w;
    }
#pragma unroll
    for (int a = 0; a < 16; a++) {
      float hv = lrelu(acc[a]);
      h0out[(size_t)(a0 + a) * D_ + tid] = (u16)f2b(hv);
      h0S[a][tid] = hv;
    }
  }
  {
    float acc[16];
#pragma unroll
    for (int a = 0; a < 16; a++) acc[a] = 0.f;
#pragma unroll 2
    for (int j = 0; j < FA_; j++) {
      float w = nbr_w[j * D_ + tid];
#pragma unroll
      for (int a = 0; a < 16; a++) acc[a] += xa[a * 40 + j] * w;
    }
#pragma unroll
    for (int a = 0; a < 16; a++)
      APg[(size_t)(a0 + a) * D_ + tid] = f2b(acc[a]);
  }
  __syncthreads();
  {
    int a = tid >> 3, seg = tid & 7;
    float s = 0.f;
#pragma unroll
    for (int j = 0; j < 16; j++) s += h0S[a][seg * 16 + j] * awS[seg * 16 + j];
    partials[tid] = s;
  }
  __syncthreads();
  if (tid < 16) {
    float s = 0.f;
#pragma unroll
    for (int g = 0; g < 8; g++) s += partials[tid * 8 + g];
    PgA[a0 + tid] = s;
  }
}

// Per-pair Q0 = sum_d lrelu(AP[aidx]+bond[bidx]@Wb+nb) * awhi0.
__global__ __launch_bounds__(256) void k_q0(
    const float* __restrict__ bond_list,
    const float* __restrict__ nbr_w, const float* __restrict__ nbr_b,
    const float* __restrict__ aw0,
    const int* __restrict__ adeg, const int* __restrict__ bdeg,
    const short* __restrict__ APg, float* __restrict__ Q0g)
{
  int tid = threadIdx.x;
  __shared__ float WbS[10 * 128];
  __shared__ float nbS[128], ahS[128];
  for (int i = tid; i < 10 * 128; i += 256)
    WbS[i] = nbr_w[(FA_ + i / 128) * D_ + (i % 128)];
  if (tid < 128) { nbS[tid] = nbr_b[tid]; ahS[tid] = aw0[D_ + tid]; }
  __syncthreads();

  int p = blockIdx.x * 64 + (tid >> 2);
  int seg = tid & 3;
  int aidx = adeg[p], bidx = bdeg[p];
  int bb = p / (L_ * K_);
  const short* rowA = APg + ((size_t)bb * L_ + aidx) * D_;
  const float* brow = bond_list + ((size_t)bb * L_ + bidx) * FB_;
  float bnd[10];
#pragma unroll
  for (int m = 0; m < 10; m++) bnd[m] = brow[m];
  float s = 0.f;
  int j0 = seg * 32;
#pragma unroll 4
  for (int j = j0; j < j0 + 32; j++) {
    float v = b2f((u16)rowA[j]) + nbS[j];
#pragma unroll
    for (int m = 0; m < 10; m++) v += bnd[m] * WbS[m * 128 + j];
    s += lrelu(v) * ahS[j];
  }
  s += __shfl_xor(s, 1, 64);
  s += __shfl_xor(s, 2, 64);
  if (seg == 0) Q0g[p] = s;
}

template <int FIRST>
__global__ __launch_bounds__(256, 6) void k_round(
    const u16* __restrict__ hin,     // bf16 h
    u16* __restrict__ hout,          // bf16 h
    const float* __restrict__ bond_list,
    const int* __restrict__ adeg, const int* __restrict__ bdeg,
    const float* __restrict__ nbr_w, const float* __restrict__ nbr_b,
    const short* __restrict__ APg,
    const float* __restrict__ ab,
    const float* __restrict__ awN,
    const float* __restrict__ tb,
    const short* __restrict__ wR,
    const float* __restrict__ bih, const float* __restrict__ bhh,
    const float* __restrict__ Pr, const float* __restrict__ Qr,
    float* __restrict__ Pw, float* __restrict__ Qw)
{
  int tid  = threadIdx.x;
  int t128 = tid & 127;
  int hf   = tid >> 7;
  int lane = tid & 63;
  int wv   = tid >> 6;
  int quad = lane >> 4;
  int col  = lane & 15;
  int a0   = blockIdx.x * NA;
  int bb   = a0 >> 7;

  const short* wihH = wR + WIH_H;
  const short* wihL = wR + WIH_L;
  const short* whhH = wR + WHH_H;
  const short* whhL = wR + WHH_L;
  const short* twH  = wR + TW_H;
  const short* twL  = wR + TW_L;

  __shared__ short hrowH[NA][136];                 // exact bf16 h
  __shared__ __align__(16) char arena[9472];       // ybar/ctx | hnrelu
  __shared__ float awNS[256];
  __shared__ float partials[256];
  __shared__ float pS[NA], qS[NPAIR], wkS[NPAIR], wsS[NA];
  __shared__ int aidxS[NPAIR];
  __shared__ int bidxS[FIRST ? NPAIR : 1];
  __shared__ float bwS[FIRST ? 2368 : 1];          // bond[96][10] | Wb[10][128] | nb[128]

  short* ybarH = (short*)arena;               // [16][136] (ctx reuses)
  short* ybarL = (short*)(arena + 4352);
  float* hnrel = (float*)arena;               // epilogue relu(hn) [16][132]

  if (tid < NPAIR) {
    int av = adeg[a0 * K_ + tid];
    aidxS[tid] = av;
    if (FIRST) { bidxS[tid] = bdeg[a0 * K_ + tid]; qS[tid] = Qr[a0 * K_ + tid]; }
    else       qS[tid] = Qr[bb * L_ + av];
  } else if (tid >= 128 && tid < 128 + NA) {
    pS[tid - 128] = Pr[a0 + (tid - 128)];
  }
  awNS[tid] = awN[tid];
  __syncthreads();

  // ---------- Phase 1: h rows (+ FIRST: bond/Wb staging) ----------
  if (FIRST) {
    for (int i = tid; i < 960; i += 256) {
      int p = i / 10, m = i % 10;
      bwS[p * 10 + m] = bond_list[((size_t)bb * L_ + bidxS[p]) * FB_ + m];
    }
    for (int i = tid; i < 1280; i += 256)
      bwS[960 + i] = nbr_w[(FA_ + i / 128) * D_ + (i % 128)];
    if (tid < 128) bwS[2240 + tid] = nbr_b[tid];
  }
#pragma unroll 4
  for (int i = 0; i < 8; i++) {
    int a = i * 2 + hf;
    hrowH[a][t128] = (short)hin[(size_t)(a0 + a) * D_ + t128];
  }
  __syncthreads();

  // ---------- Softmax over K ----------
  if (tid < NA) {
    int a = tid;
    float abv = ab[0];
    float sc[K_];
    float m = -3.0e38f;
#pragma unroll
    for (int k = 0; k < K_; k++) {
      float s = lrelu(pS[a] + qS[a * K_ + k] + abv);
      if (aidxS[a * K_ + k] == PAD_) s += NEGC;
      sc[k] = s; m = fmaxf(m, s);
    }
    float es = 0.f;
#pragma unroll
    for (int k = 0; k < K_; k++) { sc[k] = expf(sc[k] - m); es += sc[k]; }
    float ws = 0.f;
#pragma unroll
    for (int k = 0; k < K_; k++) {
      float w = (aidxS[a * K_ + k] == PAD_) ? 0.f : sc[k] / es;
      wkS[a * K_ + k] = w; ws += w;
    }
    wsS[a] = ws;
  }
  __syncthreads();

  // ---------- ybar hi/lo (gather rows loaded inline, bf16) ----------
  if (FIRST) {
    const float* bondS = bwS;
    const float* WbS   = bwS + 960;
    float nbv = bwS[2240 + t128];
#pragma unroll
    for (int i = 0; i < 8; i++) {
      int a = hf * 8 + i;
      float yb = 0.f;
#pragma unroll
      for (int k = 0; k < K_; k++) {
        int p = a * K_ + k;
        float nf = b2f((u16)APg[((size_t)bb * L_ + aidxS[p]) * D_ + t128]) + nbv;
#pragma unroll
        for (int m = 0; m < 10; m++) nf += bondS[p * 10 + m] * WbS[m * 128 + t128];
        yb += wkS[p] * lrelu(nf);
      }
      short yh = f2b(yb);
      ybarH[a * 136 + t128] = yh;
      ybarL[a * 136 + t128] = f2b(yb - b2f((u16)yh));
    }
  } else {
#pragma unroll
    for (int i = 0; i < 8; i++) {
      int a = hf * 8 + i;
      float yb = 0.f;
#pragma unroll
      for (int k = 0; k < K_; k++) {
        float v = b2f(hin[((size_t)bb * L_ + aidxS[a * K_ + k]) * D_ + t128]);
        yb += wkS[a * K_ + k] * fmaxf(v, 0.f);
      }
      short yh = f2b(yb);
      ybarH[a * 136 + t128] = yh;
      ybarL[a * 136 + t128] = f2b(yb - b2f((u16)yh));
    }
  }
  __syncthreads();

  // ---------- ctx = elu(ybar @ twT^T + wsum*tb), split MFMA (swizzled B) ----------
  {
    f4 c2[2] = {};
#pragma unroll
    for (int k0c = 0; k0c < 4; k0c++) {
      s8 ayh = *(const s8*)&ybarH[col * 136 + k0c * 32 + quad * 8];
      s8 ayl = *(const s8*)&ybarL[col * 136 + k0c * 32 + quad * 8];
#pragma unroll
      for (int t = 0; t < 2; t++) {
        int gt = 2 * wv + t;
        int fo = ((gt * 4 + k0c) * 64 + lane) * 8;
        s8 bwh = *(const s8*)&twH[fo];
        s8 bwl = *(const s8*)&twL[fo];
        c2[t] = __builtin_amdgcn_mfma_f32_16x16x32_bf16(ayh, bwh, c2[t], 0, 0, 0);
        c2[t] = __builtin_amdgcn_mfma_f32_16x16x32_bf16(ayl, bwh, c2[t], 0, 0, 0);
        c2[t] = __builtin_amdgcn_mfma_f32_16x16x32_bf16(ayh, bwl, c2[t], 0, 0, 0);
      }
    }
    __syncthreads();
#pragma unroll
    for (int t = 0; t < 2; t++) {
      int g = (2 * wv + t) * 16 + col;
      float tbv = tb[g];
#pragma unroll
      for (int r = 0; r < 4; r++) {
        int a = quad * 4 + r;
        float c = eluf(c2[t][r] + wsS[a] * tbv);
        short chs = f2b(c);
        ybarH[a * 136 + g] = chs;                    // ctxH
        ybarL[a * 136 + g] = f2b(c - b2f((u16)chs)); // ctxL
      }
    }
  }
  __syncthreads();

  // ---------- GRU via split MFMA (h exact bf16 -> 5 MFMA per (t,kd)) ----------
  {
    const short* ctxH = ybarH;
    const short* ctxL = ybarL;
    f4 gi[2][3] = {}, gh[2][3] = {};
#pragma unroll
    for (int k0c = 0; k0c < 4; k0c++) {
      s8 ach = *(const s8*)&ctxH[col * 136 + k0c * 32 + quad * 8];
      s8 acl = *(const s8*)&ctxL[col * 136 + k0c * 32 + quad * 8];
      s8 ahh = *(const s8*)&hrowH[col][k0c * 32 + quad * 8];
#pragma unroll
      for (int t = 0; t < 2; t++) {
#pragma unroll
        for (int kd = 0; kd < 3; kd++) {
          int gt = (2 * wv + t) + kd * 8;
          int fo = ((gt * 4 + k0c) * 64 + lane) * 8;
          s8 bi_h = *(const s8*)&wihH[fo];
          s8 bi_l = *(const s8*)&wihL[fo];
          s8 bh_h = *(const s8*)&whhH[fo];
          s8 bh_l = *(const s8*)&whhL[fo];
          gi[t][kd] = __builtin_amdgcn_mfma_f32_16x16x32_bf16(ach, bi_h, gi[t][kd], 0, 0, 0);
          gi[t][kd] = __builtin_amdgcn_mfma_f32_16x16x32_bf16(acl, bi_h, gi[t][kd], 0, 0, 0);
          gi[t][kd] = __builtin_amdgcn_mfma_f32_16x16x32_bf16(ach, bi_l, gi[t][kd], 0, 0, 0);
          gh[t][kd] = __builtin_amdgcn_mfma_f32_16x16x32_bf16(ahh, bh_h, gh[t][kd], 0, 0, 0);
          gh[t][kd] = __builtin_amdgcn_mfma_f32_16x16x32_bf16(ahh, bh_l, gh[t][kd], 0, 0, 0);
        }
      }
    }
    __syncthreads();

#pragma unroll
    for (int t = 0; t < 2; t++) {
      int ic = (2 * wv + t) * 16 + col;
      float bi0 = bih[ic], bi1 = bih[D_ + ic], bi2 = bih[2 * D_ + ic];
      float bh0 = bhh[ic], bh1 = bhh[D_ + ic], bh2 = bhh[2 * D_ + ic];
#pragma unroll
      for (int r = 0; r < 4; r++) {
        int a = quad * 4 + r;
        float rr = sigm(gi[t][0][r] + bi0 + gh[t][0][r] + bh0);
        float zz = sigm(gi[t][1][r] + bi1 + gh[t][1][r] + bh1);
        float nn = tanhf(gi[t][2][r] + bi2 + rr * (gh[t][2][r] + bh2));
        float hv = b2f((u16)hrowH[a][ic]);
        float hn = (1.f - zz) * nn + zz * hv;
        hout[(size_t)(a0 + a) * D_ + ic] = (u16)f2b(hn);
        if (Pw) hnrel[a * 132 + ic] = fmaxf(hn, 0.f);
      }
    }
  }

  // ---------- Epilogue: P/Q for next round (skipped on last round) ----------
  if (Pw) {
    __syncthreads();
    {
      int a = tid >> 4, dt = (tid >> 3) & 1, seg = tid & 7;
      float s = 0.f;
#pragma unroll
      for (int j = 0; j < 16; j++)
        s += hnrel[a * 132 + seg * 16 + j] * awNS[dt * 128 + seg * 16 + j];
      partials[tid] = s;
    }
    __syncthreads();
    if (tid < 32) {
      int a = tid >> 1, dt = tid & 1;
      float s = 0.f;
#pragma unroll
      for (int seg = 0; seg < 8; seg++) s += partials[a * 16 + dt * 8 + seg];
      if (dt) Qw[a0 + a] = s; else Pw[a0 + a] = s;
    }
  }
}

__global__ __launch_bounds__(512) void k_mol(
    const u16* __restrict__ hfin,    // bf16 final h
    float* __restrict__ hcopy,       // d_out h region (fp32)
    const float* __restrict__ amask,
    const float* __restrict__ maw, const float* __restrict__ mab,
    const float* __restrict__ mtw, const float* __restrict__ mtb,
    const float* __restrict__ wih_t, const float* __restrict__ whh_t,
    const float* __restrict__ bih, const float* __restrict__ bhh,
    const float* __restrict__ ow, const float* __restrict__ ob,
    float* __restrict__ pred)
{
  int b = blockIdx.x;
  int tid = threadIdx.x;
  int t128 = tid & 127;
  int qf = tid >> 7;           // quarter 0..3
  __shared__ float actS[L_][D_ + 1];
  __shared__ float red[512];
  __shared__ float par4[4][132];
  __shared__ float pg[3][6][132];
  __shared__ float wgt[128], ybv[132], ctx[132], mfS[132], amol[132];
  __shared__ float msk[128], mawh[128], scf[128];

  if (qf == 0) { msk[t128] = amask[b * L_ + t128]; mawh[t128] = maw[D_ + t128]; }
  for (int i = 0; i < 32; i++) {
    int l = qf * 32 + i;
    float hv = b2f(hfin[(size_t)(b * L_ + l) * D_ + t128]);
    hcopy[(size_t)(b * L_ + l) * D_ + t128] = hv;
    actS[l][t128] = fmaxf(hv, 0.f);
  }
  __syncthreads();

  // mol_feature (l-split quarters)
  {
    float s = 0.f;
    for (int i = 0; i < 32; i++) { int l = qf * 32 + i; s += actS[l][t128] * msk[l]; }
    par4[qf][t128] = s;
  }
  __syncthreads();
  if (qf == 0) {
    float mf = par4[0][t128] + par4[1][t128] + par4[2][t128] + par4[3][t128];
    mfS[t128] = mf; amol[t128] = fmaxf(mf, 0.f);
  }
  __syncthreads();

  float mabv = mab[0];

  for (int t = 0; t < 2; t++) {
    // s0
    red[tid] = (tid < 128) ? amol[tid] * maw[tid] : 0.f;
    __syncthreads();
    for (int s = 256; s > 0; s >>= 1) { if (tid < s) red[tid] += red[tid + s]; __syncthreads(); }
    float s0 = red[0]; __syncthreads();

    // sc[l=t128] (j-split quarters)
    {
      float s = 0.f;
      for (int i = 0; i < 32; i++) { int j = qf * 32 + i; s += actS[t128][j] * mawh[j]; }
      par4[qf][t128] = s;
    }
    __syncthreads();
    if (qf == 0) {
      float sc = lrelu(s0 + mabv + par4[0][t128] + par4[1][t128] + par4[2][t128] + par4[3][t128]);
      if (msk[t128] == 0.f) sc += NEGC;
      scf[t128] = sc;
    }
    __syncthreads();

    // softmax over l
    float scv = scf[t128];
    red[tid] = (tid < 128) ? scv : -3.0e38f;
    __syncthreads();
    for (int s = 256; s > 0; s >>= 1) { if (tid < s) red[tid] = fmaxf(red[tid], red[tid + s]); __syncthreads(); }
    float mx = red[0]; __syncthreads();
    float e = expf(scv - mx);
    red[tid] = (tid < 128) ? e : 0.f;
    __syncthreads();
    for (int s = 256; s > 0; s >>= 1) { if (tid < s) red[tid] += red[tid + s]; __syncthreads(); }
    float es = red[0]; __syncthreads();
    float w = (e / es) * msk[t128];
    if (qf == 0) wgt[t128] = w;
    red[tid] = (tid < 128) ? w : 0.f;
    __syncthreads();
    for (int s = 256; s > 0; s >>= 1) { if (tid < s) red[tid] += red[tid + s]; __syncthreads(); }
    float wsum = red[0]; __syncthreads();

    // y[j=t128] (l-split quarters)
    {
      float s = 0.f;
      for (int i = 0; i < 32; i++) { int l = qf * 32 + i; s += wgt[l] * actS[l][t128]; }
      par4[qf][t128] = s;
    }
    __syncthreads();
    if (qf == 0) ybv[t128] = par4[0][t128] + par4[1][t128] + par4[2][t128] + par4[3][t128];
    __syncthreads();

    // ctx[g=t128] (j-split quarters)
    {
      float s = 0.f;
#pragma unroll 2
      for (int i = 0; i < 32; i++) { int j = qf * 32 + i; s += ybv[j] * mtw[j * D_ + t128]; }
      par4[qf][t128] = s;
    }
    __syncthreads();
    if (qf == 0)
      ctx[t128] = eluf(par4[0][t128] + par4[1][t128] + par4[2][t128] + par4[3][t128]
                       + wsum * mtb[t128]);
    __syncthreads();

    // GRU (j-split quarters, x-stationary)
    {
      float gi0 = 0, gi1 = 0, gi2 = 0, gh0 = 0, gh1 = 0, gh2 = 0;
#pragma unroll 2
      for (int i = 0; i < 32; i++) {
        int j = qf * 32 + i;
        const float* wi = wih_t + (size_t)j * 384;
        const float* wh = whh_t + (size_t)j * 384;
        float xc = ctx[j], xh = mfS[j];
        gi0 += xc * wi[t128]; gi1 += xc * wi[128 + t128]; gi2 += xc * wi[256 + t128];
        gh0 += xh * wh[t128]; gh1 += xh * wh[128 + t128]; gh2 += xh * wh[256 + t128];
      }
      if (qf > 0) {
        pg[qf - 1][0][t128] = gi0; pg[qf - 1][1][t128] = gi1; pg[qf - 1][2][t128] = gi2;
        pg[qf - 1][3][t128] = gh0; pg[qf - 1][4][t128] = gh1; pg[qf - 1][5][t128] = gh2;
      }
      __syncthreads();
      if (qf == 0) {
        gi0 += pg[0][0][t128] + pg[1][0][t128] + pg[2][0][t128] + bih[t128];
        gi1 += pg[0][1][t128] + pg[1][1][t128] + pg[2][1][t128] + bih[128 + t128];
        gi2 += pg[0][2][t128] + pg[1][2][t128] + pg[2][2][t128] + bih[256 + t128];
        gh0 += pg[0][3][t128] + pg[1][3][t128] + pg[2][3][t128] + bhh[t128];
        gh1 += pg[0][4][t128] + pg[1][4][t128] + pg[2][4][t128] + bhh[128 + t128];
        gh2 += pg[0][5][t128] + pg[1][5][t128] + pg[2][5][t128] + bhh[256 + t128];
        float r = sigm(gi0 + gh0);
        float z = sigm(gi1 + gh1);
        float n = tanhf(gi2 + r * gh2);
        float hn = (1.f - z) * n + z * mfS[t128];
        mfS[t128] = hn;
        amol[t128] = fmaxf(hn, 0.f);
      }
      __syncthreads();
    }
  }

  red[tid] = (tid < 128) ? mfS[tid] * ow[tid] : 0.f;
  __syncthreads();
  for (int s = 256; s > 0; s >>= 1) { if (tid < s) red[tid] += red[tid + s]; __syncthreads(); }
  if (tid == 0) pred[b] = red[0] + ob[0];
}

extern "C" void kernel_launch(void* const* d_in, const int* in_sizes, int n_in,
                              void* d_out, int out_size, void* d_ws, size_t ws_size,
                              hipStream_t stream) {
  const float* atom_list    = (const float*)d_in[0];
  const float* bond_list    = (const float*)d_in[1];
  const float* atom_mask    = (const float*)d_in[2];
  const float* atom_fc_w    = (const float*)d_in[3];
  const float* atom_fc_b    = (const float*)d_in[4];
  const float* nbr_fc_w     = (const float*)d_in[5];
  const float* nbr_fc_b     = (const float*)d_in[6];
  const float* align_w      = (const float*)d_in[7];
  const float* align_b      = (const float*)d_in[8];
  const float* attend_w     = (const float*)d_in[9];
  const float* attend_b     = (const float*)d_in[10];
  const float* gru_wih      = (const float*)d_in[11];
  const float* gru_whh      = (const float*)d_in[12];
  const float* gru_bih      = (const float*)d_in[13];
  const float* gru_bhh      = (const float*)d_in[14];
  const float* mol_align_w  = (const float*)d_in[15];
  const float* mol_align_b  = (const float*)d_in[16];
  const float* mol_attend_w = (const float*)d_in[17];
  const float* mol_attend_b = (const float*)d_in[18];
  const float* mol_gru_wih  = (const float*)d_in[19];
  const float* mol_gru_whh  = (const float*)d_in[20];
  const float* mol_gru_bih  = (const float*)d_in[21];
  const float* mol_gru_bhh  = (const float*)d_in[22];
  const float* out_w        = (const float*)d_in[23];
  const float* out_b        = (const float*)d_in[24];
  const int*   adeg         = (const int*)d_in[25];
  const int*   bdeg         = (const int*)d_in[26];

  const size_t NH = (size_t)B_ * L_ * D_;
  u16*   hA   = (u16*)d_ws;              // NH shorts = 8.39 MB
  u16*   hB   = hA + NH;                 // NH shorts = 8.39 MB
  short* wB   = (short*)(hB + NH);       // NB16 shorts = 1.38 MB
  float* molT = (float*)(wB + NB16);     // NMOLF floats = 0.39 MB
  float* PgA  = molT + NMOLF;            // 4 x 128KB P/Q buffers
  float* QgA  = PgA + B_ * L_;
  float* PgB  = QgA + B_ * L_;
  float* QgB  = PgB + B_ * L_;
  short* APg  = (short*)(QgB + B_ * L_); // NH shorts = 8.39 MB
  float* Q0g  = (float*)(APg + NH);      // B*L*K floats = 0.79 MB
  float* hOut = (float*)d_out;
  float* pred = hOut + NH;

  k_tr<<<dim3((NB16 + NMOLF + 255) / 256), dim3(256), 0, stream>>>(
      gru_wih, gru_whh, attend_w, mol_gru_wih, mol_gru_whh, wB, molT);

  k_pre<<<dim3(B_ * L_ / 16), dim3(128), 0, stream>>>(
      atom_list, atom_fc_w, atom_fc_b, nbr_fc_w, align_w, hA, APg, PgA);
  k_q0<<<dim3(B_ * L_ * K_ / 64), dim3(256), 0, stream>>>(
      bond_list, nbr_fc_w, nbr_fc_b, align_w, adeg, bdeg, APg, Q0g);

  dim3 blk(256), grd(B_ * L_ / NA);

  // r0: hA -> hB ; r1: hB -> hA ; r2: hA -> hB ; k_mol: hB -> d_out
  k_round<1><<<grd, blk, 0, stream>>>(
      hA, hB, bond_list, adeg, bdeg, nbr_fc_w, nbr_fc_b, APg,
      align_b, align_w + 2 * D_, attend_b,
      wB + 0 * (size_t)RND_BLK2, gru_bih, gru_bhh,
      PgA, Q0g, PgB, QgB);
  k_round<0><<<grd, blk, 0, stream>>>(
      hB, hA, bond_list, adeg, bdeg, nbr_fc_w, nbr_fc_b, APg,
      align_b + 1, align_w + 4 * D_, attend_b + D_,
      wB + 1 * (size_t)RND_BLK2, gru_bih + 3 * D_, gru_bhh + 3 * D_,
      PgB, QgB, PgA, QgA);
  k_round<0><<<grd, blk, 0, stream>>>(
      hA, hB, bond_list, adeg, bdeg, nbr_fc_w, nbr_fc_b, APg,
      align_b + 2, align_w + 4 * D_, attend_b + 2 * D_,
      wB + 2 * (size_t)RND_BLK2, gru_bih + 6 * D_, gru_bhh + 6 * D_,
      PgA, QgA, (float*)nullptr, (float*)nullptr);

  k_mol<<<dim3(B_), dim3(512), 0, stream>>>(
      hB, hOut, atom_mask, mol_align_w, mol_align_b, mol_attend_w, mol_attend_b,
      molT, molT + 128 * 384,
      mol_gru_bih, mol_gru_bhh, out_w, out_b, pred);
}